// Round 1
// baseline (986.992 us; speedup 1.0000x reference)
//
#include <hip/hip_runtime.h>
#include <math.h>

#define Hh 8
#define Ll 1024
#define KF 24
#define Dm 512
#define EPSf 1e-5f
#define LK (Ll*KF)   // 24576 rows (t,kf) per head

// ---- workspace offsets (floats) ----
#define OFF_QH     0
#define OFF_KN     524288
#define OFF_VN     1048576
#define OFF_SIM    1572864
#define OFF_LOGITS 1581056
#define OFF_GATES  1589248
#define OFF_FACTOR 1597440
#define OFF_VC     1605632
#define OFF_KC     14188544
#define OFF_CZP    26771456
#define OFF_S0     28868608
#define OFF_CPART  29392896
#define OFF_CTXT   31490048
// total 32014336 floats = ~122 MB

// K1: q,k,v projections (+bias), sim = (q.k)*qks[h], L2-normalize k,v
__global__ __launch_bounds__(256) void qkv_kernel(
    const float* __restrict__ x, const float* __restrict__ Wq, const float* __restrict__ bq,
    const float* __restrict__ Wk, const float* __restrict__ bk,
    const float* __restrict__ Wv, const float* __restrict__ bv,
    const float* __restrict__ qks,
    float* __restrict__ qh, float* __restrict__ kn, float* __restrict__ vn,
    float* __restrict__ simg)
{
    __shared__ float xs[64][65];
    __shared__ float wt[64][64];
    int tid = threadIdx.x;
    int hd = blockIdx.y, L0 = blockIdx.x*64;
    int ty = tid>>4, tx = tid&15;
    float acc[3][4][4];
    #pragma unroll
    for (int m=0;m<3;m++) for(int i=0;i<4;i++) for(int j=0;j<4;j++) acc[m][i][j]=0.f;
    const float* Wm[3] = {Wq, Wk, Wv};
    for (int kk=0; kk<Dm; kk+=64) {
        __syncthreads();
        for (int p=0;p<16;p++){ int e=tid+p*256; int rr=e>>6, cc=e&63;
            xs[rr][cc] = x[(L0+rr)*Dm + kk+cc]; }
        #pragma unroll
        for (int m=0;m<3;m++){
            __syncthreads();
            const float* W = Wm[m];
            for (int p=0;p<16;p++){ int e=tid+p*256; int rr=e>>6, cc=e&63;
                wt[rr][cc] = W[(kk+rr)*Dm + hd*64+cc]; }
            __syncthreads();
            for (int ss=0;ss<64;ss++){
                float a0[4], b0[4];
                #pragma unroll
                for(int i=0;i<4;i++) a0[i]=xs[ty*4+i][ss];
                #pragma unroll
                for(int j=0;j<4;j++) b0[j]=wt[ss][tx*4+j];
                #pragma unroll
                for(int i=0;i<4;i++)
                    #pragma unroll
                    for(int j=0;j<4;j++) acc[m][i][j] += a0[i]*b0[j];
            }
        }
    }
    #pragma unroll
    for (int m=0;m<3;m++){
        const float* bias = (m==0)?bq:((m==1)?bk:bv);
        for(int j=0;j<4;j++){ float b=bias[hd*64+tx*4+j];
            for(int i=0;i<4;i++) acc[m][i][j]+=b; }
    }
    __syncthreads();
    float (*red)[17] = (float(*)[17])&xs[0][0];
    float* rowa = &wt[0][0];
    float* rowb = &wt[0][0]+64;
    // sim
    for(int i=0;i<4;i++){ float p=0;
        for(int j=0;j<4;j++) p+=acc[0][i][j]*acc[1][i][j];
        red[ty*4+i][tx]=p; }
    __syncthreads();
    if (tid<64){ float s=0; for(int u=0;u<16;u++) s+=red[tid][u];
        simg[hd*Ll + L0+tid] = s*qks[hd]; }
    __syncthreads();
    // 1/||k||
    for(int i=0;i<4;i++){ float p=0;
        for(int j=0;j<4;j++) p+=acc[1][i][j]*acc[1][i][j];
        red[ty*4+i][tx]=p; }
    __syncthreads();
    if (tid<64){ float s=0; for(int u=0;u<16;u++) s+=red[tid][u];
        rowa[tid] = 1.f/fmaxf(sqrtf(s), 1e-12f); }
    __syncthreads();
    // 1/||v||
    for(int i=0;i<4;i++){ float p=0;
        for(int j=0;j<4;j++) p+=acc[2][i][j]*acc[2][i][j];
        red[ty*4+i][tx]=p; }
    __syncthreads();
    if (tid<64){ float s=0; for(int u=0;u<16;u++) s+=red[tid][u];
        rowb[tid] = 1.f/fmaxf(sqrtf(s), 1e-12f); }
    __syncthreads();
    for(int i=0;i<4;i++){ int r=ty*4+i; int gb=((hd*Ll)+(L0+r))*64 + tx*4;
        float kiv=rowa[r], viv=rowb[r];
        for(int j=0;j<4;j++){ qh[gb+j]=acc[0][i][j]; kn[gb+j]=acc[1][i][j]*kiv; vn[gb+j]=acc[2][i][j]*viv; } }
}

// K2: causal conv via Toeplitz-tiled GEMM. grid (ttile, kf, tensor*8+head)
__global__ __launch_bounds__(256) void conv_kernel(
    const float* __restrict__ vn, const float* __restrict__ kn,
    const float* __restrict__ filt, float* __restrict__ vc, float* __restrict__ kc)
{
    int TT=blockIdx.x, kf=blockIdx.y, z=blockIdx.z;
    int tensor = z>>3, hd = z&7;
    const float* src = tensor ? kn : vn;
    float* dst = tensor ? kc : vc;
    int T0 = TT*64;
    __shared__ float Us[64][64];
    __shared__ float flds[128];
    int tid=threadIdx.x, ty=tid>>4, tx=tid&15;
    float acc[4][4]={};
    for (int ST=0; ST<=TT; ST++){
        int S0 = ST*64;
        __syncthreads();
        for(int p=0;p<16;p++){ int e=tid+p*256; int rr=e>>6, cc=e&63;
            Us[rr][cc] = src[((hd*Ll)+(S0+rr))*64 + cc]; }
        if (tid<128){ int idxf = T0-S0-63+tid;
            flds[tid] = (idxf>=0 && idxf<Ll) ? filt[idxf*KF+kf] : 0.0f; }
        __syncthreads();
        for (int ss=0;ss<64;ss++){
            float a0[4], b0[4];
            #pragma unroll
            for(int i=0;i<4;i++) a0[i]=flds[ty*4+i - ss + 63];
            #pragma unroll
            for(int j=0;j<4;j++) b0[j]=Us[ss][tx*4+j];
            #pragma unroll
            for(int i=0;i<4;i++)
                #pragma unroll
                for(int j=0;j<4;j++) acc[i][j] += a0[i]*b0[j];
        }
    }
    for(int i=0;i<4;i++){ int t=T0+ty*4+i;
        int base = (((hd*Ll)+t)*KF + kf)*64 + tx*4;
        float4 vv = make_float4(acc[i][0],acc[i][1],acc[i][2],acc[i][3]);
        *(float4*)(dst+base) = vv;
    }
}

// K3: logits[t] += rows of (Kc @ (kvs*Wg)^T) . Vc   (atomicAdd per row)
__global__ __launch_bounds__(256) void mkdot_kernel(
    const float* __restrict__ kc, const float* __restrict__ vc,
    const float* __restrict__ kvs, const float* __restrict__ Wg,
    float* __restrict__ logits)
{
    __shared__ float Ms[64][65];
    __shared__ float Ks[64][65];
    __shared__ float red[64][17];
    int tid=threadIdx.x, ty=tid>>4, tx=tid&15;
    int RT=blockIdx.x, hd=blockIdx.y; int R0=RT*64;
    for(int p=0;p<16;p++){ int e=tid+p*256; int d=e>>6, ee=e&63;
        Ms[d][ee] = kvs[(hd*64+d)*64+ee]*Wg[e];
        Ks[d][ee] = kc[(hd*LK + R0+d)*64 + ee]; }
    __syncthreads();
    float a1[4][4]={};
    for(int ee=0;ee<64;ee++){
        float a0[4],b0[4];
        #pragma unroll
        for(int i=0;i<4;i++) a0[i]=Ks[ty*4+i][ee];
        #pragma unroll
        for(int j=0;j<4;j++) b0[j]=Ms[tx*4+j][ee];
        #pragma unroll
        for(int i=0;i<4;i++)
            #pragma unroll
            for(int j=0;j<4;j++) a1[i][j] += a0[i]*b0[j];
    }
    for(int i=0;i<4;i++){
        int row = R0+ty*4+i;
        const float* vp = vc + (hd*LK+row)*64 + tx*4;
        red[ty*4+i][tx] = a1[i][0]*vp[0]+a1[i][1]*vp[1]+a1[i][2]*vp[2]+a1[i][3]*vp[3];
    }
    __syncthreads();
    if (tid<64){ float s=0; for(int u=0;u<16;u++) s+=red[tid][u];
        atomicAdd(&logits[hd*Ll + (R0+tid)/KF], s); }
}

__global__ __launch_bounds__(256) void gates_kernel(
    const float* __restrict__ logits, const float* __restrict__ bg, float* __restrict__ gates)
{
    int i = blockIdx.x*256 + threadIdx.x;
    float lg = logits[i] + bg[0];
    float r = fmaxf(lg, 0.f);
    gates[i] = r*r + EPSf;
}

// K5: online-softmax scan over sim + cumsum(gates) -> factor[l]
__global__ __launch_bounds__(256) void scan_kernel(
    const float* __restrict__ simg, const float* __restrict__ gates, float* __restrict__ factor)
{
    int hd=blockIdx.x, tid=threadIdx.x;
    __shared__ float sm[256], ssc[256], sg[256];
    float simv[4], m_loc[4], s_loc[4], g_loc[4];
    float m = -__builtin_inff(), s = 0.f, g = 0.f;
    for(int e=0;e<4;e++){
        simv[e] = simg[hd*Ll + tid*4 + e];
        float gv = gates[hd*Ll + tid*4 + e];
        float mn = fmaxf(m, simv[e]);
        s = s*__expf(m-mn) + __expf(simv[e]-mn);
        m = mn; g += gv;
        m_loc[e]=m; s_loc[e]=s; g_loc[e]=g;
    }
    sm[tid]=m; ssc[tid]=s; sg[tid]=g;
    __syncthreads();
    for(int off=1; off<256; off<<=1){
        float pm=0, ps=0, pg=0; bool has = (tid>=off);
        if(has){ pm=sm[tid-off]; ps=ssc[tid-off]; pg=sg[tid-off]; }
        __syncthreads();
        if(has){
            float mn=fmaxf(pm, sm[tid]);
            float sn=ps*__expf(pm-mn) + ssc[tid]*__expf(sm[tid]-mn);
            sm[tid]=mn; ssc[tid]=sn; sg[tid]=pg+sg[tid];
        }
        __syncthreads();
    }
    float pm=-__builtin_inff(), ps=0.f, pg=0.f;
    if (tid>0){ pm=sm[tid-1]; ps=ssc[tid-1]; pg=sg[tid-1]; }
    for(int e=0;e<4;e++){
        float mn=fmaxf(pm, m_loc[e]);
        float sn=ps*__expf(pm-mn) + s_loc[e]*__expf(m_loc[e]-mn);
        float gn=pg + g_loc[e];
        float sw = __expf(simv[e]-mn)/(sn+EPSf);
        float silu = sw/(1.f+__expf(-sw));
        factor[hd*Ll + tid*4 + e] = (1.f+silu)/(gn+EPSf);
    }
}

// K6: per-(chunk,quarter) partial sum of gates[t]*Z[t]  (A^T B GEMM over 384 rows)
__global__ __launch_bounds__(256) void chunkz_kernel(
    const float* __restrict__ vc, const float* __restrict__ kc,
    const float* __restrict__ gates, float* __restrict__ czp)
{
    __shared__ float Vs[64][64];
    __shared__ float Ks2[64][64];
    __shared__ float gl[16];
    int tid=threadIdx.x, ty=tid>>4, tx=tid&15;
    int c=blockIdx.x, qq=blockIdx.y, hd=blockIdx.z;
    int tq0 = c*64 + qq*16;
    int RQ0 = tq0*KF;
    if (tid<16) gl[tid] = gates[hd*Ll + tq0 + tid];
    float acc[4][4]={};
    for(int sub=0; sub<6; sub++){
        int RB = RQ0 + sub*64;
        __syncthreads();
        for(int p=0;p<16;p++){ int e=tid+p*256; int rr=e>>6, cc=e&63;
            int row=RB+rr; float g = gl[row/KF - tq0];
            Vs[rr][cc] = vc[(hd*LK+row)*64+cc]*g;
            Ks2[rr][cc]= kc[(hd*LK+row)*64+cc]; }
        __syncthreads();
        for(int rr=0;rr<64;rr++){
            float a0[4],b0[4];
            #pragma unroll
            for(int i=0;i<4;i++) a0[i]=Vs[rr][ty*4+i];
            #pragma unroll
            for(int j=0;j<4;j++) b0[j]=Ks2[rr][tx*4+j];
            #pragma unroll
            for(int i=0;i<4;i++)
                #pragma unroll
                for(int j=0;j<4;j++) acc[i][j] += a0[i]*b0[j];
        }
    }
    int ob = ((hd*16+c)*4+qq)*4096;
    for(int i=0;i<4;i++)
        for(int j=0;j<4;j++)
            czp[ob + (ty*4+i)*64 + tx*4+j] = acc[i][j];
}

// K6b: exclusive prefix over chunks of (sum of 4 quarter partials)
__global__ __launch_bounds__(256) void s0_kernel(
    const float* __restrict__ czp, float* __restrict__ S0)
{
    int hd=blockIdx.x, tid=threadIdx.x;
    float accv[16];
    #pragma unroll
    for(int p=0;p<16;p++) accv[p]=0.f;
    for(int c=0;c<16;c++){
        for(int p=0;p<16;p++){ int idx=tid+p*256;
            S0[(hd*16+c)*4096 + idx] = accv[p];
            int b = ((hd*16+c)*4)*4096 + idx;
            accv[p] += czp[b] + czp[b+4096] + czp[b+2*4096] + czp[b+3*4096];
        }
    }
}

// K7: intra-chunk attention-form partial:  ctxt_p[t,e] = sum_{t' in quarter, t'<=t} g[t'] (q_t.vc_{t',kf}) kc_{t',kf,e}
__global__ __launch_bounds__(256) void phase3_kernel(
    const float* __restrict__ qh, const float* __restrict__ vc, const float* __restrict__ kc,
    const float* __restrict__ gates, float* __restrict__ cpart)
{
    __shared__ float Qs[64][65];
    __shared__ float Ts[64][65];   // VsT then Ks
    __shared__ float A1s[64][65];
    __shared__ float gl[16];
    int tid=threadIdx.x, ty=tid>>4, tx=tid&15;
    int c=blockIdx.x, qq=blockIdx.y, hd=blockIdx.z;
    int T0=c*64, tq0=T0+qq*16, RQ0=tq0*KF;
    for(int p=0;p<16;p++){ int e=tid+p*256; int rr=e>>6, cc=e&63;
        Qs[rr][cc] = qh[(hd*Ll+T0+rr)*64+cc]; }
    if (tid<16) gl[tid]=gates[hd*Ll+tq0+tid];
    float ctx[4][4]={};
    for(int sub=0;sub<6;sub++){
        int RB=RQ0+sub*64;
        __syncthreads();
        for(int p=0;p<16;p++){ int e=tid+p*256; int rr=e&63, cc=e>>6;
            // contiguous global read; transposed LDS write (padded -> conflict-free)
            Ts[ (e&63) ][ 0 ]; }
        // (the real transposed load:)
        for(int p=0;p<16;p++){ int e=tid+p*256; int rr=e>>6, cc=e&63;
            Ts[cc][rr] = vc[(hd*LK+RB+rr)*64+cc]; }
        __syncthreads();
        float a1[4][4]={};
        for(int d=0; d<64; d++){
            float a0[4],b0[4];
            #pragma unroll
            for(int i=0;i<4;i++) a0[i]=Qs[ty*4+i][d];
            #pragma unroll
            for(int j=0;j<4;j++) b0[j]=Ts[d][tx*4+j];
            #pragma unroll
            for(int i=0;i<4;i++)
                #pragma unroll
                for(int j=0;j<4;j++) a1[i][j] += a0[i]*b0[j];
        }
        for(int i=0;i<4;i++){ int t=T0+ty*4+i;
            for(int j=0;j<4;j++){ int row=RB+tx*4+j; int tp=row/KF;
                float v = (t>=tp) ? a1[i][j]*gl[tp-tq0] : 0.f;
                A1s[ty*4+i][tx*4+j]=v; } }
        __syncthreads();
        for(int p=0;p<16;p++){ int e=tid+p*256; int rr=e>>6, cc=e&63;
            Ts[rr][cc] = kc[(hd*LK+RB+rr)*64+cc]; }
        __syncthreads();
        for(int rr=0;rr<64;rr++){
            float a0[4],b0[4];
            #pragma unroll
            for(int i=0;i<4;i++) a0[i]=A1s[ty*4+i][rr];
            #pragma unroll
            for(int j=0;j<4;j++) b0[j]=Ts[rr][tx*4+j];
            #pragma unroll
            for(int i=0;i<4;i++)
                #pragma unroll
                for(int j=0;j<4;j++) ctx[i][j] += a0[i]*b0[j];
        }
    }
    for(int i=0;i<4;i++){ int t=T0+ty*4+i;
        int gb=((qq*8+hd)*Ll + t)*64 + tx*4;
        for(int j=0;j<4;j++) cpart[gb+j]=ctx[i][j];
    }
}

// K8: ctxt[t, hd*64+e] = factor[t] * ( q_t @ S0_chunk + sum_q cpart )
__global__ __launch_bounds__(256) void combine_kernel(
    const float* __restrict__ qh, const float* __restrict__ S0,
    const float* __restrict__ cpart, const float* __restrict__ factor,
    float* __restrict__ ctxt)
{
    __shared__ float Qs[64][65];
    __shared__ float Ss[64][64];
    __shared__ float fl[64];
    int tid=threadIdx.x, ty=tid>>4, tx=tid&15;
    int c=blockIdx.x, hd=blockIdx.y; int T0=c*64;
    for(int p=0;p<16;p++){ int e=tid+p*256; int rr=e>>6, cc=e&63;
        Qs[rr][cc]=qh[(hd*Ll+T0+rr)*64+cc];
        Ss[rr][cc]=S0[(hd*16+c)*4096 + e]; }
    if(tid<64) fl[tid]=factor[hd*Ll+T0+tid];
    __syncthreads();
    float acc[4][4]={};
    for(int d=0;d<64;d++){
        float a0[4],b0[4];
        #pragma unroll
        for(int i=0;i<4;i++) a0[i]=Qs[ty*4+i][d];
        #pragma unroll
        for(int j=0;j<4;j++) b0[j]=Ss[d][tx*4+j];
        #pragma unroll
        for(int i=0;i<4;i++)
            #pragma unroll
            for(int j=0;j<4;j++) acc[i][j]+=a0[i]*b0[j];
    }
    for(int i=0;i<4;i++){ int t=T0+ty*4+i; float f=fl[ty*4+i];
        for(int j=0;j<4;j++){ float v=acc[i][j];
            for(int q=0;q<4;q++) v += cpart[((q*8+hd)*Ll + t)*64 + tx*4+j];
            ctxt[t*Dm + hd*64 + tx*4+j] = v*f; } }
}

// K9: out = ctxt @ Wo + bo
__global__ __launch_bounds__(256) void outproj_kernel(
    const float* __restrict__ ctxt, const float* __restrict__ Wo,
    const float* __restrict__ bo, float* __restrict__ out)
{
    __shared__ float Cs[64][65];
    __shared__ float Ws2[64][64];
    int tid=threadIdx.x, ty=tid>>4, tx=tid&15;
    int L0=blockIdx.x*64, N0=blockIdx.y*64;
    float acc[4][4]={};
    for(int kk=0;kk<Dm;kk+=64){
        __syncthreads();
        for(int p=0;p<16;p++){ int e=tid+p*256; int rr=e>>6, cc=e&63;
            Cs[rr][cc]=ctxt[(L0+rr)*Dm + kk+cc];
            Ws2[rr][cc]=Wo[(kk+rr)*Dm + N0+cc]; }
        __syncthreads();
        for(int ss=0;ss<64;ss++){
            float a0[4],b0[4];
            #pragma unroll
            for(int i=0;i<4;i++) a0[i]=Cs[ty*4+i][ss];
            #pragma unroll
            for(int j=0;j<4;j++) b0[j]=Ws2[ss][tx*4+j];
            #pragma unroll
            for(int i=0;i<4;i++)
                #pragma unroll
                for(int j=0;j<4;j++) acc[i][j]+=a0[i]*b0[j];
        }
    }
    for(int j=0;j<4;j++){ float b=bo[N0+tx*4+j];
        for(int i=0;i<4;i++)
            out[(L0+ty*4+i)*Dm + N0+tx*4+j] = acc[i][j]+b;
    }
}

extern "C" void kernel_launch(void* const* d_in, const int* in_sizes, int n_in,
                              void* d_out, int out_size, void* d_ws, size_t ws_size,
                              hipStream_t stream)
{
    (void)in_sizes; (void)n_in; (void)out_size; (void)ws_size;
    const float* x   =(const float*)d_in[0];
    const float* Wq  =(const float*)d_in[1];
    const float* bq  =(const float*)d_in[2];
    const float* Wk  =(const float*)d_in[3];
    const float* bk  =(const float*)d_in[4];
    const float* Wv  =(const float*)d_in[5];
    const float* bv  =(const float*)d_in[6];
    const float* Wo  =(const float*)d_in[7];
    const float* bo  =(const float*)d_in[8];
    const float* Wg  =(const float*)d_in[9];
    const float* bg  =(const float*)d_in[10];
    const float* kvs =(const float*)d_in[11];
    const float* qks =(const float*)d_in[12];
    const float* filt=(const float*)d_in[13];
    float* ws = (float*)d_ws;
    float* qh    = ws+OFF_QH;
    float* kn    = ws+OFF_KN;
    float* vn    = ws+OFF_VN;
    float* simg  = ws+OFF_SIM;
    float* logits= ws+OFF_LOGITS;
    float* gates = ws+OFF_GATES;
    float* factor= ws+OFF_FACTOR;
    float* vc    = ws+OFF_VC;
    float* kc    = ws+OFF_KC;
    float* czp   = ws+OFF_CZP;
    float* S0v   = ws+OFF_S0;
    float* cpart = ws+OFF_CPART;
    float* ctxt  = ws+OFF_CTXT;
    float* out   = (float*)d_out;

    hipMemsetAsync(logits, 0, Hh*Ll*sizeof(float), stream);
    qkv_kernel   <<<dim3(16,8),   256,0,stream>>>(x,Wq,bq,Wk,bk,Wv,bv,qks,qh,kn,vn,simg);
    conv_kernel  <<<dim3(16,24,16),256,0,stream>>>(vn,kn,filt,vc,kc);
    mkdot_kernel <<<dim3(384,8),  256,0,stream>>>(kc,vc,kvs,Wg,logits);
    gates_kernel <<<dim3(32),     256,0,stream>>>(logits,bg,gates);
    scan_kernel  <<<dim3(8),      256,0,stream>>>(simg,gates,factor);
    chunkz_kernel<<<dim3(16,4,8), 256,0,stream>>>(vc,kc,gates,czp);
    s0_kernel    <<<dim3(8),      256,0,stream>>>(czp,S0v);
    phase3_kernel<<<dim3(16,4,8), 256,0,stream>>>(qh,vc,kc,gates,cpart);
    combine_kernel<<<dim3(16,8),  256,0,stream>>>(qh,S0v,cpart,factor,ctxt);
    outproj_kernel<<<dim3(16,8),  256,0,stream>>>(ctxt,Wo,bo,out);
}

// Round 2
// 522.369 us; speedup vs baseline: 1.8895x; 1.8895x over previous
//
#include <hip/hip_runtime.h>
#include <math.h>

#define Hh 8
#define Ll 1024
#define KF 24
#define Dm 512
#define EPSf 1e-5f
#define LK (Ll*KF)   // 24576 rows (t,kf) per head

typedef __attribute__((ext_vector_type(8))) short short8;
typedef __attribute__((ext_vector_type(4))) float f32x4;

// ---- workspace offsets (floats) ----
#define OFF_QH     0
#define OFF_KN     524288
#define OFF_VN     1048576
#define OFF_SIM    1572864
#define OFF_LOGITS 1581056
#define OFF_GATES  1589248
#define OFF_FACTOR 1597440
#define OFF_VC     1605632
#define OFF_KC     14188544
#define OFF_CZP    26771456
#define OFF_S0     28868608
#define OFF_CPART  29392896
#define OFF_CTXT   31490048
// Fpk/Upk (bf16) overlay the CZP region: conv uses them before chunkz writes czp.
// Fpk: 24*17*4096 ushort = 1,671,168 ushort = 835,584 floats
// Upk: 2*8*16*4096 ushort = 2,097,152 ushort... (2*8*16*4096 = 2,097,152? = 1,048,576 floats/2) -> 524,288 floats
#define OFF_FPK_F  26771456
#define OFF_UPK_F  (26771456+835584)

__device__ inline unsigned short f2bf(float x){
    unsigned int u = __float_as_uint(x);
    unsigned int r = (u + 0x7fffu + ((u>>16)&1u)) >> 16;
    return (unsigned short)r;
}

// K1: q,k,v projections (+bias), sim = (q.k)*qks[h], L2-normalize k,v
__global__ __launch_bounds__(256) void qkv_kernel(
    const float* __restrict__ x, const float* __restrict__ Wq, const float* __restrict__ bq,
    const float* __restrict__ Wk, const float* __restrict__ bk,
    const float* __restrict__ Wv, const float* __restrict__ bv,
    const float* __restrict__ qks,
    float* __restrict__ qh, float* __restrict__ kn, float* __restrict__ vn,
    float* __restrict__ simg)
{
    __shared__ float xs[64][65];
    __shared__ float wt[64][64];
    int tid = threadIdx.x;
    int hd = blockIdx.y, L0 = blockIdx.x*64;
    int ty = tid>>4, tx = tid&15;
    float acc[3][4][4];
    #pragma unroll
    for (int m=0;m<3;m++) for(int i=0;i<4;i++) for(int j=0;j<4;j++) acc[m][i][j]=0.f;
    const float* Wm[3] = {Wq, Wk, Wv};
    for (int kk=0; kk<Dm; kk+=64) {
        __syncthreads();
        for (int p=0;p<16;p++){ int e=tid+p*256; int rr=e>>6, cc=e&63;
            xs[rr][cc] = x[(L0+rr)*Dm + kk+cc]; }
        #pragma unroll
        for (int m=0;m<3;m++){
            __syncthreads();
            const float* W = Wm[m];
            for (int p=0;p<16;p++){ int e=tid+p*256; int rr=e>>6, cc=e&63;
                wt[rr][cc] = W[(kk+rr)*Dm + hd*64+cc]; }
            __syncthreads();
            for (int ss=0;ss<64;ss++){
                float a0[4], b0[4];
                #pragma unroll
                for(int i=0;i<4;i++) a0[i]=xs[ty*4+i][ss];
                #pragma unroll
                for(int j=0;j<4;j++) b0[j]=wt[ss][tx*4+j];
                #pragma unroll
                for(int i=0;i<4;i++)
                    #pragma unroll
                    for(int j=0;j<4;j++) acc[m][i][j] += a0[i]*b0[j];
            }
        }
    }
    #pragma unroll
    for (int m=0;m<3;m++){
        const float* bias = (m==0)?bq:((m==1)?bk:bv);
        for(int j=0;j<4;j++){ float b=bias[hd*64+tx*4+j];
            for(int i=0;i<4;i++) acc[m][i][j]+=b; }
    }
    __syncthreads();
    float (*red)[17] = (float(*)[17])&xs[0][0];
    float* rowa = &wt[0][0];
    float* rowb = &wt[0][0]+64;
    // sim
    for(int i=0;i<4;i++){ float p=0;
        for(int j=0;j<4;j++) p+=acc[0][i][j]*acc[1][i][j];
        red[ty*4+i][tx]=p; }
    __syncthreads();
    if (tid<64){ float s=0; for(int u=0;u<16;u++) s+=red[tid][u];
        simg[hd*Ll + L0+tid] = s*qks[hd]; }
    __syncthreads();
    // 1/||k||
    for(int i=0;i<4;i++){ float p=0;
        for(int j=0;j<4;j++) p+=acc[1][i][j]*acc[1][i][j];
        red[ty*4+i][tx]=p; }
    __syncthreads();
    if (tid<64){ float s=0; for(int u=0;u<16;u++) s+=red[tid][u];
        rowa[tid] = 1.f/fmaxf(sqrtf(s), 1e-12f); }
    __syncthreads();
    // 1/||v||
    for(int i=0;i<4;i++){ float p=0;
        for(int j=0;j<4;j++) p+=acc[2][i][j]*acc[2][i][j];
        red[ty*4+i][tx]=p; }
    __syncthreads();
    if (tid<64){ float s=0; for(int u=0;u<16;u++) s+=red[tid][u];
        rowb[tid] = 1.f/fmaxf(sqrtf(s), 1e-12f); }
    __syncthreads();
    for(int i=0;i<4;i++){ int r=ty*4+i; int gb=((hd*Ll)+(L0+r))*64 + tx*4;
        float kiv=rowa[r], viv=rowb[r];
        for(int j=0;j<4;j++){ qh[gb+j]=acc[0][i][j]; kn[gb+j]=acc[1][i][j]*kiv; vn[gb+j]=acc[2][i][j]*viv; } }
}

// K2a: precompute Toeplitz filter blocks in bf16, MFMA-A-fragment order.
// Fpk[kf][dslot(17)][mb(4)][ks(2)][lane(64)][j(8)], value = F[(dslot-1)*64 + m - k, kf]
// with m = mb*16 + (lane&15), k = ks*32 + (lane>>4)*8 + j; 0 outside [0,Ll).
__global__ __launch_bounds__(256) void fpk_kernel(
    const float* __restrict__ filt, unsigned short* __restrict__ Fpk)
{
    int kf = blockIdx.x, dslot = blockIdx.y, tid = threadIdx.x;
    unsigned short* dst = Fpk + (kf*17 + dslot)*4096;
    for (int p=0;p<16;p++){
        int e = tid + p*256;
        int j = e&7, lane = (e>>3)&63, ks = (e>>9)&1, mb = (e>>10)&3;
        int m = mb*16 + (lane&15);
        int k = ks*32 + (lane>>4)*8 + j;
        int fidx = (dslot-1)*64 + m - k;
        float v = (fidx>=0 && fidx<Ll) ? filt[fidx*KF + kf] : 0.f;
        dst[e] = f2bf(v);
    }
}

// K2b: pack normalized k/v into bf16 MFMA-B-fragment order.
// Upk[z(16)][ST(16)][ks(2)][nb(4)][lane(64)][j(8)], value = U[S0+ks*32+(lane>>4)*8+j][nb*16+(lane&15)]
__global__ __launch_bounds__(256) void upk_kernel(
    const float* __restrict__ vn, const float* __restrict__ kn,
    unsigned short* __restrict__ Upk)
{
    int ST = blockIdx.x, hd = blockIdx.y, tensor = blockIdx.z;
    int z = tensor*8 + hd, tid = threadIdx.x;
    const float* src = tensor ? kn : vn;
    unsigned short* dst = Upk + (z*16 + ST)*4096;
    for (int fi=0; fi<2; fi++){
        int f = tid + fi*256;            // frag index 0..511
        int lane = f&63, nb = (f>>6)&3, ks = f>>8;
        int d = nb*16 + (lane&15);
        int s0 = ST*64 + ks*32 + ((lane>>4)&3)*8;
        #pragma unroll
        for (int j=0;j<8;j++){
            dst[f*8 + j] = f2bf(src[(hd*Ll + s0 + j)*64 + d]);
        }
    }
}

// K2: causal conv as block-triangular bf16 MFMA GEMM.
// grid (TT 0..7 [128-row t-tiles], kf 0..23, z = tensor*8+hd 0..15), 256 thr = 4 waves.
// wave wid: t-half hf = wid>>1, m-blocks mb0=(wid&1)*2 .. +1 (rows wid*32..wid*32+31).
// A/B fragments loaded straight from global (fragment-order, coalesced dwordx4) — no LDS.
__global__ __launch_bounds__(256) void convm_kernel(
    const unsigned short* __restrict__ Fpk, const unsigned short* __restrict__ Upk,
    float* __restrict__ vc, float* __restrict__ kc)
{
    int TT = blockIdx.x, kf = blockIdx.y, z = blockIdx.z;
    int tensor = z>>3, hd = z&7;
    float* dst = tensor ? kc : vc;
    int tid = threadIdx.x, wid = tid>>6, lane = tid&63;
    int hf = wid>>1, mb0 = (wid&1)*2;
    const unsigned short* Fkf = Fpk + kf*17*4096;
    const unsigned short* Uz  = Upk + z*16*4096;

    f32x4 acc[2][4];
    #pragma unroll
    for (int i=0;i<2;i++)
        #pragma unroll
        for (int nb=0;nb<4;nb++) acc[i][nb] = (f32x4){0.f,0.f,0.f,0.f};

    int STend = 2*TT + 2;
    for (int ST=0; ST<STend; ST++){
        int dslot = 2*TT + hf - ST + 1;   // in [0,16]; 0 = all-zero block
        const unsigned short* Fb = Fkf + dslot*4096;
        const unsigned short* Ub = Uz + ST*4096;
        short8 a[2][2], b[2][4];
        #pragma unroll
        for (int i=0;i<2;i++)
            #pragma unroll
            for (int ks=0;ks<2;ks++)
                a[i][ks] = *(const short8*)(Fb + ((mb0+i)*1024 + ks*512 + lane*8));
        #pragma unroll
        for (int ks=0;ks<2;ks++)
            #pragma unroll
            for (int nb=0;nb<4;nb++)
                b[ks][nb] = *(const short8*)(Ub + (ks*2048 + nb*512 + lane*8));
        #pragma unroll
        for (int ks=0;ks<2;ks++)
            #pragma unroll
            for (int i=0;i<2;i++)
                #pragma unroll
                for (int nb=0;nb<4;nb++)
                    acc[i][nb] = __builtin_amdgcn_mfma_f32_16x16x32_bf16(
                        a[i][ks], b[ks][nb], acc[i][nb], 0, 0, 0);
    }
    // C layout: col = lane&15 (d), row = (lane>>4)*4 + r (t within 16-block)
    int quad = lane>>4, col = lane&15;
    #pragma unroll
    for (int i=0;i<2;i++){
        int tbase = TT*128 + hf*64 + (mb0+i)*16 + quad*4;
        #pragma unroll
        for (int nb=0;nb<4;nb++){
            int d = nb*16 + col;
            #pragma unroll
            for (int r=0;r<4;r++){
                dst[((hd*Ll + tbase + r)*KF + kf)*64 + d] = acc[i][nb][r];
            }
        }
    }
}

// K3: logits[t] += rows of (Kc @ (kvs*Wg)^T) . Vc   (atomicAdd per row)
__global__ __launch_bounds__(256) void mkdot_kernel(
    const float* __restrict__ kc, const float* __restrict__ vc,
    const float* __restrict__ kvs, const float* __restrict__ Wg,
    float* __restrict__ logits)
{
    __shared__ float Ms[64][65];
    __shared__ float Ks[64][65];
    __shared__ float red[64][17];
    int tid=threadIdx.x, ty=tid>>4, tx=tid&15;
    int RT=blockIdx.x, hd=blockIdx.y; int R0=RT*64;
    for(int p=0;p<16;p++){ int e=tid+p*256; int d=e>>6, ee=e&63;
        Ms[d][ee] = kvs[(hd*64+d)*64+ee]*Wg[e];
        Ks[d][ee] = kc[(hd*LK + R0+d)*64 + ee]; }
    __syncthreads();
    float a1[4][4]={};
    for(int ee=0;ee<64;ee++){
        float a0[4],b0[4];
        #pragma unroll
        for(int i=0;i<4;i++) a0[i]=Ks[ty*4+i][ee];
        #pragma unroll
        for(int j=0;j<4;j++) b0[j]=Ms[tx*4+j][ee];
        #pragma unroll
        for(int i=0;i<4;i++)
            #pragma unroll
            for(int j=0;j<4;j++) a1[i][j] += a0[i]*b0[j];
    }
    for(int i=0;i<4;i++){
        int row = R0+ty*4+i;
        const float* vp = vc + (hd*LK+row)*64 + tx*4;
        red[ty*4+i][tx] = a1[i][0]*vp[0]+a1[i][1]*vp[1]+a1[i][2]*vp[2]+a1[i][3]*vp[3];
    }
    __syncthreads();
    if (tid<64){ float s=0; for(int u=0;u<16;u++) s+=red[tid][u];
        atomicAdd(&logits[hd*Ll + (R0+tid)/KF], s); }
}

__global__ __launch_bounds__(256) void gates_kernel(
    const float* __restrict__ logits, const float* __restrict__ bg, float* __restrict__ gates)
{
    int i = blockIdx.x*256 + threadIdx.x;
    float lg = logits[i] + bg[0];
    float r = fmaxf(lg, 0.f);
    gates[i] = r*r + EPSf;
}

// K5: online-softmax scan over sim + cumsum(gates) -> factor[l]
__global__ __launch_bounds__(256) void scan_kernel(
    const float* __restrict__ simg, const float* __restrict__ gates, float* __restrict__ factor)
{
    int hd=blockIdx.x, tid=threadIdx.x;
    __shared__ float sm[256], ssc[256], sg[256];
    float simv[4], m_loc[4], s_loc[4], g_loc[4];
    float m = -__builtin_inff(), s = 0.f, g = 0.f;
    for(int e=0;e<4;e++){
        simv[e] = simg[hd*Ll + tid*4 + e];
        float gv = gates[hd*Ll + tid*4 + e];
        float mn = fmaxf(m, simv[e]);
        s = s*__expf(m-mn) + __expf(simv[e]-mn);
        m = mn; g += gv;
        m_loc[e]=m; s_loc[e]=s; g_loc[e]=g;
    }
    sm[tid]=m; ssc[tid]=s; sg[tid]=g;
    __syncthreads();
    for(int off=1; off<256; off<<=1){
        float pm=0, ps=0, pg=0; bool has = (tid>=off);
        if(has){ pm=sm[tid-off]; ps=ssc[tid-off]; pg=sg[tid-off]; }
        __syncthreads();
        if(has){
            float mn=fmaxf(pm, sm[tid]);
            float sn=ps*__expf(pm-mn) + ssc[tid]*__expf(sm[tid]-mn);
            sm[tid]=mn; ssc[tid]=sn; sg[tid]=pg+sg[tid];
        }
        __syncthreads();
    }
    float pm=-__builtin_inff(), ps=0.f, pg=0.f;
    if (tid>0){ pm=sm[tid-1]; ps=ssc[tid-1]; pg=sg[tid-1]; }
    for(int e=0;e<4;e++){
        float mn=fmaxf(pm, m_loc[e]);
        float sn=ps*__expf(pm-mn) + s_loc[e]*__expf(m_loc[e]-mn);
        float gn=pg + g_loc[e];
        float sw = __expf(simv[e]-mn)/(sn+EPSf);
        float silu = sw/(1.f+__expf(-sw));
        factor[hd*Ll + tid*4 + e] = (1.f+silu)/(gn+EPSf);
    }
}

// K6: per-(chunk,quarter) partial sum of gates[t]*Z[t]  (A^T B GEMM over 384 rows)
__global__ __launch_bounds__(256) void chunkz_kernel(
    const float* __restrict__ vc, const float* __restrict__ kc,
    const float* __restrict__ gates, float* __restrict__ czp)
{
    __shared__ float Vs[64][64];
    __shared__ float Ks2[64][64];
    __shared__ float gl[16];
    int tid=threadIdx.x, ty=tid>>4, tx=tid&15;
    int c=blockIdx.x, qq=blockIdx.y, hd=blockIdx.z;
    int tq0 = c*64 + qq*16;
    int RQ0 = tq0*KF;
    if (tid<16) gl[tid] = gates[hd*Ll + tq0 + tid];
    float acc[4][4]={};
    for(int sub=0; sub<6; sub++){
        int RB = RQ0 + sub*64;
        __syncthreads();
        for(int p=0;p<16;p++){ int e=tid+p*256; int rr=e>>6, cc=e&63;
            int row=RB+rr; float g = gl[row/KF - tq0];
            Vs[rr][cc] = vc[(hd*LK+row)*64+cc]*g;
            Ks2[rr][cc]= kc[(hd*LK+row)*64+cc]; }
        __syncthreads();
        for(int rr=0;rr<64;rr++){
            float a0[4],b0[4];
            #pragma unroll
            for(int i=0;i<4;i++) a0[i]=Vs[rr][ty*4+i];
            #pragma unroll
            for(int j=0;j<4;j++) b0[j]=Ks2[rr][tx*4+j];
            #pragma unroll
            for(int i=0;i<4;i++)
                #pragma unroll
                for(int j=0;j<4;j++) acc[i][j] += a0[i]*b0[j];
        }
    }
    int ob = ((hd*16+c)*4+qq)*4096;
    for(int i=0;i<4;i++)
        for(int j=0;j<4;j++)
            czp[ob + (ty*4+i)*64 + tx*4+j] = acc[i][j];
}

// K6b: exclusive prefix over chunks of (sum of 4 quarter partials)
__global__ __launch_bounds__(256) void s0_kernel(
    const float* __restrict__ czp, float* __restrict__ S0)
{
    int hd=blockIdx.x, tid=threadIdx.x;
    float accv[16];
    #pragma unroll
    for(int p=0;p<16;p++) accv[p]=0.f;
    for(int c=0;c<16;c++){
        for(int p=0;p<16;p++){ int idx=tid+p*256;
            S0[(hd*16+c)*4096 + idx] = accv[p];
            int b = ((hd*16+c)*4)*4096 + idx;
            accv[p] += czp[b] + czp[b+4096] + czp[b+2*4096] + czp[b+3*4096];
        }
    }
}

// K7: intra-chunk attention-form partial
__global__ __launch_bounds__(256) void phase3_kernel(
    const float* __restrict__ qh, const float* __restrict__ vc, const float* __restrict__ kc,
    const float* __restrict__ gates, float* __restrict__ cpart)
{
    __shared__ float Qs[64][65];
    __shared__ float Ts[64][65];   // VsT then Ks
    __shared__ float A1s[64][65];
    __shared__ float gl[16];
    int tid=threadIdx.x, ty=tid>>4, tx=tid&15;
    int c=blockIdx.x, qq=blockIdx.y, hd=blockIdx.z;
    int T0=c*64, tq0=T0+qq*16, RQ0=tq0*KF;
    for(int p=0;p<16;p++){ int e=tid+p*256; int rr=e>>6, cc=e&63;
        Qs[rr][cc] = qh[(hd*Ll+T0+rr)*64+cc]; }
    if (tid<16) gl[tid]=gates[hd*Ll+tq0+tid];
    float ctx[4][4]={};
    for(int sub=0;sub<6;sub++){
        int RB=RQ0+sub*64;
        __syncthreads();
        for(int p=0;p<16;p++){ int e=tid+p*256; int rr=e>>6, cc=e&63;
            Ts[cc][rr] = vc[(hd*LK+RB+rr)*64+cc]; }
        __syncthreads();
        float a1[4][4]={};
        for(int d=0; d<64; d++){
            float a0[4],b0[4];
            #pragma unroll
            for(int i=0;i<4;i++) a0[i]=Qs[ty*4+i][d];
            #pragma unroll
            for(int j=0;j<4;j++) b0[j]=Ts[d][tx*4+j];
            #pragma unroll
            for(int i=0;i<4;i++)
                #pragma unroll
                for(int j=0;j<4;j++) a1[i][j] += a0[i]*b0[j];
        }
        for(int i=0;i<4;i++){ int t=T0+ty*4+i;
            for(int j=0;j<4;j++){ int row=RB+tx*4+j; int tp=row/KF;
                float v = (t>=tp) ? a1[i][j]*gl[tp-tq0] : 0.f;
                A1s[ty*4+i][tx*4+j]=v; } }
        __syncthreads();
        for(int p=0;p<16;p++){ int e=tid+p*256; int rr=e>>6, cc=e&63;
            Ts[rr][cc] = kc[(hd*LK+RB+rr)*64+cc]; }
        __syncthreads();
        for(int rr=0;rr<64;rr++){
            float a0[4],b0[4];
            #pragma unroll
            for(int i=0;i<4;i++) a0[i]=A1s[ty*4+i][rr];
            #pragma unroll
            for(int j=0;j<4;j++) b0[j]=Ts[rr][tx*4+j];
            #pragma unroll
            for(int i=0;i<4;i++)
                #pragma unroll
                for(int j=0;j<4;j++) ctx[i][j] += a0[i]*b0[j];
        }
    }
    for(int i=0;i<4;i++){ int t=T0+ty*4+i;
        int gb=((qq*8+hd)*Ll + t)*64 + tx*4;
        for(int j=0;j<4;j++) cpart[gb+j]=ctx[i][j];
    }
}

// K8: ctxt[t, hd*64+e] = factor[t] * ( q_t @ S0_chunk + sum_q cpart )
__global__ __launch_bounds__(256) void combine_kernel(
    const float* __restrict__ qh, const float* __restrict__ S0,
    const float* __restrict__ cpart, const float* __restrict__ factor,
    float* __restrict__ ctxt)
{
    __shared__ float Qs[64][65];
    __shared__ float Ss[64][64];
    __shared__ float fl[64];
    int tid=threadIdx.x, ty=tid>>4, tx=tid&15;
    int c=blockIdx.x, hd=blockIdx.y; int T0=c*64;
    for(int p=0;p<16;p++){ int e=tid+p*256; int rr=e>>6, cc=e&63;
        Qs[rr][cc]=qh[(hd*Ll+T0+rr)*64+cc];
        Ss[rr][cc]=S0[(hd*16+c)*4096 + e]; }
    if(tid<64) fl[tid]=factor[hd*Ll+T0+tid];
    __syncthreads();
    float acc[4][4]={};
    for(int d=0;d<64;d++){
        float a0[4],b0[4];
        #pragma unroll
        for(int i=0;i<4;i++) a0[i]=Qs[ty*4+i][d];
        #pragma unroll
        for(int j=0;j<4;j++) b0[j]=Ss[d][tx*4+j];
        #pragma unroll
        for(int i=0;i<4;i++)
            #pragma unroll
            for(int j=0;j<4;j++) acc[i][j]+=a0[i]*b0[j];
    }
    for(int i=0;i<4;i++){ int t=T0+ty*4+i; float f=fl[ty*4+i];
        for(int j=0;j<4;j++){ float v=acc[i][j];
            for(int q=0;q<4;q++) v += cpart[((q*8+hd)*Ll + t)*64 + tx*4+j];
            ctxt[t*Dm + hd*64 + tx*4+j] = v*f; } }
}

// K9: out = ctxt @ Wo + bo
__global__ __launch_bounds__(256) void outproj_kernel(
    const float* __restrict__ ctxt, const float* __restrict__ Wo,
    const float* __restrict__ bo, float* __restrict__ out)
{
    __shared__ float Cs[64][65];
    __shared__ float Ws2[64][64];
    int tid=threadIdx.x, ty=tid>>4, tx=tid&15;
    int L0=blockIdx.x*64, N0=blockIdx.y*64;
    float acc[4][4]={};
    for(int kk=0;kk<Dm;kk+=64){
        __syncthreads();
        for(int p=0;p<16;p++){ int e=tid+p*256; int rr=e>>6, cc=e&63;
            Cs[rr][cc]=ctxt[(L0+rr)*Dm + kk+cc];
            Ws2[rr][cc]=Wo[(kk+rr)*Dm + N0+cc]; }
        __syncthreads();
        for(int ss=0;ss<64;ss++){
            float a0[4],b0[4];
            #pragma unroll
            for(int i=0;i<4;i++) a0[i]=Cs[ty*4+i][ss];
            #pragma unroll
            for(int j=0;j<4;j++) b0[j]=Ws2[ss][tx*4+j];
            #pragma unroll
            for(int i=0;i<4;i++)
                #pragma unroll
                for(int j=0;j<4;j++) acc[i][j]+=a0[i]*b0[j];
        }
    }
    for(int j=0;j<4;j++){ float b=bo[N0+tx*4+j];
        for(int i=0;i<4;i++)
            out[(L0+ty*4+i)*Dm + N0+tx*4+j] = acc[i][j]+b;
    }
}

extern "C" void kernel_launch(void* const* d_in, const int* in_sizes, int n_in,
                              void* d_out, int out_size, void* d_ws, size_t ws_size,
                              hipStream_t stream)
{
    (void)in_sizes; (void)n_in; (void)out_size; (void)ws_size;
    const float* x   =(const float*)d_in[0];
    const float* Wq  =(const float*)d_in[1];
    const float* bq  =(const float*)d_in[2];
    const float* Wk  =(const float*)d_in[3];
    const float* bk  =(const float*)d_in[4];
    const float* Wv  =(const float*)d_in[5];
    const float* bv  =(const float*)d_in[6];
    const float* Wo  =(const float*)d_in[7];
    const float* bo  =(const float*)d_in[8];
    const float* Wg  =(const float*)d_in[9];
    const float* bg  =(const float*)d_in[10];
    const float* kvs =(const float*)d_in[11];
    const float* qks =(const float*)d_in[12];
    const float* filt=(const float*)d_in[13];
    float* ws = (float*)d_ws;
    float* qh    = ws+OFF_QH;
    float* kn    = ws+OFF_KN;
    float* vn    = ws+OFF_VN;
    float* simg  = ws+OFF_SIM;
    float* logits= ws+OFF_LOGITS;
    float* gates = ws+OFF_GATES;
    float* factor= ws+OFF_FACTOR;
    float* vc    = ws+OFF_VC;
    float* kc    = ws+OFF_KC;
    float* czp   = ws+OFF_CZP;
    float* S0v   = ws+OFF_S0;
    float* cpart = ws+OFF_CPART;
    float* ctxt  = ws+OFF_CTXT;
    unsigned short* Fpk = (unsigned short*)(ws + OFF_FPK_F);
    unsigned short* Upk = (unsigned short*)(ws + OFF_UPK_F);
    float* out   = (float*)d_out;

    hipMemsetAsync(logits, 0, Hh*Ll*sizeof(float), stream);
    qkv_kernel   <<<dim3(16,8),   256,0,stream>>>(x,Wq,bq,Wk,bk,Wv,bv,qks,qh,kn,vn,simg);
    fpk_kernel   <<<dim3(24,17),  256,0,stream>>>(filt,Fpk);
    upk_kernel   <<<dim3(16,8,2), 256,0,stream>>>(vn,kn,Upk);
    convm_kernel <<<dim3(8,24,16),256,0,stream>>>(Fpk,Upk,vc,kc);
    mkdot_kernel <<<dim3(384,8),  256,0,stream>>>(kc,vc,kvs,Wg,logits);
    gates_kernel <<<dim3(32),     256,0,stream>>>(logits,bg,gates);
    scan_kernel  <<<dim3(8),      256,0,stream>>>(simg,gates,factor);
    chunkz_kernel<<<dim3(16,4,8), 256,0,stream>>>(vc,kc,gates,czp);
    s0_kernel    <<<dim3(8),      256,0,stream>>>(czp,S0v);
    phase3_kernel<<<dim3(16,4,8), 256,0,stream>>>(qh,vc,kc,gates,cpart);
    combine_kernel<<<dim3(16,8),  256,0,stream>>>(qh,S0v,cpart,factor,ctxt);
    outproj_kernel<<<dim3(16,8),  256,0,stream>>>(ctxt,Wo,bo,out);
}

// Round 3
// 415.945 us; speedup vs baseline: 2.3729x; 1.2559x over previous
//
#include <hip/hip_runtime.h>
#include <math.h>

#define Hh 8
#define Ll 1024
#define KF 24
#define Dm 512
#define EPSf 1e-5f
#define LK (Ll*KF)   // 24576 rows (t,kf) per head

typedef __attribute__((ext_vector_type(8))) short short8;
typedef __attribute__((ext_vector_type(4))) float f32x4;

// ---- workspace offsets (floats) ----
#define OFF_QH     0
#define OFF_KN     524288
#define OFF_VN     1048576
#define OFF_SIM    1572864
#define OFF_LOGITS 1581056
#define OFF_GATES  1589248
#define OFF_FACTOR 1597440
#define OFF_VC     1605632
#define OFF_KC     14188544
#define OFF_CZP    26771456
#define OFF_S0     28868608
#define OFF_CPART  29392896
#define OFF_CTXT   31490048
// bf16 pack buffers overlay the CZP region (consumed before chunkz writes czp):
// Fpk 835,584 fl | Upk 524,288 fl | Apk 262,144 fl | Bpk 393,216 fl -> end 28,786,688 <= OFF_S0
#define OFF_FPK_F  26771456
#define OFF_UPK_F  27607040
#define OFF_APK_F  28131328
#define OFF_BPK_F  28393472

__device__ inline unsigned short f2bf(float x){
    unsigned int u = __float_as_uint(x);
    unsigned int r = (u + 0x7fffu + ((u>>16)&1u)) >> 16;
    return (unsigned short)r;
}

// K1a: pack x [1024x512] into bf16 MFMA-A fragment order.
// Apk[mb(64)][ks(16)][lane(64)][j(8)] = x[mb*16+(lane&15)][ks*32+((lane>>4)&3)*8+j]
__global__ __launch_bounds__(256) void xpk_kernel(
    const float* __restrict__ x, unsigned short* __restrict__ Apk)
{
    int mb = blockIdx.x, tid = threadIdx.x;
    for (int ks=0; ks<16; ks++){
        #pragma unroll
        for (int p=0;p<2;p++){
            int e = tid + p*256;
            int lane = e>>3, j = e&7;
            int m = mb*16 + (lane&15);
            int k = ks*32 + ((lane>>4)&3)*8 + j;
            Apk[(mb*16+ks)*512 + e] = f2bf(x[m*Dm + k]);
        }
    }
}

// K1b: pack [Wq|Wk|Wv] (each [512x512]) into bf16 MFMA-B fragment order over N=1536.
// Bpk[nb(96)][ks(16)][lane(64)][j(8)] = W_mm[ks*32+((lane>>4)&3)*8+j][col]
__global__ __launch_bounds__(256) void wpk_kernel(
    const float* __restrict__ Wq, const float* __restrict__ Wk, const float* __restrict__ Wv,
    unsigned short* __restrict__ Bpk)
{
    int nb = blockIdx.x, tid = threadIdx.x;
    int n0 = nb*16;
    int mm = n0>>9;
    const float* W = (mm==0)?Wq:((mm==1)?Wk:Wv);
    int coff = n0 & 511;
    for (int ks=0; ks<16; ks++){
        #pragma unroll
        for (int p=0;p<2;p++){
            int e = tid + p*256;
            int lane = e>>3, j = e&7;
            int kk = ks*32 + ((lane>>4)&3)*8 + j;
            int col = coff + (lane&15);
            Bpk[(nb*16+ks)*512 + e] = f2bf(W[kk*Dm + col]);
        }
    }
}

// K1c: QKV projection as one bf16 MFMA GEMM, M=1024 N=1536 K=512.
// grid (mt 0..15, nt 0..23), 4 waves; wave = one 16-row m-block, all 4 n-blocks.
// nt -> (matrix mm = nt>>3, head hd = nt&7). Bias fused; writes raw q/k/v.
__global__ __launch_bounds__(256) void qkvm_kernel(
    const unsigned short* __restrict__ Apk, const unsigned short* __restrict__ Bpk,
    const float* __restrict__ bq, const float* __restrict__ bk, const float* __restrict__ bv,
    float* __restrict__ qh, float* __restrict__ kn, float* __restrict__ vn)
{
    int mt = blockIdx.x, nt = blockIdx.y;
    int tid = threadIdx.x, wid = tid>>6, lane = tid&63;
    int mb = mt*4 + wid;
    f32x4 acc[4];
    #pragma unroll
    for (int nb=0;nb<4;nb++) acc[nb]=(f32x4){0.f,0.f,0.f,0.f};
    for (int ks=0; ks<16; ks++){
        short8 a = *(const short8*)(Apk + (mb*16+ks)*512 + lane*8);
        #pragma unroll
        for (int nb2=0;nb2<4;nb2++){
            short8 b = *(const short8*)(Bpk + ((nt*4+nb2)*16+ks)*512 + lane*8);
            acc[nb2] = __builtin_amdgcn_mfma_f32_16x16x32_bf16(a, b, acc[nb2], 0,0,0);
        }
    }
    int mm = nt>>3, hd = nt&7;
    const float* bias = (mm==0)?bq:((mm==1)?bk:bv);
    float* dst = (mm==0)?qh:((mm==1)?kn:vn);
    int quad = lane>>4, col = lane&15;
    #pragma unroll
    for (int nb2=0;nb2<4;nb2++){
        int d = nb2*16 + col;
        float bval = bias[hd*64+d];
        #pragma unroll
        for (int r=0;r<4;r++){
            int t = mb*16 + quad*4 + r;
            dst[(hd*Ll + t)*64 + d] = acc[nb2][r] + bval;
        }
    }
}

// K1d: per-row sim = (q.k)*qks[hd]; in-place L2-normalize k,v. One wave per row.
__global__ __launch_bounds__(256) void nse_kernel(
    const float* __restrict__ qh, float* __restrict__ kn, float* __restrict__ vn,
    const float* __restrict__ qks, float* __restrict__ simg)
{
    int gw = blockIdx.x*4 + (threadIdx.x>>6);  // row 0..8191 = hd*1024+t
    int lane = threadIdx.x & 63;
    int hd = gw>>10;
    int base = gw*64 + lane;
    float q = qh[base], k = kn[base], v = vn[base];
    float sim = q*k, k2 = k*k, v2 = v*v;
    #pragma unroll
    for (int off=32; off; off>>=1){
        sim += __shfl_xor(sim, off, 64);
        k2  += __shfl_xor(k2,  off, 64);
        v2  += __shfl_xor(v2,  off, 64);
    }
    float invk = 1.f/fmaxf(sqrtf(k2), 1e-12f);
    float invv = 1.f/fmaxf(sqrtf(v2), 1e-12f);
    kn[base] = k*invk;
    vn[base] = v*invv;
    if (lane==0) simg[gw] = sim * qks[hd];
}

// K2a: precompute Toeplitz filter blocks in bf16, MFMA-A-fragment order.
__global__ __launch_bounds__(256) void fpk_kernel(
    const float* __restrict__ filt, unsigned short* __restrict__ Fpk)
{
    int kf = blockIdx.x, dslot = blockIdx.y, tid = threadIdx.x;
    unsigned short* dst = Fpk + (kf*17 + dslot)*4096;
    for (int p=0;p<16;p++){
        int e = tid + p*256;
        int j = e&7, lane = (e>>3)&63, ks = (e>>9)&1, mb = (e>>10)&3;
        int m = mb*16 + (lane&15);
        int k = ks*32 + (lane>>4)*8 + j;
        int fidx = (dslot-1)*64 + m - k;
        float v = (fidx>=0 && fidx<Ll) ? filt[fidx*KF + kf] : 0.f;
        dst[e] = f2bf(v);
    }
}

// K2b: pack normalized k/v into bf16 MFMA-B-fragment order.
__global__ __launch_bounds__(256) void upk_kernel(
    const float* __restrict__ vn, const float* __restrict__ kn,
    unsigned short* __restrict__ Upk)
{
    int ST = blockIdx.x, hd = blockIdx.y, tensor = blockIdx.z;
    int z = tensor*8 + hd, tid = threadIdx.x;
    const float* src = tensor ? kn : vn;
    unsigned short* dst = Upk + (z*16 + ST)*4096;
    for (int fi=0; fi<2; fi++){
        int f = tid + fi*256;
        int lane = f&63, nb = (f>>6)&3, ks = f>>8;
        int d = nb*16 + (lane&15);
        int s0 = ST*64 + ks*32 + ((lane>>4)&3)*8;
        #pragma unroll
        for (int j=0;j<8;j++){
            dst[f*8 + j] = f2bf(src[(hd*Ll + s0 + j)*64 + d]);
        }
    }
}

// K2: causal conv as block-triangular bf16 MFMA GEMM.
__global__ __launch_bounds__(256) void convm_kernel(
    const unsigned short* __restrict__ Fpk, const unsigned short* __restrict__ Upk,
    float* __restrict__ vc, float* __restrict__ kc)
{
    int TT = blockIdx.x, kf = blockIdx.y, z = blockIdx.z;
    int tensor = z>>3, hd = z&7;
    float* dst = tensor ? kc : vc;
    int tid = threadIdx.x, wid = tid>>6, lane = tid&63;
    int hf = wid>>1, mb0 = (wid&1)*2;
    const unsigned short* Fkf = Fpk + kf*17*4096;
    const unsigned short* Uz  = Upk + z*16*4096;

    f32x4 acc[2][4];
    #pragma unroll
    for (int i=0;i<2;i++)
        #pragma unroll
        for (int nb=0;nb<4;nb++) acc[i][nb] = (f32x4){0.f,0.f,0.f,0.f};

    int STend = 2*TT + 2;
    for (int ST=0; ST<STend; ST++){
        int dslot = 2*TT + hf - ST + 1;
        const unsigned short* Fb = Fkf + dslot*4096;
        const unsigned short* Ub = Uz + ST*4096;
        short8 a[2][2], b[2][4];
        #pragma unroll
        for (int i=0;i<2;i++)
            #pragma unroll
            for (int ks=0;ks<2;ks++)
                a[i][ks] = *(const short8*)(Fb + ((mb0+i)*1024 + ks*512 + lane*8));
        #pragma unroll
        for (int ks=0;ks<2;ks++)
            #pragma unroll
            for (int nb=0;nb<4;nb++)
                b[ks][nb] = *(const short8*)(Ub + (ks*2048 + nb*512 + lane*8));
        #pragma unroll
        for (int ks=0;ks<2;ks++)
            #pragma unroll
            for (int i=0;i<2;i++)
                #pragma unroll
                for (int nb=0;nb<4;nb++)
                    acc[i][nb] = __builtin_amdgcn_mfma_f32_16x16x32_bf16(
                        a[i][ks], b[ks][nb], acc[i][nb], 0, 0, 0);
    }
    int quad = lane>>4, col = lane&15;
    #pragma unroll
    for (int i=0;i<2;i++){
        int tbase = TT*128 + hf*64 + (mb0+i)*16 + quad*4;
        #pragma unroll
        for (int nb=0;nb<4;nb++){
            int d = nb*16 + col;
            #pragma unroll
            for (int r=0;r<4;r++){
                dst[((hd*Ll + tbase + r)*KF + kf)*64 + d] = acc[i][nb][r];
            }
        }
    }
}

// K3: logits[t] += rows of (Kc @ (kvs*Wg)^T) . Vc   (atomicAdd per row)
__global__ __launch_bounds__(256) void mkdot_kernel(
    const float* __restrict__ kc, const float* __restrict__ vc,
    const float* __restrict__ kvs, const float* __restrict__ Wg,
    float* __restrict__ logits)
{
    __shared__ float Ms[64][65];
    __shared__ float Ks[64][65];
    __shared__ float red[64][17];
    int tid=threadIdx.x, ty=tid>>4, tx=tid&15;
    int RT=blockIdx.x, hd=blockIdx.y; int R0=RT*64;
    for(int p=0;p<16;p++){ int e=tid+p*256; int d=e>>6, ee=e&63;
        Ms[d][ee] = kvs[(hd*64+d)*64+ee]*Wg[e];
        Ks[d][ee] = kc[(hd*LK + R0+d)*64 + ee]; }
    __syncthreads();
    float a1[4][4]={};
    for(int ee=0;ee<64;ee++){
        float a0[4],b0[4];
        #pragma unroll
        for(int i=0;i<4;i++) a0[i]=Ks[ty*4+i][ee];
        #pragma unroll
        for(int j=0;j<4;j++) b0[j]=Ms[tx*4+j][ee];
        #pragma unroll
        for(int i=0;i<4;i++)
            #pragma unroll
            for(int j=0;j<4;j++) a1[i][j] += a0[i]*b0[j];
    }
    for(int i=0;i<4;i++){
        int row = R0+ty*4+i;
        const float* vp = vc + (hd*LK+row)*64 + tx*4;
        red[ty*4+i][tx] = a1[i][0]*vp[0]+a1[i][1]*vp[1]+a1[i][2]*vp[2]+a1[i][3]*vp[3];
    }
    __syncthreads();
    if (tid<64){ float s=0; for(int u=0;u<16;u++) s+=red[tid][u];
        atomicAdd(&logits[hd*Ll + (R0+tid)/KF], s); }
}

__global__ __launch_bounds__(256) void gates_kernel(
    const float* __restrict__ logits, const float* __restrict__ bg, float* __restrict__ gates)
{
    int i = blockIdx.x*256 + threadIdx.x;
    float lg = logits[i] + bg[0];
    float r = fmaxf(lg, 0.f);
    gates[i] = r*r + EPSf;
}

// K5: online-softmax scan over sim + cumsum(gates) -> factor[l]
__global__ __launch_bounds__(256) void scan_kernel(
    const float* __restrict__ simg, const float* __restrict__ gates, float* __restrict__ factor)
{
    int hd=blockIdx.x, tid=threadIdx.x;
    __shared__ float sm[256], ssc[256], sg[256];
    float simv[4], m_loc[4], s_loc[4], g_loc[4];
    float m = -__builtin_inff(), s = 0.f, g = 0.f;
    for(int e=0;e<4;e++){
        simv[e] = simg[hd*Ll + tid*4 + e];
        float gv = gates[hd*Ll + tid*4 + e];
        float mn = fmaxf(m, simv[e]);
        s = s*__expf(m-mn) + __expf(simv[e]-mn);
        m = mn; g += gv;
        m_loc[e]=m; s_loc[e]=s; g_loc[e]=g;
    }
    sm[tid]=m; ssc[tid]=s; sg[tid]=g;
    __syncthreads();
    for(int off=1; off<256; off<<=1){
        float pm=0, ps=0, pg=0; bool has = (tid>=off);
        if(has){ pm=sm[tid-off]; ps=ssc[tid-off]; pg=sg[tid-off]; }
        __syncthreads();
        if(has){
            float mn=fmaxf(pm, sm[tid]);
            float sn=ps*__expf(pm-mn) + ssc[tid]*__expf(sm[tid]-mn);
            sm[tid]=mn; ssc[tid]=sn; sg[tid]=pg+sg[tid];
        }
        __syncthreads();
    }
    float pm=-__builtin_inff(), ps=0.f, pg=0.f;
    if (tid>0){ pm=sm[tid-1]; ps=ssc[tid-1]; pg=sg[tid-1]; }
    for(int e=0;e<4;e++){
        float mn=fmaxf(pm, m_loc[e]);
        float sn=ps*__expf(pm-mn) + s_loc[e]*__expf(m_loc[e]-mn);
        float gn=pg + g_loc[e];
        float sw = __expf(simv[e]-mn)/(sn+EPSf);
        float silu = sw/(1.f+__expf(-sw));
        factor[hd*Ll + tid*4 + e] = (1.f+silu)/(gn+EPSf);
    }
}

// K6: per-(chunk,quarter) partial sum of gates[t]*Z[t]
__global__ __launch_bounds__(256) void chunkz_kernel(
    const float* __restrict__ vc, const float* __restrict__ kc,
    const float* __restrict__ gates, float* __restrict__ czp)
{
    __shared__ float Vs[64][64];
    __shared__ float Ks2[64][64];
    __shared__ float gl[16];
    int tid=threadIdx.x, ty=tid>>4, tx=tid&15;
    int c=blockIdx.x, qq=blockIdx.y, hd=blockIdx.z;
    int tq0 = c*64 + qq*16;
    int RQ0 = tq0*KF;
    if (tid<16) gl[tid] = gates[hd*Ll + tq0 + tid];
    float acc[4][4]={};
    for(int sub=0; sub<6; sub++){
        int RB = RQ0 + sub*64;
        __syncthreads();
        for(int p=0;p<16;p++){ int e=tid+p*256; int rr=e>>6, cc=e&63;
            int row=RB+rr; float g = gl[row/KF - tq0];
            Vs[rr][cc] = vc[(hd*LK+row)*64+cc]*g;
            Ks2[rr][cc]= kc[(hd*LK+row)*64+cc]; }
        __syncthreads();
        for(int rr=0;rr<64;rr++){
            float a0[4],b0[4];
            #pragma unroll
            for(int i=0;i<4;i++) a0[i]=Vs[rr][ty*4+i];
            #pragma unroll
            for(int j=0;j<4;j++) b0[j]=Ks2[rr][tx*4+j];
            #pragma unroll
            for(int i=0;i<4;i++)
                #pragma unroll
                for(int j=0;j<4;j++) acc[i][j] += a0[i]*b0[j];
        }
    }
    int ob = ((hd*16+c)*4+qq)*4096;
    for(int i=0;i<4;i++)
        for(int j=0;j<4;j++)
            czp[ob + (ty*4+i)*64 + tx*4+j] = acc[i][j];
}

// K6b: exclusive prefix over chunks of (sum of 4 quarter partials)
__global__ __launch_bounds__(256) void s0_kernel(
    const float* __restrict__ czp, float* __restrict__ S0)
{
    int hd=blockIdx.x, tid=threadIdx.x;
    float accv[16];
    #pragma unroll
    for(int p=0;p<16;p++) accv[p]=0.f;
    for(int c=0;c<16;c++){
        for(int p=0;p<16;p++){ int idx=tid+p*256;
            S0[(hd*16+c)*4096 + idx] = accv[p];
            int b = ((hd*16+c)*4)*4096 + idx;
            accv[p] += czp[b] + czp[b+4096] + czp[b+2*4096] + czp[b+3*4096];
        }
    }
}

// K7: intra-chunk attention-form partial
__global__ __launch_bounds__(256) void phase3_kernel(
    const float* __restrict__ qh, const float* __restrict__ vc, const float* __restrict__ kc,
    const float* __restrict__ gates, float* __restrict__ cpart)
{
    __shared__ float Qs[64][65];
    __shared__ float Ts[64][65];
    __shared__ float A1s[64][65];
    __shared__ float gl[16];
    int tid=threadIdx.x, ty=tid>>4, tx=tid&15;
    int c=blockIdx.x, qq=blockIdx.y, hd=blockIdx.z;
    int T0=c*64, tq0=T0+qq*16, RQ0=tq0*KF;
    for(int p=0;p<16;p++){ int e=tid+p*256; int rr=e>>6, cc=e&63;
        Qs[rr][cc] = qh[(hd*Ll+T0+rr)*64+cc]; }
    if (tid<16) gl[tid]=gates[hd*Ll+tq0+tid];
    float ctx[4][4]={};
    for(int sub=0;sub<6;sub++){
        int RB=RQ0+sub*64;
        __syncthreads();
        for(int p=0;p<16;p++){ int e=tid+p*256; int rr=e>>6, cc=e&63;
            Ts[cc][rr] = vc[(hd*LK+RB+rr)*64+cc]; }
        __syncthreads();
        float a1[4][4]={};
        for(int d=0; d<64; d++){
            float a0[4],b0[4];
            #pragma unroll
            for(int i=0;i<4;i++) a0[i]=Qs[ty*4+i][d];
            #pragma unroll
            for(int j=0;j<4;j++) b0[j]=Ts[d][tx*4+j];
            #pragma unroll
            for(int i=0;i<4;i++)
                #pragma unroll
                for(int j=0;j<4;j++) a1[i][j] += a0[i]*b0[j];
        }
        for(int i=0;i<4;i++){ int t=T0+ty*4+i;
            for(int j=0;j<4;j++){ int row=RB+tx*4+j; int tp=row/KF;
                float v = (t>=tp) ? a1[i][j]*gl[tp-tq0] : 0.f;
                A1s[ty*4+i][tx*4+j]=v; } }
        __syncthreads();
        for(int p=0;p<16;p++){ int e=tid+p*256; int rr=e>>6, cc=e&63;
            Ts[rr][cc] = kc[(hd*LK+RB+rr)*64+cc]; }
        __syncthreads();
        for(int rr=0;rr<64;rr++){
            float a0[4],b0[4];
            #pragma unroll
            for(int i=0;i<4;i++) a0[i]=A1s[ty*4+i][rr];
            #pragma unroll
            for(int j=0;j<4;j++) b0[j]=Ts[rr][tx*4+j];
            #pragma unroll
            for(int i=0;i<4;i++)
                #pragma unroll
                for(int j=0;j<4;j++) ctx[i][j] += a0[i]*b0[j];
        }
    }
    for(int i=0;i<4;i++){ int t=T0+ty*4+i;
        int gb=((qq*8+hd)*Ll + t)*64 + tx*4;
        for(int j=0;j<4;j++) cpart[gb+j]=ctx[i][j];
    }
}

// K8: ctxt[t, hd*64+e] = factor[t] * ( q_t @ S0_chunk + sum_q cpart )
__global__ __launch_bounds__(256) void combine_kernel(
    const float* __restrict__ qh, const float* __restrict__ S0,
    const float* __restrict__ cpart, const float* __restrict__ factor,
    float* __restrict__ ctxt)
{
    __shared__ float Qs[64][65];
    __shared__ float Ss[64][64];
    __shared__ float fl[64];
    int tid=threadIdx.x, ty=tid>>4, tx=tid&15;
    int c=blockIdx.x, hd=blockIdx.y; int T0=c*64;
    for(int p=0;p<16;p++){ int e=tid+p*256; int rr=e>>6, cc=e&63;
        Qs[rr][cc]=qh[(hd*Ll+T0+rr)*64+cc];
        Ss[rr][cc]=S0[(hd*16+c)*4096 + e]; }
    if(tid<64) fl[tid]=factor[hd*Ll+T0+tid];
    __syncthreads();
    float acc[4][4]={};
    for(int d=0;d<64;d++){
        float a0[4],b0[4];
        #pragma unroll
        for(int i=0;i<4;i++) a0[i]=Qs[ty*4+i][d];
        #pragma unroll
        for(int j=0;j<4;j++) b0[j]=Ss[d][tx*4+j];
        #pragma unroll
        for(int i=0;i<4;i++)
            #pragma unroll
            for(int j=0;j<4;j++) acc[i][j]+=a0[i]*b0[j];
    }
    for(int i=0;i<4;i++){ int t=T0+ty*4+i; float f=fl[ty*4+i];
        for(int j=0;j<4;j++){ float v=acc[i][j];
            for(int q=0;q<4;q++) v += cpart[((q*8+hd)*Ll + t)*64 + tx*4+j];
            ctxt[t*Dm + hd*64 + tx*4+j] = v*f; } }
}

// K9: out = ctxt @ Wo + bo
__global__ __launch_bounds__(256) void outproj_kernel(
    const float* __restrict__ ctxt, const float* __restrict__ Wo,
    const float* __restrict__ bo, float* __restrict__ out)
{
    __shared__ float Cs[64][65];
    __shared__ float Ws2[64][64];
    int tid=threadIdx.x, ty=tid>>4, tx=tid&15;
    int L0=blockIdx.x*64, N0=blockIdx.y*64;
    float acc[4][4]={};
    for(int kk=0;kk<Dm;kk+=64){
        __syncthreads();
        for(int p=0;p<16;p++){ int e=tid+p*256; int rr=e>>6, cc=e&63;
            Cs[rr][cc]=ctxt[(L0+rr)*Dm + kk+cc];
            Ws2[rr][cc]=Wo[(kk+rr)*Dm + N0+cc]; }
        __syncthreads();
        for(int ss=0;ss<64;ss++){
            float a0[4],b0[4];
            #pragma unroll
            for(int i=0;i<4;i++) a0[i]=Cs[ty*4+i][ss];
            #pragma unroll
            for(int j=0;j<4;j++) b0[j]=Ws2[ss][tx*4+j];
            #pragma unroll
            for(int i=0;i<4;i++)
                #pragma unroll
                for(int j=0;j<4;j++) acc[i][j]+=a0[i]*b0[j];
        }
    }
    for(int j=0;j<4;j++){ float b=bo[N0+tx*4+j];
        for(int i=0;i<4;i++)
            out[(L0+ty*4+i)*Dm + N0+tx*4+j] = acc[i][j]+b;
    }
}

extern "C" void kernel_launch(void* const* d_in, const int* in_sizes, int n_in,
                              void* d_out, int out_size, void* d_ws, size_t ws_size,
                              hipStream_t stream)
{
    (void)in_sizes; (void)n_in; (void)out_size; (void)ws_size;
    const float* x   =(const float*)d_in[0];
    const float* Wq  =(const float*)d_in[1];
    const float* bq  =(const float*)d_in[2];
    const float* Wk  =(const float*)d_in[3];
    const float* bk  =(const float*)d_in[4];
    const float* Wv  =(const float*)d_in[5];
    const float* bv  =(const float*)d_in[6];
    const float* Wo  =(const float*)d_in[7];
    const float* bo  =(const float*)d_in[8];
    const float* Wg  =(const float*)d_in[9];
    const float* bg  =(const float*)d_in[10];
    const float* kvs =(const float*)d_in[11];
    const float* qks =(const float*)d_in[12];
    const float* filt=(const float*)d_in[13];
    float* ws = (float*)d_ws;
    float* qh    = ws+OFF_QH;
    float* kn    = ws+OFF_KN;
    float* vn    = ws+OFF_VN;
    float* simg  = ws+OFF_SIM;
    float* logits= ws+OFF_LOGITS;
    float* gates = ws+OFF_GATES;
    float* factor= ws+OFF_FACTOR;
    float* vc    = ws+OFF_VC;
    float* kc    = ws+OFF_KC;
    float* czp   = ws+OFF_CZP;
    float* S0v   = ws+OFF_S0;
    float* cpart = ws+OFF_CPART;
    float* ctxt  = ws+OFF_CTXT;
    unsigned short* Fpk = (unsigned short*)(ws + OFF_FPK_F);
    unsigned short* Upk = (unsigned short*)(ws + OFF_UPK_F);
    unsigned short* Apk = (unsigned short*)(ws + OFF_APK_F);
    unsigned short* Bpk = (unsigned short*)(ws + OFF_BPK_F);
    float* out   = (float*)d_out;

    hipMemsetAsync(logits, 0, Hh*Ll*sizeof(float), stream);
    xpk_kernel   <<<dim3(64),     256,0,stream>>>(x,Apk);
    wpk_kernel   <<<dim3(96),     256,0,stream>>>(Wq,Wk,Wv,Bpk);
    qkvm_kernel  <<<dim3(16,24),  256,0,stream>>>(Apk,Bpk,bq,bk,bv,qh,kn,vn);
    nse_kernel   <<<dim3(2048),   256,0,stream>>>(qh,kn,vn,qks,simg);
    fpk_kernel   <<<dim3(24,17),  256,0,stream>>>(filt,Fpk);
    upk_kernel   <<<dim3(16,8,2), 256,0,stream>>>(vn,kn,Upk);
    convm_kernel <<<dim3(8,24,16),256,0,stream>>>(Fpk,Upk,vc,kc);
    mkdot_kernel <<<dim3(384,8),  256,0,stream>>>(kc,vc,kvs,Wg,logits);
    gates_kernel <<<dim3(32),     256,0,stream>>>(logits,bg,gates);
    scan_kernel  <<<dim3(8),      256,0,stream>>>(simg,gates,factor);
    chunkz_kernel<<<dim3(16,4,8), 256,0,stream>>>(vc,kc,gates,czp);
    s0_kernel    <<<dim3(8),      256,0,stream>>>(czp,S0v);
    phase3_kernel<<<dim3(16,4,8), 256,0,stream>>>(qh,vc,kc,gates,cpart);
    combine_kernel<<<dim3(16,8),  256,0,stream>>>(qh,S0v,cpart,factor,ctxt);
    outproj_kernel<<<dim3(16,8),  256,0,stream>>>(ctxt,Wo,bo,out);
}

// Round 4
// 290.591 us; speedup vs baseline: 3.3965x; 1.4314x over previous
//
#include <hip/hip_runtime.h>
#include <math.h>

#define Hh 8
#define Ll 1024
#define KF 24
#define Dm 512
#define EPSf 1e-5f
#define LK (Ll*KF)   // 24576 rows (t,kf) per head

typedef __attribute__((ext_vector_type(8))) short sh8;
typedef __attribute__((ext_vector_type(4))) short sh4;
typedef __attribute__((ext_vector_type(4))) float f32x4;

// ---- workspace offsets (floats) ----
#define OFF_QH     0
#define OFF_KN     524288
#define OFF_VN     1048576
#define OFF_SIM    1572864
#define OFF_LOGITS 1581056
#define OFF_GATES  1589248
#define OFF_FACTOR 1597440
#define OFF_VCB    1605632     // bf16 vc: 12,582,912 ushorts = 6,291,456 fl
#define OFF_KCB    7897088     // bf16 kc
#define OFF_QPK    14188544    // bf16 Q A-frags: 262,144 fl
#define OFF_MPK    14450688    // bf16 M B-frags: 16,384 fl
#define OFF_WOPK   14467072    // bf16 Wo B-frags: 131,072 fl
#define OFF_CPK    14598144    // bf16 ctxt A-frags: 262,144 fl
#define OFF_CZP    26771456
#define OFF_S0     28868608
#define OFF_CPART  29392896
// pack overlays in CZP region (consumed by convm/qkvm before p3cz writes czp):
#define OFF_FPK_F  26771456
#define OFF_UPK_F  27607040
#define OFF_APK_F  28131328
#define OFF_BPK_F  28393472

__device__ inline unsigned short f2bf(float x){
    unsigned int u = __float_as_uint(x);
    unsigned int r = (u + 0x7fffu + ((u>>16)&1u)) >> 16;
    return (unsigned short)r;
}
__device__ inline float bf2f(unsigned short u){ return __uint_as_float(((unsigned int)u)<<16); }
// 8-byte-aligned short8 load (for 136B-stride LDS rows)
__device__ inline sh8 ld8_8B(const unsigned short* p){
    union { sh8 s; sh4 h[2]; } u;
    u.h[0] = *(const sh4*)(p);
    u.h[1] = *(const sh4*)(p+4);
    return u.s;
}

// ---------- packing kernels ----------
// Apk[mb(64)][ks(16)][lane(64)][j(8)] = x[mb*16+(lane&15)][ks*32+((lane>>4)&3)*8+j]
__global__ __launch_bounds__(256) void xpk_kernel(
    const float* __restrict__ x, unsigned short* __restrict__ Apk)
{
    int mb = blockIdx.x, tid = threadIdx.x;
    for (int ks=0; ks<16; ks++){
        #pragma unroll
        for (int p=0;p<2;p++){
            int e = tid + p*256;
            int lane = e>>3, j = e&7;
            int m = mb*16 + (lane&15);
            int k = ks*32 + ((lane>>4)&3)*8 + j;
            Apk[(mb*16+ks)*512 + e] = f2bf(x[m*Dm + k]);
        }
    }
}

__global__ __launch_bounds__(256) void wpk_kernel(
    const float* __restrict__ Wq, const float* __restrict__ Wk, const float* __restrict__ Wv,
    unsigned short* __restrict__ Bpk)
{
    int nb = blockIdx.x, tid = threadIdx.x;
    int n0 = nb*16;
    int mm = n0>>9;
    const float* W = (mm==0)?Wq:((mm==1)?Wk:Wv);
    int coff = n0 & 511;
    for (int ks=0; ks<16; ks++){
        #pragma unroll
        for (int p=0;p<2;p++){
            int e = tid + p*256;
            int lane = e>>3, j = e&7;
            int kk = ks*32 + ((lane>>4)&3)*8 + j;
            int col = coff + (lane&15);
            Bpk[(nb*16+ks)*512 + e] = f2bf(W[kk*Dm + col]);
        }
    }
}

// Wo pack: Bpk2[nb(32)][ks(16)][512]
__global__ __launch_bounds__(256) void wopk_kernel(
    const float* __restrict__ Wo, unsigned short* __restrict__ Bpk2)
{
    int nb = blockIdx.x, tid = threadIdx.x;
    int n0 = nb*16;
    for (int ks=0; ks<16; ks++){
        #pragma unroll
        for (int p=0;p<2;p++){
            int e = tid + p*256;
            int lane = e>>3, j = e&7;
            int kk = ks*32 + ((lane>>4)&3)*8 + j;
            Bpk2[(nb*16+ks)*512 + e] = f2bf(Wo[kk*Dm + n0 + (lane&15)]);
        }
    }
}

// Q pack: Qpk[hd][mb(64)][ks(2)][512]
__global__ __launch_bounds__(256) void qpk_kernel(
    const float* __restrict__ qh, unsigned short* __restrict__ Qpk)
{
    int mb = blockIdx.x, hd = blockIdx.y, tid = threadIdx.x;
    for (int it=0; it<4; it++){
        int idx = tid + it*256;            // 0..1023
        int ks = idx>>9, f = idx&511;
        int lane = f>>3, j = f&7;
        int m = lane&15;
        int koff = ((lane>>4)&3)*8 + j;
        Qpk[((hd*64+mb)*2 + ks)*512 + f] =
            f2bf(qh[(hd*Ll + mb*16 + m)*64 + ks*32 + koff]);
    }
}

// M pack: Mpk[hd][nb(4)][ks(2)][512], M[e][d] = kvs[hd,e,d]*Wg[e*64+d]
__global__ __launch_bounds__(256) void mpk_kernel(
    const float* __restrict__ kvs, const float* __restrict__ Wg,
    unsigned short* __restrict__ Mpk)
{
    int hd = blockIdx.x, tid = threadIdx.x;
    for (int it=0; it<16; it++){
        int idx = tid + it*256;            // 0..4095
        int f = idx & 511, ksnb = idx >> 9;
        int nb = ksnb>>1, ks = ksnb&1;
        int lane = f>>3, j = f&7;
        int e = nb*16 + (lane&15);
        int d = ks*32 + ((lane>>4)&3)*8 + j;
        Mpk[hd*4096 + idx] = f2bf(kvs[(hd*64+e)*64 + d]*Wg[e*64+d]);
    }
}

// ---------- QKV MFMA GEMM ----------
__global__ __launch_bounds__(256) void qkvm_kernel(
    const unsigned short* __restrict__ Apk, const unsigned short* __restrict__ Bpk,
    const float* __restrict__ bq, const float* __restrict__ bk, const float* __restrict__ bv,
    float* __restrict__ qh, float* __restrict__ kn, float* __restrict__ vn)
{
    int mt = blockIdx.x, nt = blockIdx.y;
    int tid = threadIdx.x, wid = tid>>6, lane = tid&63;
    int mb = mt*4 + wid;
    f32x4 acc[4];
    #pragma unroll
    for (int nb=0;nb<4;nb++) acc[nb]=(f32x4){0.f,0.f,0.f,0.f};
    for (int ks=0; ks<16; ks++){
        sh8 a = *(const sh8*)(Apk + (mb*16+ks)*512 + lane*8);
        #pragma unroll
        for (int nb2=0;nb2<4;nb2++){
            sh8 b = *(const sh8*)(Bpk + ((nt*4+nb2)*16+ks)*512 + lane*8);
            acc[nb2] = __builtin_amdgcn_mfma_f32_16x16x32_bf16(a, b, acc[nb2], 0,0,0);
        }
    }
    int mm = nt>>3, hd = nt&7;
    const float* bias = (mm==0)?bq:((mm==1)?bk:bv);
    float* dst = (mm==0)?qh:((mm==1)?kn:vn);
    int quad = lane>>4, col = lane&15;
    #pragma unroll
    for (int nb2=0;nb2<4;nb2++){
        int d = nb2*16 + col;
        float bval = bias[hd*64+d];
        #pragma unroll
        for (int r=0;r<4;r++){
            int t = mb*16 + quad*4 + r;
            dst[(hd*Ll + t)*64 + d] = acc[nb2][r] + bval;
        }
    }
}

// per-row sim + in-place normalize
__global__ __launch_bounds__(256) void nse_kernel(
    const float* __restrict__ qh, float* __restrict__ kn, float* __restrict__ vn,
    const float* __restrict__ qks, float* __restrict__ simg)
{
    int gw = blockIdx.x*4 + (threadIdx.x>>6);
    int lane = threadIdx.x & 63;
    int hd = gw>>10;
    int base = gw*64 + lane;
    float q = qh[base], k = kn[base], v = vn[base];
    float sim = q*k, k2 = k*k, v2 = v*v;
    #pragma unroll
    for (int off=32; off; off>>=1){
        sim += __shfl_xor(sim, off, 64);
        k2  += __shfl_xor(k2,  off, 64);
        v2  += __shfl_xor(v2,  off, 64);
    }
    float invk = 1.f/fmaxf(sqrtf(k2), 1e-12f);
    float invv = 1.f/fmaxf(sqrtf(v2), 1e-12f);
    kn[base] = k*invk;
    vn[base] = v*invv;
    if (lane==0) simg[gw] = sim * qks[hd];
}

// ---------- conv packs ----------
__global__ __launch_bounds__(256) void fpk_kernel(
    const float* __restrict__ filt, unsigned short* __restrict__ Fpk)
{
    int kf = blockIdx.x, dslot = blockIdx.y, tid = threadIdx.x;
    unsigned short* dst = Fpk + (kf*17 + dslot)*4096;
    for (int p=0;p<16;p++){
        int e = tid + p*256;
        int j = e&7, lane = (e>>3)&63, ks = (e>>9)&1, mb = (e>>10)&3;
        int m = mb*16 + (lane&15);
        int k = ks*32 + (lane>>4)*8 + j;
        int fidx = (dslot-1)*64 + m - k;
        float v = (fidx>=0 && fidx<Ll) ? filt[fidx*KF+kf] : 0.0f;
        dst[e] = f2bf(v);
    }
}

__global__ __launch_bounds__(256) void upk_kernel(
    const float* __restrict__ vn, const float* __restrict__ kn,
    unsigned short* __restrict__ Upk)
{
    int ST = blockIdx.x, hd = blockIdx.y, tensor = blockIdx.z;
    int z = tensor*8 + hd, tid = threadIdx.x;
    const float* src = tensor ? kn : vn;
    unsigned short* dst = Upk + (z*16 + ST)*4096;
    for (int fi=0; fi<2; fi++){
        int f = tid + fi*256;
        int lane = f&63, nb = (f>>6)&3, ks = f>>8;
        int d = nb*16 + (lane&15);
        int s0 = ST*64 + ks*32 + ((lane>>4)&3)*8;
        #pragma unroll
        for (int j=0;j<8;j++){
            dst[f*8 + j] = f2bf(src[(hd*Ll + s0 + j)*64 + d]);
        }
    }
}

// ---------- conv MFMA with ping-pong prefetch, bf16 output ----------
__device__ inline void conv_load(const unsigned short* Fkf, const unsigned short* Uz,
    int TT, int hf, int mb0, int lane, int ST, sh8 a[2][2], sh8 b[2][4])
{
    int dslot = 2*TT + hf - ST + 1;
    const unsigned short* Fb = Fkf + dslot*4096;
    const unsigned short* Ub = Uz + ST*4096;
    #pragma unroll
    for (int i=0;i<2;i++)
        #pragma unroll
        for (int ks=0;ks<2;ks++)
            a[i][ks] = *(const sh8*)(Fb + ((mb0+i)*1024 + ks*512 + lane*8));
    #pragma unroll
    for (int ks=0;ks<2;ks++)
        #pragma unroll
        for (int nb=0;nb<4;nb++)
            b[ks][nb] = *(const sh8*)(Ub + (ks*2048 + nb*512 + lane*8));
}
__device__ inline void conv_mma(sh8 a[2][2], sh8 b[2][4], f32x4 acc[2][4])
{
    #pragma unroll
    for (int ks=0;ks<2;ks++)
        #pragma unroll
        for (int i=0;i<2;i++)
            #pragma unroll
            for (int nb=0;nb<4;nb++)
                acc[i][nb] = __builtin_amdgcn_mfma_f32_16x16x32_bf16(
                    a[i][ks], b[ks][nb], acc[i][nb], 0, 0, 0);
}

__global__ __launch_bounds__(256) void convm_kernel(
    const unsigned short* __restrict__ Fpk, const unsigned short* __restrict__ Upk,
    unsigned short* __restrict__ vcb, unsigned short* __restrict__ kcb)
{
    __shared__ unsigned short Cs[128*64];
    int TT = 7 - blockIdx.x;   // big tiles dispatched first
    int kf = blockIdx.y, z = blockIdx.z;
    int tensor = z>>3, hd = z&7;
    unsigned short* dst = tensor ? kcb : vcb;
    int tid = threadIdx.x, wid = tid>>6, lane = tid&63;
    int hf = wid>>1, mb0 = (wid&1)*2;
    const unsigned short* Fkf = Fpk + kf*17*4096;
    const unsigned short* Uz  = Upk + z*16*4096;

    f32x4 acc[2][4];
    #pragma unroll
    for (int i=0;i<2;i++)
        #pragma unroll
        for (int nb=0;nb<4;nb++) acc[i][nb]=(f32x4){0.f,0.f,0.f,0.f};

    int STend = 2*TT + 2;  // always even
    sh8 aA[2][2], bA[2][4], aB[2][2], bB[2][4];
    conv_load(Fkf, Uz, TT, hf, mb0, lane, 0, aA, bA);
    for (int ST=0; ST<STend; ST+=2){
        conv_load(Fkf, Uz, TT, hf, mb0, lane, ST+1, aB, bB);
        conv_mma(aA, bA, acc);
        if (ST+2 < STend) conv_load(Fkf, Uz, TT, hf, mb0, lane, ST+2, aA, bA);
        conv_mma(aB, bB, acc);
    }
    int quad = lane>>4, col = lane&15;
    #pragma unroll
    for (int i=0;i<2;i++){
        #pragma unroll
        for (int nb=0;nb<4;nb++){
            #pragma unroll
            for (int r=0;r<4;r++){
                int tl = hf*64 + (mb0+i)*16 + quad*4 + r;
                Cs[tl*64 + nb*16 + col] = f2bf(acc[i][nb][r]);
            }
        }
    }
    __syncthreads();
    #pragma unroll
    for (int it=0; it<4; it++){
        int idx = tid + it*256;
        int row = idx>>3, seg = idx&7;
        sh8 v = *(const sh8*)(&Cs[row*64 + seg*8]);
        *(sh8*)(dst + (((hd*Ll + TT*128 + row)*KF) + kf)*64 + seg*8) = v;
    }
}

// ---------- mkdot MFMA ----------
__global__ __launch_bounds__(256) void mkdotm_kernel(
    const unsigned short* __restrict__ kcb, const unsigned short* __restrict__ vcb,
    const unsigned short* __restrict__ Mpk, float* __restrict__ logits)
{
    __shared__ unsigned short Vs[64*66];
    int tid=threadIdx.x, w=tid>>6, lane=tid&63, quad=lane>>4, lm=lane&15;
    int R0=blockIdx.x*64, hd=blockIdx.y;
    const unsigned short* kb = kcb + (hd*LK + R0)*64;
    const unsigned short* vb = vcb + (hd*LK + R0)*64;
    #pragma unroll
    for (int it=0; it<2; it++){
        int idx = tid + it*256;
        int row = idx>>3, e0 = (idx&7)*8;
        sh8 v = *(const sh8*)(vb + row*64 + e0);
        #pragma unroll
        for (int i2=0;i2<4;i2++){
            unsigned int pv = (unsigned int)(unsigned short)v[2*i2]
                            | ((unsigned int)(unsigned short)v[2*i2+1]<<16);
            *(unsigned int*)(&Vs[row*66 + e0 + 2*i2]) = pv;
        }
    }
    f32x4 acc[4];
    #pragma unroll
    for (int nb=0;nb<4;nb++) acc[nb]=(f32x4){0.f,0.f,0.f,0.f};
    const unsigned short* mb = Mpk + hd*4096;
    #pragma unroll
    for (int ks=0;ks<2;ks++){
        sh8 a = *(const sh8*)(kb + (w*16+lm)*64 + ks*32 + quad*8);
        #pragma unroll
        for (int nb=0;nb<4;nb++){
            sh8 bm = *(const sh8*)(mb + (nb*2+ks)*512 + lane*8);
            acc[nb] = __builtin_amdgcn_mfma_f32_16x16x32_bf16(a, bm, acc[nb], 0,0,0);
        }
    }
    __syncthreads();
    float p[4];
    #pragma unroll
    for (int r=0;r<4;r++){
        int rloc = w*16 + quad*4 + r;
        float s = 0.f;
        #pragma unroll
        for (int nb=0;nb<4;nb++)
            s += acc[nb][r]*bf2f(Vs[rloc*66 + nb*16 + lm]);
        p[r] = s;
    }
    #pragma unroll
    for (int off=1; off<16; off<<=1){
        #pragma unroll
        for (int r=0;r<4;r++) p[r] += __shfl_xor(p[r], off, 64);
    }
    if (lm==0){
        #pragma unroll
        for (int r=0;r<4;r++){
            int rowg = R0 + w*16 + quad*4 + r;
            atomicAdd(&logits[hd*Ll + rowg/KF], p[r]);
        }
    }
}

__global__ __launch_bounds__(256) void gates_kernel(
    const float* __restrict__ logits, const float* __restrict__ bg, float* __restrict__ gates)
{
    int i = blockIdx.x*256 + threadIdx.x;
    float lg = logits[i] + bg[0];
    float r = fmaxf(lg, 0.f);
    gates[i] = r*r + EPSf;
}

__global__ __launch_bounds__(256) void scan_kernel(
    const float* __restrict__ simg, const float* __restrict__ gates, float* __restrict__ factor)
{
    int hd=blockIdx.x, tid=threadIdx.x;
    __shared__ float sm[256], ssc[256], sg[256];
    float simv[4], m_loc[4], s_loc[4], g_loc[4];
    float m = -__builtin_inff(), s = 0.f, g = 0.f;
    for(int e=0;e<4;e++){
        simv[e] = simg[hd*Ll + tid*4 + e];
        float gv = gates[hd*Ll + tid*4 + e];
        float mn = fmaxf(m, simv[e]);
        s = s*__expf(m-mn) + __expf(simv[e]-mn);
        m = mn; g += gv;
        m_loc[e]=m; s_loc[e]=s; g_loc[e]=g;
    }
    sm[tid]=m; ssc[tid]=s; sg[tid]=g;
    __syncthreads();
    for(int off=1; off<256; off<<=1){
        float pm=0, ps=0, pg=0; bool has = (tid>=off);
        if(has){ pm=sm[tid-off]; ps=ssc[tid-off]; pg=sg[tid-off]; }
        __syncthreads();
        if(has){
            float mn=fmaxf(pm, sm[tid]);
            float sn=ps*__expf(pm-mn) + ssc[tid]*__expf(sm[tid]-mn);
            sm[tid]=mn; ssc[tid]=sn; sg[tid]=pg+sg[tid];
        }
        __syncthreads();
    }
    float pm=-__builtin_inff(), ps=0.f, pg=0.f;
    if (tid>0){ pm=sm[tid-1]; ps=ssc[tid-1]; pg=sg[tid-1]; }
    for(int e=0;e<4;e++){
        float mn=fmaxf(pm, m_loc[e]);
        float sn=ps*__expf(pm-mn) + s_loc[e]*__expf(m_loc[e]-mn);
        float gn=pg + g_loc[e];
        float sw = __expf(simv[e]-mn)/(sn+EPSf);
        float silu = sw/(1.f+__expf(-sw));
        factor[hd*Ll + tid*4 + e] = (1.f+silu)/(gn+EPSf);
    }
}

// ---------- fused phase3 + chunkz (MFMA) ----------
#define VTS 68   // VT/KT row stride (ushorts), 136B: 8B-aligned, low-conflict
#define ASS 72   // As row stride (ushorts), 144B: 16B-aligned
__global__ __launch_bounds__(256) void p3cz_kernel(
    const unsigned short* __restrict__ Qpk,
    const unsigned short* __restrict__ vcb, const unsigned short* __restrict__ kcb,
    const float* __restrict__ gates, float* __restrict__ cpart, float* __restrict__ czp)
{
    __shared__ unsigned short VT[64*VTS];   // (g*vc)^T : [d][row]
    __shared__ unsigned short KT[64*VTS];   // kc^T : [e][row]
    __shared__ unsigned short As[4][16*ASS];// per-wave masked A1 [t][row]
    __shared__ float gl[16];
    int tid=threadIdx.x, w=tid>>6, lane=tid&63;
    int quad=lane>>4, lm=lane&15;
    int c=blockIdx.x, qq=blockIdx.y, hd=blockIdx.z;
    int T0=c*64, tq0=T0+qq*16, RQ0=tq0*KF;
    if (tid<16) gl[tid]=gates[hd*Ll+tq0+tid];
    // constant GEMM1 A-frags: Q m-block c*4+w
    sh8 aq[2];
    {
        const unsigned short* qb = Qpk + ((hd*64 + (c*4+w))*2)*512;
        aq[0] = *(const sh8*)(qb + lane*8);
        aq[1] = *(const sh8*)(qb + 512 + lane*8);
    }
    f32x4 ctx[4], cz[4];
    #pragma unroll
    for (int nb=0;nb<4;nb++){ ctx[nb]=(f32x4){0,0,0,0}; cz[nb]=(f32x4){0,0,0,0}; }
    int t_g = T0 + w*16 + quad*4;     // + r
    int rp = tid>>3, e0 = (tid&7)*8, r0 = rp*2;

    for (int sub=0; sub<6; sub++){
        int RB = RQ0 + sub*64;
        const unsigned short* vrow = vcb + (hd*LK + RB)*64;
        const unsigned short* krow = kcb + (hd*LK + RB)*64;
        __syncthreads();
        // transposed staging (u32-paired writes); fold gate into VT
        {
            float g0 = gl[(RB + r0)/KF - tq0];
            float g1 = gl[(RB + r0 + 1)/KF - tq0];
            sh8 v0 = *(const sh8*)(vrow + r0*64 + e0);
            sh8 v1 = *(const sh8*)(vrow + (r0+1)*64 + e0);
            sh8 k0 = *(const sh8*)(krow + r0*64 + e0);
            sh8 k1 = *(const sh8*)(krow + (r0+1)*64 + e0);
            #pragma unroll
            for (int j=0;j<8;j++){
                unsigned int pv = (unsigned int)f2bf(bf2f((unsigned short)v0[j])*g0)
                                | ((unsigned int)f2bf(bf2f((unsigned short)v1[j])*g1)<<16);
                *(unsigned int*)(&VT[(e0+j)*VTS + r0]) = pv;
                unsigned int pk = (unsigned int)(unsigned short)k0[j]
                                | ((unsigned int)(unsigned short)k1[j]<<16);
                *(unsigned int*)(&KT[(e0+j)*VTS + r0]) = pk;
            }
        }
        // GEMM1: S[t][row'] = Q . vc^T (B-frags direct from global bf16)
        f32x4 S[4];
        #pragma unroll
        for (int nb=0;nb<4;nb++) S[nb]=(f32x4){0,0,0,0};
        #pragma unroll
        for (int ks=0;ks<2;ks++){
            #pragma unroll
            for (int nb=0;nb<4;nb++){
                sh8 b = *(const sh8*)(vrow + (nb*16+lm)*64 + ks*32 + quad*8);
                S[nb] = __builtin_amdgcn_mfma_f32_16x16x32_bf16(aq[ks], b, S[nb], 0,0,0);
            }
        }
        // mask + gate -> As (per-wave region, same-wave consumer)
        #pragma unroll
        for (int nb=0;nb<4;nb++){
            int row_l = nb*16+lm;
            int tp = (RB + row_l)/KF;
            float g = gl[tp - tq0];
            #pragma unroll
            for (int r=0;r<4;r++){
                float v = (t_g + r >= tp) ? S[nb][r]*g : 0.f;
                As[w][(quad*4+r)*ASS + row_l] = f2bf(v);
            }
        }
        __syncthreads();
        // GEMM2 (ctx += A1 @ kc) and chunkz (cz += (g vc)^T @ kc); shared KT B-frags
        #pragma unroll
        for (int ks=0;ks<2;ks++){
            sh8 a2 = *(const sh8*)(&As[w][lm*ASS + ks*32 + quad*8]);
            sh8 av = ld8_8B(&VT[(w*16+lm)*VTS + ks*32 + quad*8]);
            #pragma unroll
            for (int nb=0;nb<4;nb++){
                sh8 bk = ld8_8B(&KT[(nb*16+lm)*VTS + ks*32 + quad*8]);
                ctx[nb] = __builtin_amdgcn_mfma_f32_16x16x32_bf16(a2, bk, ctx[nb], 0,0,0);
                cz[nb]  = __builtin_amdgcn_mfma_f32_16x16x32_bf16(av, bk, cz[nb], 0,0,0);
            }
        }
    }
    #pragma unroll
    for (int nb=0;nb<4;nb++){
        #pragma unroll
        for (int r=0;r<4;r++){
            cpart[((qq*8+hd)*Ll + t_g + r)*64 + nb*16+lm] = ctx[nb][r];
        }
    }
    int ob = ((hd*16+c)*4+qq)*4096;
    #pragma unroll
    for (int nb=0;nb<4;nb++){
        #pragma unroll
        for (int r=0;r<4;r++){
            czp[ob + (w*16+quad*4+r)*64 + nb*16+lm] = cz[nb][r];
        }
    }
}

// exclusive prefix over chunks
__global__ __launch_bounds__(256) void s0_kernel(
    const float* __restrict__ czp, float* __restrict__ S0)
{
    int hd=blockIdx.x, tid=threadIdx.x;
    float accv[16];
    #pragma unroll
    for(int p=0;p<16;p++) accv[p]=0.f;
    for(int c=0;c<16;c++){
        for(int p=0;p<16;p++){ int idx=tid+p*256;
            S0[(hd*16+c)*4096 + idx] = accv[p];
            int b = ((hd*16+c)*4)*4096 + idx;
            accv[p] += czp[b] + czp[b+4096] + czp[b+2*4096] + czp[b+3*4096];
        }
    }
}

// combine: Cpk(bf16 A-frags) = factor * ( q @ S0 + sum_q cpart )
__global__ __launch_bounds__(256) void combine_kernel(
    const float* __restrict__ qh, const float* __restrict__ S0,
    const float* __restrict__ cpart, const float* __restrict__ factor,
    unsigned short* __restrict__ Cpk)
{
    __shared__ float Qs[64][65];
    __shared__ float Ss[64][64];
    __shared__ float fl[64];
    int tid=threadIdx.x, ty=tid>>4, tx=tid&15;
    int c=blockIdx.x, hd=blockIdx.y; int T0=c*64;
    for(int p=0;p<16;p++){ int e=tid+p*256; int rr=e>>6, cc=e&63;
        Qs[rr][cc]=qh[(hd*Ll+T0+rr)*64+cc];
        Ss[rr][cc]=S0[(hd*16+c)*4096 + e]; }
    if(tid<64) fl[tid]=factor[hd*Ll+T0+tid];
    __syncthreads();
    float acc[4][4]={};
    for(int d=0;d<64;d++){
        float a0[4],b0[4];
        #pragma unroll
        for(int i=0;i<4;i++) a0[i]=Qs[ty*4+i][d];
        #pragma unroll
        for(int j=0;j<4;j++) b0[j]=Ss[d][tx*4+j];
        #pragma unroll
        for(int i=0;i<4;i++)
            #pragma unroll
            for(int j=0;j<4;j++) acc[i][j]+=a0[i]*b0[j];
    }
    for(int i=0;i<4;i++){ int t=T0+ty*4+i; float f=fl[ty*4+i];
        for(int j=0;j<4;j++){ float v=acc[i][j];
            for(int q=0;q<4;q++) v += cpart[((q*8+hd)*Ll + t)*64 + tx*4+j];
            v *= f;
            int dim = hd*64 + tx*4+j;
            int mb2 = t>>4, m = t&15, ks = dim>>5, koff = dim&31;
            int qd = koff>>3, jj = koff&7;
            Cpk[(mb2*16+ks)*512 + qd*128 + m*8 + jj] = f2bf(v);
        } }
}

// out = Cpk @ Wopk + bo  (MFMA)
__global__ __launch_bounds__(256) void outprojm_kernel(
    const unsigned short* __restrict__ Cpk, const unsigned short* __restrict__ Wopk,
    const float* __restrict__ bo, float* __restrict__ out)
{
    int mt=blockIdx.x, nt=blockIdx.y;
    int tid=threadIdx.x, wid=tid>>6, lane=tid&63;
    int mb=mt*4+wid;
    f32x4 acc[4];
    #pragma unroll
    for (int nb=0;nb<4;nb++) acc[nb]=(f32x4){0.f,0.f,0.f,0.f};
    for (int ks=0;ks<16;ks++){
        sh8 a = *(const sh8*)(Cpk + (mb*16+ks)*512 + lane*8);
        #pragma unroll
        for (int nb2=0;nb2<4;nb2++){
            sh8 b = *(const sh8*)(Wopk + ((nt*4+nb2)*16+ks)*512 + lane*8);
            acc[nb2] = __builtin_amdgcn_mfma_f32_16x16x32_bf16(a, b, acc[nb2], 0,0,0);
        }
    }
    int quad=lane>>4, col=lane&15;
    #pragma unroll
    for (int nb2=0;nb2<4;nb2++){
        int n = nt*64 + nb2*16 + col;
        float bval = bo[n];
        #pragma unroll
        for (int r=0;r<4;r++){
            out[(mb*16+quad*4+r)*Dm + n] = acc[nb2][r] + bval;
        }
    }
}

extern "C" void kernel_launch(void* const* d_in, const int* in_sizes, int n_in,
                              void* d_out, int out_size, void* d_ws, size_t ws_size,
                              hipStream_t stream)
{
    (void)in_sizes; (void)n_in; (void)out_size; (void)ws_size;
    const float* x   =(const float*)d_in[0];
    const float* Wq  =(const float*)d_in[1];
    const float* bq  =(const float*)d_in[2];
    const float* Wk  =(const float*)d_in[3];
    const float* bk  =(const float*)d_in[4];
    const float* Wv  =(const float*)d_in[5];
    const float* bv  =(const float*)d_in[6];
    const float* Wo  =(const float*)d_in[7];
    const float* bo  =(const float*)d_in[8];
    const float* Wg  =(const float*)d_in[9];
    const float* bg  =(const float*)d_in[10];
    const float* kvs =(const float*)d_in[11];
    const float* qks =(const float*)d_in[12];
    const float* filt=(const float*)d_in[13];
    float* ws = (float*)d_ws;
    float* qh    = ws+OFF_QH;
    float* kn    = ws+OFF_KN;
    float* vn    = ws+OFF_VN;
    float* simg  = ws+OFF_SIM;
    float* logits= ws+OFF_LOGITS;
    float* gates = ws+OFF_GATES;
    float* factor= ws+OFF_FACTOR;
    float* czp   = ws+OFF_CZP;
    float* S0v   = ws+OFF_S0;
    float* cpart = ws+OFF_CPART;
    unsigned short* vcb  = (unsigned short*)(ws + OFF_VCB);
    unsigned short* kcb  = (unsigned short*)(ws + OFF_KCB);
    unsigned short* Qpk  = (unsigned short*)(ws + OFF_QPK);
    unsigned short* Mpk  = (unsigned short*)(ws + OFF_MPK);
    unsigned short* Wopk = (unsigned short*)(ws + OFF_WOPK);
    unsigned short* Cpk  = (unsigned short*)(ws + OFF_CPK);
    unsigned short* Fpk  = (unsigned short*)(ws + OFF_FPK_F);
    unsigned short* Upk  = (unsigned short*)(ws + OFF_UPK_F);
    unsigned short* Apk  = (unsigned short*)(ws + OFF_APK_F);
    unsigned short* Bpk  = (unsigned short*)(ws + OFF_BPK_F);
    float* out   = (float*)d_out;

    hipMemsetAsync(logits, 0, Hh*Ll*sizeof(float), stream);
    xpk_kernel    <<<dim3(64),      256,0,stream>>>(x,Apk);
    wpk_kernel    <<<dim3(96),      256,0,stream>>>(Wq,Wk,Wv,Bpk);
    qkvm_kernel   <<<dim3(16,24),   256,0,stream>>>(Apk,Bpk,bq,bk,bv,qh,kn,vn);
    nse_kernel    <<<dim3(2048),    256,0,stream>>>(qh,kn,vn,qks,simg);
    qpk_kernel    <<<dim3(64,8),    256,0,stream>>>(qh,Qpk);
    fpk_kernel    <<<dim3(24,17),   256,0,stream>>>(filt,Fpk);
    upk_kernel    <<<dim3(16,8,2),  256,0,stream>>>(vn,kn,Upk);
    mpk_kernel    <<<dim3(8),       256,0,stream>>>(kvs,Wg,Mpk);
    wopk_kernel   <<<dim3(32),      256,0,stream>>>(Wo,Wopk);
    convm_kernel  <<<dim3(8,24,16), 256,0,stream>>>(Fpk,Upk,vcb,kcb);
    mkdotm_kernel <<<dim3(384,8),   256,0,stream>>>(kcb,vcb,Mpk,logits);
    gates_kernel  <<<dim3(32),      256,0,stream>>>(logits,bg,gates);
    scan_kernel   <<<dim3(8),       256,0,stream>>>(simg,gates,factor);
    p3cz_kernel   <<<dim3(16,4,8),  256,0,stream>>>(Qpk,vcb,kcb,gates,cpart,czp);
    s0_kernel     <<<dim3(8),       256,0,stream>>>(czp,S0v);
    combine_kernel<<<dim3(16,8),    256,0,stream>>>(qh,S0v,cpart,factor,Cpk);
    outprojm_kernel<<<dim3(16,8),   256,0,stream>>>(Cpk,Wopk,bo,out);
}

// Round 5
// 240.411 us; speedup vs baseline: 4.1054x; 1.2087x over previous
//
#include <hip/hip_runtime.h>
#include <math.h>

#define Hh 8
#define Ll 1024
#define KF 24
#define Dm 512
#define EPSf 1e-5f
#define LK (Ll*KF)   // 24576 rows (t,kf) per head

typedef __attribute__((ext_vector_type(8))) short sh8;
typedef __attribute__((ext_vector_type(4))) short sh4;
typedef __attribute__((ext_vector_type(4))) float f32x4;

// ---- workspace offsets (floats) ----
#define OFF_QH     0
#define OFF_KN     524288
#define OFF_VN     1048576
#define OFF_SIM    1572864
#define OFF_LOGITS 1581056
#define OFF_GATES  1589248
#define OFF_FACTOR 1597440
#define OFF_VCB    1605632     // bf16 vc
#define OFF_KCB    7897088     // bf16 kc
#define OFF_QPK    14188544    // bf16 Q A-frags
#define OFF_MPK    14450688    // bf16 M B-frags
#define OFF_WOPK   14467072    // bf16 Wo B-frags
#define OFF_CPK    14598144    // bf16 ctxt A-frags
#define OFF_CZP    26771456
#define OFF_S0     28868608
#define OFF_CPART  29392896
// pack overlays inside CZP region (all consumed before p3cz writes czp):
#define OFF_FPK_F  26771456
#define OFF_UPK_F  27607040
#define OFF_APK_F  28131328
#define OFF_BPK_F  28393472

__device__ inline unsigned short f2bf(float x){
    unsigned int u = __float_as_uint(x);
    unsigned int r = (u + 0x7fffu + ((u>>16)&1u)) >> 16;
    return (unsigned short)r;
}
__device__ inline float bf2f(unsigned short u){ return __uint_as_float(((unsigned int)u)<<16); }
__device__ inline sh8 ld8_8B(const unsigned short* p){
    union { sh8 s; sh4 h[2]; } u;
    u.h[0] = *(const sh4*)(p);
    u.h[1] = *(const sh4*)(p+4);
    return u.s;
}

// ---------- packing kernels ----------
__global__ __launch_bounds__(256) void xpk_kernel(
    const float* __restrict__ x, unsigned short* __restrict__ Apk)
{
    int mb = blockIdx.x, tid = threadIdx.x;
    for (int ks=0; ks<16; ks++){
        #pragma unroll
        for (int p=0;p<2;p++){
            int e = tid + p*256;
            int lane = e>>3, j = e&7;
            int m = mb*16 + (lane&15);
            int k = ks*32 + ((lane>>4)&3)*8 + j;
            Apk[(mb*16+ks)*512 + e] = f2bf(x[m*Dm + k]);
        }
    }
}

__global__ __launch_bounds__(256) void wpk_kernel(
    const float* __restrict__ Wq, const float* __restrict__ Wk, const float* __restrict__ Wv,
    unsigned short* __restrict__ Bpk)
{
    int nb = blockIdx.x, tid = threadIdx.x;
    int n0 = nb*16;
    int mm = n0>>9;
    const float* W = (mm==0)?Wq:((mm==1)?Wk:Wv);
    int coff = n0 & 511;
    for (int ks=0; ks<16; ks++){
        #pragma unroll
        for (int p=0;p<2;p++){
            int e = tid + p*256;
            int lane = e>>3, j = e&7;
            int kk = ks*32 + ((lane>>4)&3)*8 + j;
            int col = coff + (lane&15);
            Bpk[(nb*16+ks)*512 + e] = f2bf(W[kk*Dm + col]);
        }
    }
}

__global__ __launch_bounds__(256) void wopk_kernel(
    const float* __restrict__ Wo, unsigned short* __restrict__ Bpk2)
{
    int nb = blockIdx.x, tid = threadIdx.x;
    int n0 = nb*16;
    for (int ks=0; ks<16; ks++){
        #pragma unroll
        for (int p=0;p<2;p++){
            int e = tid + p*256;
            int lane = e>>3, j = e&7;
            int kk = ks*32 + ((lane>>4)&3)*8 + j;
            Bpk2[(nb*16+ks)*512 + e] = f2bf(Wo[kk*Dm + n0 + (lane&15)]);
        }
    }
}

// M pack: Mpk[hd][nb(4)][ks(2)][512]
__global__ __launch_bounds__(256) void mpk_kernel(
    const float* __restrict__ kvs, const float* __restrict__ Wg,
    unsigned short* __restrict__ Mpk)
{
    int hd = blockIdx.x, tid = threadIdx.x;
    for (int it=0; it<16; it++){
        int idx = tid + it*256;
        int f = idx & 511, ksnb = idx >> 9;
        int nb = ksnb>>1, ks = ksnb&1;
        int lane = f>>3, j = f&7;
        int e = nb*16 + (lane&15);
        int d = ks*32 + ((lane>>4)&3)*8 + j;
        Mpk[hd*4096 + idx] = f2bf(kvs[(hd*64+e)*64 + d]*Wg[e*64+d]);
    }
}

// ---------- QKV MFMA GEMM ----------
__global__ __launch_bounds__(256) void qkvm_kernel(
    const unsigned short* __restrict__ Apk, const unsigned short* __restrict__ Bpk,
    const float* __restrict__ bq, const float* __restrict__ bk, const float* __restrict__ bv,
    float* __restrict__ qh, float* __restrict__ kn, float* __restrict__ vn)
{
    int mt = blockIdx.x, nt = blockIdx.y;
    int tid = threadIdx.x, wid = tid>>6, lane = tid&63;
    int mb = mt*4 + wid;
    f32x4 acc[4];
    #pragma unroll
    for (int nb=0;nb<4;nb++) acc[nb]=(f32x4){0.f,0.f,0.f,0.f};
    for (int ks=0; ks<16; ks++){
        sh8 a = *(const sh8*)(Apk + (mb*16+ks)*512 + lane*8);
        #pragma unroll
        for (int nb2=0;nb2<4;nb2++){
            sh8 b = *(const sh8*)(Bpk + ((nt*4+nb2)*16+ks)*512 + lane*8);
            acc[nb2] = __builtin_amdgcn_mfma_f32_16x16x32_bf16(a, b, acc[nb2], 0,0,0);
        }
    }
    int mm = nt>>3, hd = nt&7;
    const float* bias = (mm==0)?bq:((mm==1)?bk:bv);
    float* dst = (mm==0)?qh:((mm==1)?kn:vn);
    int quad = lane>>4, col = lane&15;
    #pragma unroll
    for (int nb2=0;nb2<4;nb2++){
        int d = nb2*16 + col;
        float bval = bias[hd*64+d];
        #pragma unroll
        for (int r=0;r<4;r++){
            int t = mb*16 + quad*4 + r;
            dst[(hd*Ll + t)*64 + d] = acc[nb2][r] + bval;
        }
    }
}

// nse: per-row sim; normalize k,v and write DIRECTLY as packed bf16 (Upk) + pack q (Qpk)
__global__ __launch_bounds__(256) void nse_kernel(
    const float* __restrict__ qh, const float* __restrict__ kn, const float* __restrict__ vn,
    const float* __restrict__ qks, float* __restrict__ simg,
    unsigned short* __restrict__ Upk, unsigned short* __restrict__ Qpk)
{
    int gw = blockIdx.x*4 + (threadIdx.x>>6);   // hd*1024 + t
    int lane = threadIdx.x & 63;                 // = d
    int hd = gw>>10, t = gw&1023;
    int base = gw*64 + lane;
    float q = qh[base], k = kn[base], v = vn[base];
    float sim = q*k, k2 = k*k, v2 = v*v;
    #pragma unroll
    for (int off=32; off; off>>=1){
        sim += __shfl_xor(sim, off, 64);
        k2  += __shfl_xor(k2,  off, 64);
        v2  += __shfl_xor(v2,  off, 64);
    }
    float kfv = k * (1.f/fmaxf(sqrtf(k2), 1e-12f));
    float vfv = v * (1.f/fmaxf(sqrtf(v2), 1e-12f));
    int d = lane;
    // Upk[z][ST][ks*2048 + nb*512 + fl*8 + j]
    int ST = t>>6, ks = (t>>5)&1, j = t&7;
    int frag = ks*2048 + (d>>4)*512 + (((t>>3)&3)*16 + (d&15))*8 + j;
    Upk[((hd*16) + ST)*4096 + frag]        = f2bf(vfv);   // tensor 0 = v
    Upk[(((8+hd)*16) + ST)*4096 + frag]    = f2bf(kfv);   // tensor 1 = k
    // Qpk[hd][mb][ks2][fl2*8+j2]
    int mb = t>>4, ks2 = d>>5, j2 = d&7;
    int fl2 = ((d>>3)&3)*16 + (t&15);
    Qpk[((hd*64+mb)*2+ks2)*512 + fl2*8 + j2] = f2bf(q);
    if (lane==0) simg[gw] = sim * qks[hd];
}

// Toeplitz filter blocks (bf16, A-frag order)
__global__ __launch_bounds__(256) void fpk_kernel(
    const float* __restrict__ filt, unsigned short* __restrict__ Fpk)
{
    int kf = blockIdx.x, dslot = blockIdx.y, tid = threadIdx.x;
    unsigned short* dst = Fpk + (kf*17 + dslot)*4096;
    for (int p=0;p<16;p++){
        int e = tid + p*256;
        int j = e&7, lane = (e>>3)&63, ks = (e>>9)&1, mb = (e>>10)&3;
        int m = mb*16 + (lane&15);
        int k = ks*32 + (lane>>4)*8 + j;
        int fidx = (dslot-1)*64 + m - k;
        float v = (fidx>=0 && fidx<Ll) ? filt[fidx*KF+kf] : 0.0f;
        dst[e] = f2bf(v);
    }
}

// ---------- conv: B-tile LDS-shared, 2 kf per block, double-buffered ----------
__global__ __launch_bounds__(256) void convm_kernel(
    const unsigned short* __restrict__ Fpk, const unsigned short* __restrict__ Upk,
    unsigned short* __restrict__ vcb, unsigned short* __restrict__ kcb)
{
    __shared__ unsigned short lds[9216];   // union: B ping-pong 2*4096 | C staging 128*72
    int TT = 7 - blockIdx.x;               // big tiles first
    int kf0 = blockIdx.y*2, z = blockIdx.z;
    int tensor = z>>3, hd = z&7;
    unsigned short* dst = tensor ? kcb : vcb;
    int tid=threadIdx.x, wid=tid>>6, lane=tid&63;
    int hf=wid>>1, mb0=(wid&1)*2;
    const unsigned short* Fk0 = Fpk + (kf0*17)*4096;
    const unsigned short* Fk1 = Fpk + ((kf0+1)*17)*4096;
    const unsigned short* Uz  = Upk + z*16*4096;

    f32x4 acc[2][2][4];
    #pragma unroll
    for (int kf=0;kf<2;kf++)
        #pragma unroll
        for (int i=0;i<2;i++)
            #pragma unroll
            for (int nb=0;nb<4;nb++) acc[kf][i][nb]=(f32x4){0.f,0.f,0.f,0.f};

    int STend = 2*TT + 2;
    // prologue: stage B(0) -> buf0 (each wave covers 2 of 8 segments)
    {
        sh8 s0 = *(const sh8*)(Uz + wid*1024 + lane*8);
        sh8 s1 = *(const sh8*)(Uz + wid*1024 + 512 + lane*8);
        *(sh8*)(&lds[wid*1024 + lane*8]) = s0;
        *(sh8*)(&lds[wid*1024 + 512 + lane*8]) = s1;
    }
    for (int ST=0; ST<STend; ST++){
        sh8 n0, n1;
        bool more = (ST+1 < STend);
        if (more){
            const unsigned short* Un = Uz + (ST+1)*4096;
            n0 = *(const sh8*)(Un + wid*1024 + lane*8);
            n1 = *(const sh8*)(Un + wid*1024 + 512 + lane*8);
        }
        // A fragments (direct; L1-resident across the 2 waves sharing each dslot tile)
        int dslot = 2*TT + hf - ST + 1;
        sh8 a[2][2][2];
        #pragma unroll
        for (int i=0;i<2;i++)
            #pragma unroll
            for (int ks=0;ks<2;ks++){
                a[0][i][ks] = *(const sh8*)(Fk0 + dslot*4096 + (mb0+i)*1024 + ks*512 + lane*8);
                a[1][i][ks] = *(const sh8*)(Fk1 + dslot*4096 + (mb0+i)*1024 + ks*512 + lane*8);
            }
        __syncthreads();   // buf[ST&1] ready; prev iter fully done
        const unsigned short* Bb = &lds[(ST&1)*4096];
        #pragma unroll
        for (int ks=0;ks<2;ks++)
            #pragma unroll
            for (int nb=0;nb<4;nb++){
                sh8 b = *(const sh8*)(Bb + ks*2048 + nb*512 + lane*8);
                #pragma unroll
                for (int kf=0;kf<2;kf++)
                    #pragma unroll
                    for (int i=0;i<2;i++)
                        acc[kf][i][nb] = __builtin_amdgcn_mfma_f32_16x16x32_bf16(
                            a[kf][i][ks], b, acc[kf][i][nb], 0,0,0);
            }
        if (more){
            unsigned short* Bn = &lds[((ST+1)&1)*4096];
            *(sh8*)(Bn + wid*1024 + lane*8) = n0;
            *(sh8*)(Bn + wid*1024 + 512 + lane*8) = n1;
        }
    }
    // epilogue: stage bf16 C in LDS (stride 72 = 144B, 16B-aligned rows), 16B stores
    int quad=lane>>4, col=lane&15;
    #pragma unroll
    for (int kf=0;kf<2;kf++){
        __syncthreads();
        #pragma unroll
        for (int i=0;i<2;i++)
            #pragma unroll
            for (int nb=0;nb<4;nb++)
                #pragma unroll
                for (int r=0;r<4;r++){
                    int tl = hf*64 + (mb0+i)*16 + quad*4 + r;
                    lds[tl*72 + nb*16 + col] = f2bf(acc[kf][i][nb][r]);
                }
        __syncthreads();
        #pragma unroll
        for (int it=0; it<4; it++){
            int idx = tid + it*256;            // 1024 segments of 8 ushorts
            int row = idx>>3, seg = idx&7;
            sh8 v = *(const sh8*)(&lds[row*72 + seg*8]);
            *(sh8*)(dst + ((hd*Ll + TT*128 + row)*KF + kf0+kf)*64 + seg*8) = v;
        }
    }
}

// ---------- mkdot MFMA ----------
__global__ __launch_bounds__(256) void mkdotm_kernel(
    const unsigned short* __restrict__ kcb, const unsigned short* __restrict__ vcb,
    const unsigned short* __restrict__ Mpk, float* __restrict__ logits)
{
    __shared__ unsigned short Vs[64*66];
    int tid=threadIdx.x, w=tid>>6, lane=tid&63, quad=lane>>4, lm=lane&15;
    int R0=blockIdx.x*64, hd=blockIdx.y;
    const unsigned short* kb = kcb + (hd*LK + R0)*64;
    const unsigned short* vb = vcb + (hd*LK + R0)*64;
    #pragma unroll
    for (int it=0; it<2; it++){
        int idx = tid + it*256;
        int row = idx>>3, e0 = (idx&7)*8;
        sh8 v = *(const sh8*)(vb + row*64 + e0);
        #pragma unroll
        for (int i2=0;i2<4;i2++){
            unsigned int pv = (unsigned int)(unsigned short)v[2*i2]
                            | ((unsigned int)(unsigned short)v[2*i2+1]<<16);
            *(unsigned int*)(&Vs[row*66 + e0 + 2*i2]) = pv;
        }
    }
    f32x4 acc[4];
    #pragma unroll
    for (int nb=0;nb<4;nb++) acc[nb]=(f32x4){0.f,0.f,0.f,0.f};
    const unsigned short* mb = Mpk + hd*4096;
    #pragma unroll
    for (int ks=0;ks<2;ks++){
        sh8 a = *(const sh8*)(kb + (w*16+lm)*64 + ks*32 + quad*8);
        #pragma unroll
        for (int nb=0;nb<4;nb++){
            sh8 bm = *(const sh8*)(mb + (nb*2+ks)*512 + lane*8);
            acc[nb] = __builtin_amdgcn_mfma_f32_16x16x32_bf16(a, bm, acc[nb], 0,0,0);
        }
    }
    __syncthreads();
    float p[4];
    #pragma unroll
    for (int r=0;r<4;r++){
        int rloc = w*16 + quad*4 + r;
        float s = 0.f;
        #pragma unroll
        for (int nb=0;nb<4;nb++)
            s += acc[nb][r]*bf2f(Vs[rloc*66 + nb*16 + lm]);
        p[r] = s;
    }
    #pragma unroll
    for (int off=1; off<16; off<<=1){
        #pragma unroll
        for (int r=0;r<4;r++) p[r] += __shfl_xor(p[r], off, 64);
    }
    if (lm==0){
        #pragma unroll
        for (int r=0;r<4;r++){
            int rowg = R0 + w*16 + quad*4 + r;
            atomicAdd(&logits[hd*Ll + rowg/KF], p[r]);
        }
    }
}

// scan (fused gates): logits -> gates, factor
__global__ __launch_bounds__(256) void scan_kernel(
    const float* __restrict__ simg, const float* __restrict__ logits,
    const float* __restrict__ bg, float* __restrict__ gates, float* __restrict__ factor)
{
    int hd=blockIdx.x, tid=threadIdx.x;
    __shared__ float sm[256], ssc[256], sg[256];
    float bgv = bg[0];
    float simv[4], m_loc[4], s_loc[4], g_loc[4];
    float m = -__builtin_inff(), s = 0.f, g = 0.f;
    for(int e=0;e<4;e++){
        int ix = hd*Ll + tid*4 + e;
        simv[e] = simg[ix];
        float lg = logits[ix] + bgv;
        float r = fmaxf(lg, 0.f);
        float gv = r*r + EPSf;
        gates[ix] = gv;
        float mn = fmaxf(m, simv[e]);
        s = s*__expf(m-mn) + __expf(simv[e]-mn);
        m = mn; g += gv;
        m_loc[e]=m; s_loc[e]=s; g_loc[e]=g;
    }
    sm[tid]=m; ssc[tid]=s; sg[tid]=g;
    __syncthreads();
    for(int off=1; off<256; off<<=1){
        float pm=0, ps=0, pg=0; bool has = (tid>=off);
        if(has){ pm=sm[tid-off]; ps=ssc[tid-off]; pg=sg[tid-off]; }
        __syncthreads();
        if(has){
            float mn=fmaxf(pm, sm[tid]);
            float sn=ps*__expf(pm-mn) + ssc[tid]*__expf(sm[tid]-mn);
            sm[tid]=mn; ssc[tid]=sn; sg[tid]=pg+sg[tid];
        }
        __syncthreads();
    }
    float pm=-__builtin_inff(), ps=0.f, pg=0.f;
    if (tid>0){ pm=sm[tid-1]; ps=ssc[tid-1]; pg=sg[tid-1]; }
    for(int e=0;e<4;e++){
        float mn=fmaxf(pm, m_loc[e]);
        float sn=ps*__expf(pm-mn) + s_loc[e]*__expf(m_loc[e]-mn);
        float gn=pg + g_loc[e];
        float sw = __expf(simv[e]-mn)/(sn+EPSf);
        float silu = sw/(1.f+__expf(-sw));
        factor[hd*Ll + tid*4 + e] = (1.f+silu)/(gn+EPSf);
    }
}

// ---------- fused phase3 + chunkz (MFMA) ----------
#define VTS 68
#define ASS 72
__global__ __launch_bounds__(256) void p3cz_kernel(
    const unsigned short* __restrict__ Qpk,
    const unsigned short* __restrict__ vcb, const unsigned short* __restrict__ kcb,
    const float* __restrict__ gates, float* __restrict__ cpart, float* __restrict__ czp)
{
    __shared__ unsigned short VT[64*VTS];
    __shared__ unsigned short KT[64*VTS];
    __shared__ unsigned short As[4][16*ASS];
    __shared__ float gl[16];
    int tid=threadIdx.x, w=tid>>6, lane=tid&63;
    int quad=lane>>4, lm=lane&15;
    int c=blockIdx.x, qq=blockIdx.y, hd=blockIdx.z;
    int T0=c*64, tq0=T0+qq*16, RQ0=tq0*KF;
    if (tid<16) gl[tid]=gates[hd*Ll+tq0+tid];
    sh8 aq[2];
    {
        const unsigned short* qb = Qpk + ((hd*64 + (c*4+w))*2)*512;
        aq[0] = *(const sh8*)(qb + lane*8);
        aq[1] = *(const sh8*)(qb + 512 + lane*8);
    }
    f32x4 ctx[4], cz[4];
    #pragma unroll
    for (int nb=0;nb<4;nb++){ ctx[nb]=(f32x4){0,0,0,0}; cz[nb]=(f32x4){0,0,0,0}; }
    int t_g = T0 + w*16 + quad*4;
    int rp = tid>>3, e0 = (tid&7)*8, r0 = rp*2;

    for (int sub=0; sub<6; sub++){
        int RB = RQ0 + sub*64;
        const unsigned short* vrow = vcb + (hd*LK + RB)*64;
        const unsigned short* krow = kcb + (hd*LK + RB)*64;
        __syncthreads();
        {
            float g0 = gl[(RB + r0)/KF - tq0];
            float g1 = gl[(RB + r0 + 1)/KF - tq0];
            sh8 v0 = *(const sh8*)(vrow + r0*64 + e0);
            sh8 v1 = *(const sh8*)(vrow + (r0+1)*64 + e0);
            sh8 k0 = *(const sh8*)(krow + r0*64 + e0);
            sh8 k1 = *(const sh8*)(krow + (r0+1)*64 + e0);
            #pragma unroll
            for (int j=0;j<8;j++){
                unsigned int pv = (unsigned int)f2bf(bf2f((unsigned short)v0[j])*g0)
                                | ((unsigned int)f2bf(bf2f((unsigned short)v1[j])*g1)<<16);
                *(unsigned int*)(&VT[(e0+j)*VTS + r0]) = pv;
                unsigned int pk = (unsigned int)(unsigned short)k0[j]
                                | ((unsigned int)(unsigned short)k1[j]<<16);
                *(unsigned int*)(&KT[(e0+j)*VTS + r0]) = pk;
            }
        }
        f32x4 S[4];
        #pragma unroll
        for (int nb=0;nb<4;nb++) S[nb]=(f32x4){0,0,0,0};
        #pragma unroll
        for (int ks=0;ks<2;ks++){
            #pragma unroll
            for (int nb=0;nb<4;nb++){
                sh8 b = *(const sh8*)(vrow + (nb*16+lm)*64 + ks*32 + quad*8);
                S[nb] = __builtin_amdgcn_mfma_f32_16x16x32_bf16(aq[ks], b, S[nb], 0,0,0);
            }
        }
        #pragma unroll
        for (int nb=0;nb<4;nb++){
            int row_l = nb*16+lm;
            int tp = (RB + row_l)/KF;
            float g = gl[tp - tq0];
            #pragma unroll
            for (int r=0;r<4;r++){
                float v = (t_g + r >= tp) ? S[nb][r]*g : 0.f;
                As[w][(quad*4+r)*ASS + row_l] = f2bf(v);
            }
        }
        __syncthreads();
        #pragma unroll
        for (int ks=0;ks<2;ks++){
            sh8 a2 = *(const sh8*)(&As[w][lm*ASS + ks*32 + quad*8]);
            sh8 av = ld8_8B(&VT[(w*16+lm)*VTS + ks*32 + quad*8]);
            #pragma unroll
            for (int nb=0;nb<4;nb++){
                sh8 bk = ld8_8B(&KT[(nb*16+lm)*VTS + ks*32 + quad*8]);
                ctx[nb] = __builtin_amdgcn_mfma_f32_16x16x32_bf16(a2, bk, ctx[nb], 0,0,0);
                cz[nb]  = __builtin_amdgcn_mfma_f32_16x16x32_bf16(av, bk, cz[nb], 0,0,0);
            }
        }
    }
    #pragma unroll
    for (int nb=0;nb<4;nb++){
        #pragma unroll
        for (int r=0;r<4;r++){
            cpart[((qq*8+hd)*Ll + t_g + r)*64 + nb*16+lm] = ctx[nb][r];
        }
    }
    int ob = ((hd*16+c)*4+qq)*4096;
    #pragma unroll
    for (int nb=0;nb<4;nb++){
        #pragma unroll
        for (int r=0;r<4;r++){
            czp[ob + (w*16+quad*4+r)*64 + nb*16+lm] = cz[nb][r];
        }
    }
}

// exclusive chunk prefix, parallel over (hd, idx)
__global__ __launch_bounds__(256) void s0_kernel(
    const float* __restrict__ czp, float* __restrict__ S0)
{
    int idx = blockIdx.x*256 + threadIdx.x;   // 0..4095
    int hd = blockIdx.y;
    float a = 0.f;
    for (int c=0;c<16;c++){
        S0[(hd*16+c)*4096 + idx] = a;
        int b = ((hd*16+c)*4)*4096 + idx;
        a += czp[b] + czp[b+4096] + czp[b+2*4096] + czp[b+3*4096];
    }
}

// combine: Cpk(bf16 A-frags) = factor * ( q @ S0 + sum_q cpart )
__global__ __launch_bounds__(256) void combine_kernel(
    const float* __restrict__ qh, const float* __restrict__ S0,
    const float* __restrict__ cpart, const float* __restrict__ factor,
    unsigned short* __restrict__ Cpk)
{
    __shared__ float Qs[64][65];
    __shared__ float Ss[64][64];
    __shared__ float fl[64];
    int tid=threadIdx.x, ty=tid>>4, tx=tid&15;
    int c=blockIdx.x, hd=blockIdx.y; int T0=c*64;
    for(int p=0;p<16;p++){ int e=tid+p*256; int rr=e>>6, cc=e&63;
        Qs[rr][cc]=qh[(hd*Ll+T0+rr)*64+cc];
        Ss[rr][cc]=S0[(hd*16+c)*4096 + e]; }
    if(tid<64) fl[tid]=factor[hd*Ll+T0+tid];
    __syncthreads();
    float acc[4][4]={};
    for(int d=0;d<64;d++){
        float a0[4],b0[4];
        #pragma unroll
        for(int i=0;i<4;i++) a0[i]=Qs[ty*4+i][d];
        #pragma unroll
        for(int j=0;j<4;j++) b0[j]=Ss[d][tx*4+j];
        #pragma unroll
        for(int i=0;i<4;i++)
            #pragma unroll
            for(int j=0;j<4;j++) acc[i][j]+=a0[i]*b0[j];
    }
    for(int i=0;i<4;i++){ int t=T0+ty*4+i; float f=fl[ty*4+i];
        for(int j=0;j<4;j++){ float v=acc[i][j];
            for(int q=0;q<4;q++) v += cpart[((q*8+hd)*Ll + t)*64 + tx*4+j];
            v *= f;
            int dim = hd*64 + tx*4+j;
            int mb2 = t>>4, m = t&15, ks = dim>>5, koff = dim&31;
            int qd = koff>>3, jj = koff&7;
            Cpk[(mb2*16+ks)*512 + qd*128 + m*8 + jj] = f2bf(v);
        } }
}

// out = Cpk @ Wopk + bo
__global__ __launch_bounds__(256) void outprojm_kernel(
    const unsigned short* __restrict__ Cpk, const unsigned short* __restrict__ Wopk,
    const float* __restrict__ bo, float* __restrict__ out)
{
    int mt=blockIdx.x, nt=blockIdx.y;
    int tid=threadIdx.x, wid=tid>>6, lane=tid&63;
    int mb=mt*4+wid;
    f32x4 acc[4];
    #pragma unroll
    for (int nb=0;nb<4;nb++) acc[nb]=(f32x4){0.f,0.f,0.f,0.f};
    for (int ks=0;ks<16;ks++){
        sh8 a = *(const sh8*)(Cpk + (mb*16+ks)*512 + lane*8);
        #pragma unroll
        for (int nb2=0;nb2<4;nb2++){
            sh8 b = *(const sh8*)(Wopk + ((nt*4+nb2)*16+ks)*512 + lane*8);
            acc[nb2] = __builtin_amdgcn_mfma_f32_16x16x32_bf16(a, b, acc[nb2], 0,0,0);
        }
    }
    int quad=lane>>4, col=lane&15;
    #pragma unroll
    for (int nb2=0;nb2<4;nb2++){
        int n = nt*64 + nb2*16 + col;
        float bval = bo[n];
        #pragma unroll
        for (int r=0;r<4;r++){
            out[(mb*16+quad*4+r)*Dm + n] = acc[nb2][r] + bval;
        }
    }
}

extern "C" void kernel_launch(void* const* d_in, const int* in_sizes, int n_in,
                              void* d_out, int out_size, void* d_ws, size_t ws_size,
                              hipStream_t stream)
{
    (void)in_sizes; (void)n_in; (void)out_size; (void)ws_size;
    const float* x   =(const float*)d_in[0];
    const float* Wq  =(const float*)d_in[1];
    const float* bq  =(const float*)d_in[2];
    const float* Wk  =(const float*)d_in[3];
    const float* bk  =(const float*)d_in[4];
    const float* Wv  =(const float*)d_in[5];
    const float* bv  =(const float*)d_in[6];
    const float* Wo  =(const float*)d_in[7];
    const float* bo  =(const float*)d_in[8];
    const float* Wg  =(const float*)d_in[9];
    const float* bg  =(const float*)d_in[10];
    const float* kvs =(const float*)d_in[11];
    const float* qks =(const float*)d_in[12];
    const float* filt=(const float*)d_in[13];
    float* ws = (float*)d_ws;
    float* qh    = ws+OFF_QH;
    float* kn    = ws+OFF_KN;
    float* vn    = ws+OFF_VN;
    float* simg  = ws+OFF_SIM;
    float* logits= ws+OFF_LOGITS;
    float* gates = ws+OFF_GATES;
    float* factor= ws+OFF_FACTOR;
    float* czp   = ws+OFF_CZP;
    float* S0v   = ws+OFF_S0;
    float* cpart = ws+OFF_CPART;
    unsigned short* vcb  = (unsigned short*)(ws + OFF_VCB);
    unsigned short* kcb  = (unsigned short*)(ws + OFF_KCB);
    unsigned short* Qpk  = (unsigned short*)(ws + OFF_QPK);
    unsigned short* Mpk  = (unsigned short*)(ws + OFF_MPK);
    unsigned short* Wopk = (unsigned short*)(ws + OFF_WOPK);
    unsigned short* Cpk  = (unsigned short*)(ws + OFF_CPK);
    unsigned short* Fpk  = (unsigned short*)(ws + OFF_FPK_F);
    unsigned short* Upk  = (unsigned short*)(ws + OFF_UPK_F);
    unsigned short* Apk  = (unsigned short*)(ws + OFF_APK_F);
    unsigned short* Bpk  = (unsigned short*)(ws + OFF_BPK_F);
    float* out   = (float*)d_out;

    hipMemsetAsync(logits, 0, Hh*Ll*sizeof(float), stream);
    xpk_kernel    <<<dim3(64),      256,0,stream>>>(x,Apk);
    wpk_kernel    <<<dim3(96),      256,0,stream>>>(Wq,Wk,Wv,Bpk);
    qkvm_kernel   <<<dim3(16,24),   256,0,stream>>>(Apk,Bpk,bq,bk,bv,qh,kn,vn);
    nse_kernel    <<<dim3(2048),    256,0,stream>>>(qh,kn,vn,qks,simg,Upk,Qpk);
    fpk_kernel    <<<dim3(24,17),   256,0,stream>>>(filt,Fpk);
    mpk_kernel    <<<dim3(8),       256,0,stream>>>(kvs,Wg,Mpk);
    wopk_kernel   <<<dim3(32),      256,0,stream>>>(Wo,Wopk);
    convm_kernel  <<<dim3(8,12,16), 256,0,stream>>>(Fpk,Upk,vcb,kcb);
    mkdotm_kernel <<<dim3(384,8),   256,0,stream>>>(kcb,vcb,Mpk,logits);
    scan_kernel   <<<dim3(8),       256,0,stream>>>(simg,logits,bg,gates,factor);
    p3cz_kernel   <<<dim3(16,4,8),  256,0,stream>>>(Qpk,vcb,kcb,gates,cpart,czp);
    s0_kernel     <<<dim3(16,8),    256,0,stream>>>(czp,S0v);
    combine_kernel<<<dim3(16,8),    256,0,stream>>>(qh,S0v,cpart,factor,Cpk);
    outprojm_kernel<<<dim3(16,8),   256,0,stream>>>(Cpk,Wopk,bo,out);
}

// Round 6
// 206.370 us; speedup vs baseline: 4.7826x; 1.1650x over previous
//
#include <hip/hip_runtime.h>
#include <math.h>

#define Hh 8
#define Ll 1024
#define KF 24
#define Dm 512
#define EPSf 1e-5f
#define LK (Ll*KF)   // 24576 rows (t,kf) per head

typedef __attribute__((ext_vector_type(8))) short sh8;
typedef __attribute__((ext_vector_type(4))) short sh4;
typedef __attribute__((ext_vector_type(4))) float f32x4;

// ---- workspace offsets (floats) ----
#define OFF_QH     0
#define OFF_KN     524288
#define OFF_VN     1048576
#define OFF_SIM    1572864
#define OFF_LOGITS 1581056
#define OFF_GATES  1589248
#define OFF_FACTOR 1597440
#define OFF_VCB    1605632     // bf16 vc
#define OFF_KCB    7897088     // bf16 kc
#define OFF_QPK    14188544    // bf16 Q A-frags
#define OFF_MPK    14450688    // bf16 M B-frags
#define OFF_WOPK   14467072    // bf16 Wo B-frags
#define OFF_CPK    14598144    // bf16 ctxt A-frags
#define OFF_CZP    26771456
#define OFF_S0     28868608    // bf16 S0 B-frags (as ushort)
#define OFF_CPART  29392896
// pack overlays inside CZP region (all consumed before p3cz writes czp):
#define OFF_FPK_F  26771456
#define OFF_UPK_F  27607040
#define OFF_APK_F  28131328
#define OFF_BPK_F  28393472

__device__ inline unsigned short f2bf(float x){
    unsigned int u = __float_as_uint(x);
    unsigned int r = (u + 0x7fffu + ((u>>16)&1u)) >> 16;
    return (unsigned short)r;
}
__device__ inline float bf2f(unsigned short u){ return __uint_as_float(((unsigned int)u)<<16); }
__device__ inline sh8 ld8_8B(const unsigned short* p){
    union { sh8 s; sh4 h[2]; } u;
    u.h[0] = *(const sh4*)(p);
    u.h[1] = *(const sh4*)(p+4);
    return u.s;
}

// ---------- packing kernels ----------
__global__ __launch_bounds__(256) void xpk_kernel(
    const float* __restrict__ x, unsigned short* __restrict__ Apk)
{
    int mb = blockIdx.x, tid = threadIdx.x;
    for (int ks=0; ks<16; ks++){
        #pragma unroll
        for (int p=0;p<2;p++){
            int e = tid + p*256;
            int lane = e>>3, j = e&7;
            int m = mb*16 + (lane&15);
            int k = ks*32 + ((lane>>4)&3)*8 + j;
            Apk[(mb*16+ks)*512 + e] = f2bf(x[m*Dm + k]);
        }
    }
}

__global__ __launch_bounds__(256) void wpk_kernel(
    const float* __restrict__ Wq, const float* __restrict__ Wk, const float* __restrict__ Wv,
    unsigned short* __restrict__ Bpk)
{
    int nb = blockIdx.x, tid = threadIdx.x;
    int n0 = nb*16;
    int mm = n0>>9;
    const float* W = (mm==0)?Wq:((mm==1)?Wk:Wv);
    int coff = n0 & 511;
    for (int ks=0; ks<16; ks++){
        #pragma unroll
        for (int p=0;p<2;p++){
            int e = tid + p*256;
            int lane = e>>3, j = e&7;
            int kk = ks*32 + ((lane>>4)&3)*8 + j;
            int col = coff + (lane&15);
            Bpk[(nb*16+ks)*512 + e] = f2bf(W[kk*Dm + col]);
        }
    }
}

__global__ __launch_bounds__(256) void wopk_kernel(
    const float* __restrict__ Wo, unsigned short* __restrict__ Bpk2)
{
    int nb = blockIdx.x, tid = threadIdx.x;
    int n0 = nb*16;
    for (int ks=0; ks<16; ks++){
        #pragma unroll
        for (int p=0;p<2;p++){
            int e = tid + p*256;
            int lane = e>>3, j = e&7;
            int kk = ks*32 + ((lane>>4)&3)*8 + j;
            Bpk2[(nb*16+ks)*512 + e] = f2bf(Wo[kk*Dm + n0 + (lane&15)]);
        }
    }
}

// M pack: Mpk[hd][nb(4)][ks(2)][512]
__global__ __launch_bounds__(256) void mpk_kernel(
    const float* __restrict__ kvs, const float* __restrict__ Wg,
    unsigned short* __restrict__ Mpk)
{
    int hd = blockIdx.x, tid = threadIdx.x;
    for (int it=0; it<16; it++){
        int idx = tid + it*256;
        int f = idx & 511, ksnb = idx >> 9;
        int nb = ksnb>>1, ks = ksnb&1;
        int lane = f>>3, j = f&7;
        int e = nb*16 + (lane&15);
        int d = ks*32 + ((lane>>4)&3)*8 + j;
        Mpk[hd*4096 + idx] = f2bf(kvs[(hd*64+e)*64 + d]*Wg[e*64+d]);
    }
}

// ---------- QKV MFMA GEMM ----------
__global__ __launch_bounds__(256) void qkvm_kernel(
    const unsigned short* __restrict__ Apk, const unsigned short* __restrict__ Bpk,
    const float* __restrict__ bq, const float* __restrict__ bk, const float* __restrict__ bv,
    float* __restrict__ qh, float* __restrict__ kn, float* __restrict__ vn)
{
    int mt = blockIdx.x, nt = blockIdx.y;
    int tid = threadIdx.x, wid = tid>>6, lane = tid&63;
    int mb = mt*4 + wid;
    f32x4 acc[4];
    #pragma unroll
    for (int nb=0;nb<4;nb++) acc[nb]=(f32x4){0.f,0.f,0.f,0.f};
    for (int ks=0; ks<16; ks++){
        sh8 a = *(const sh8*)(Apk + (mb*16+ks)*512 + lane*8);
        #pragma unroll
        for (int nb2=0;nb2<4;nb2++){
            sh8 b = *(const sh8*)(Bpk + ((nt*4+nb2)*16+ks)*512 + lane*8);
            acc[nb2] = __builtin_amdgcn_mfma_f32_16x16x32_bf16(a, b, acc[nb2], 0,0,0);
        }
    }
    int mm = nt>>3, hd = nt&7;
    const float* bias = (mm==0)?bq:((mm==1)?bk:bv);
    float* dst = (mm==0)?qh:((mm==1)?kn:vn);
    int quad = lane>>4, col = lane&15;
    #pragma unroll
    for (int nb2=0;nb2<4;nb2++){
        int d = nb2*16 + col;
        float bval = bias[hd*64+d];
        #pragma unroll
        for (int r=0;r<4;r++){
            int t = mb*16 + quad*4 + r;
            dst[(hd*Ll + t)*64 + d] = acc[nb2][r] + bval;
        }
    }
}

// nse: per-row sim; normalize k,v -> packed bf16 (Upk) + pack q (Qpk)
__global__ __launch_bounds__(256) void nse_kernel(
    const float* __restrict__ qh, const float* __restrict__ kn, const float* __restrict__ vn,
    const float* __restrict__ qks, float* __restrict__ simg,
    unsigned short* __restrict__ Upk, unsigned short* __restrict__ Qpk)
{
    int gw = blockIdx.x*4 + (threadIdx.x>>6);   // hd*1024 + t
    int lane = threadIdx.x & 63;                 // = d
    int hd = gw>>10, t = gw&1023;
    int base = gw*64 + lane;
    float q = qh[base], k = kn[base], v = vn[base];
    float sim = q*k, k2 = k*k, v2 = v*v;
    #pragma unroll
    for (int off=32; off; off>>=1){
        sim += __shfl_xor(sim, off, 64);
        k2  += __shfl_xor(k2,  off, 64);
        v2  += __shfl_xor(v2,  off, 64);
    }
    float kfv = k * (1.f/fmaxf(sqrtf(k2), 1e-12f));
    float vfv = v * (1.f/fmaxf(sqrtf(v2), 1e-12f));
    int d = lane;
    int ST = t>>6, ks = (t>>5)&1, j = t&7;
    int frag = ks*2048 + (d>>4)*512 + (((t>>3)&3)*16 + (d&15))*8 + j;
    Upk[((hd*16) + ST)*4096 + frag]        = f2bf(vfv);   // tensor 0 = v
    Upk[(((8+hd)*16) + ST)*4096 + frag]    = f2bf(kfv);   // tensor 1 = k
    int mb = t>>4, ks2 = d>>5, j2 = d&7;
    int fl2 = ((d>>3)&3)*16 + (t&15);
    Qpk[((hd*64+mb)*2+ks2)*512 + fl2*8 + j2] = f2bf(q);
    if (lane==0) simg[gw] = sim * qks[hd];
}

// Toeplitz filter blocks (bf16, A-frag order)
__global__ __launch_bounds__(256) void fpk_kernel(
    const float* __restrict__ filt, unsigned short* __restrict__ Fpk)
{
    int kf = blockIdx.x, dslot = blockIdx.y, tid = threadIdx.x;
    unsigned short* dst = Fpk + (kf*17 + dslot)*4096;
    for (int p=0;p<16;p++){
        int e = tid + p*256;
        int j = e&7, lane = (e>>3)&63, ks = (e>>9)&1, mb = (e>>10)&3;
        int m = mb*16 + (lane&15);
        int k = ks*32 + (lane>>4)*8 + j;
        int fidx = (dslot-1)*64 + m - k;
        float v = (fidx>=0 && fidx<Ll) ? filt[fidx*KF+kf] : 0.0f;
        dst[e] = f2bf(v);
    }
}

// ---------- fused conv (both tensors) + mkdot logits ----------
// grid (8 TT, 12 kf-pairs, 8 hd); 4 waves; A amortized over 2 tensors.
// LDS: main 2-buf x 2-tensor B (16K ush) UNION epilogue 2x[128x72] staging (18432 ush)
__global__ __launch_bounds__(256,2) void convf_kernel(
    const unsigned short* __restrict__ Fpk, const unsigned short* __restrict__ Upk,
    const unsigned short* __restrict__ Mpk,
    unsigned short* __restrict__ vcb, unsigned short* __restrict__ kcb,
    float* __restrict__ logits)
{
    __shared__ unsigned short lds[18432];
    int TT = 7 - blockIdx.x;               // big tiles first
    int kf0 = blockIdx.y*2, hd = blockIdx.z;
    int tid=threadIdx.x, wid=tid>>6, lane=tid&63;
    int hf=wid>>1, mb0=(wid&1)*2;
    int quad=lane>>4, lm=lane&15;
    const unsigned short* Fk0 = Fpk + (kf0*17)*4096;
    const unsigned short* Fk1 = Fpk + ((kf0+1)*17)*4096;
    const unsigned short* Uv = Upk + (hd*16)*4096;
    const unsigned short* Uk = Upk + ((8+hd)*16)*4096;

    f32x4 acc[2][2][2][4];   // [tz][kf][i][nb]
    #pragma unroll
    for (int tz=0;tz<2;tz++)
        #pragma unroll
        for (int kf=0;kf<2;kf++)
            #pragma unroll
            for (int i=0;i<2;i++)
                #pragma unroll
                for (int nb=0;nb<4;nb++) acc[tz][kf][i][nb]=(f32x4){0.f,0.f,0.f,0.f};

    int STend = 2*TT + 2;
    // prologue: stage B(0) both tensors -> buf0
    {
        sh8 v0=*(const sh8*)(Uv+tid*8), v1=*(const sh8*)(Uv+(tid+256)*8);
        sh8 k0=*(const sh8*)(Uk+tid*8), k1=*(const sh8*)(Uk+(tid+256)*8);
        *(sh8*)(&lds[tid*8])=v0; *(sh8*)(&lds[(tid+256)*8])=v1;
        *(sh8*)(&lds[4096+tid*8])=k0; *(sh8*)(&lds[4096+(tid+256)*8])=k1;
    }
    for (int ST=0; ST<STend; ST++){
        sh8 nv0,nv1,nk0,nk1;
        bool more = (ST+1 < STend);
        if (more){
            const unsigned short* Uvn = Uv + (ST+1)*4096;
            const unsigned short* Ukn = Uk + (ST+1)*4096;
            nv0=*(const sh8*)(Uvn+tid*8); nv1=*(const sh8*)(Uvn+(tid+256)*8);
            nk0=*(const sh8*)(Ukn+tid*8); nk1=*(const sh8*)(Ukn+(tid+256)*8);
        }
        int dslot = 2*TT + hf - ST + 1;
        sh8 a[2][2][2];
        #pragma unroll
        for (int i=0;i<2;i++)
            #pragma unroll
            for (int ks=0;ks<2;ks++){
                a[0][i][ks] = *(const sh8*)(Fk0 + dslot*4096 + (mb0+i)*1024 + ks*512 + lane*8);
                a[1][i][ks] = *(const sh8*)(Fk1 + dslot*4096 + (mb0+i)*1024 + ks*512 + lane*8);
            }
        __syncthreads();
        const unsigned short* Bb = &lds[(ST&1)*8192];
        #pragma unroll
        for (int ks=0;ks<2;ks++)
            #pragma unroll
            for (int nb=0;nb<4;nb++){
                sh8 bv = *(const sh8*)(Bb + ks*2048 + nb*512 + lane*8);
                sh8 bk = *(const sh8*)(Bb + 4096 + ks*2048 + nb*512 + lane*8);
                #pragma unroll
                for (int kf=0;kf<2;kf++)
                    #pragma unroll
                    for (int i=0;i<2;i++){
                        acc[0][kf][i][nb] = __builtin_amdgcn_mfma_f32_16x16x32_bf16(
                            a[kf][i][ks], bv, acc[0][kf][i][nb], 0,0,0);
                        acc[1][kf][i][nb] = __builtin_amdgcn_mfma_f32_16x16x32_bf16(
                            a[kf][i][ks], bk, acc[1][kf][i][nb], 0,0,0);
                    }
            }
        if (more){
            unsigned short* Bn = &lds[((ST+1)&1)*8192];
            *(sh8*)(Bn+tid*8)=nv0; *(sh8*)(Bn+(tid+256)*8)=nv1;
            *(sh8*)(Bn+4096+tid*8)=nk0; *(sh8*)(Bn+4096+(tid+256)*8)=nk1;
        }
    }
    // epilogue: per kf: stage vc+kc (bf16, stride 72), write out, P=kc@M^T, dot vc
    float logacc[2][4];
    #pragma unroll
    for (int i2=0;i2<2;i2++)
        #pragma unroll
        for (int r=0;r<4;r++) logacc[i2][r]=0.f;
    const unsigned short* mbp = Mpk + hd*4096;
    #pragma unroll
    for (int kf=0;kf<2;kf++){
        __syncthreads();
        #pragma unroll
        for (int tz=0;tz<2;tz++)
            #pragma unroll
            for (int i=0;i<2;i++)
                #pragma unroll
                for (int nb=0;nb<4;nb++)
                    #pragma unroll
                    for (int r=0;r<4;r++){
                        int tl = hf*64 + (mb0+i)*16 + quad*4 + r;
                        lds[tz*9216 + tl*72 + nb*16 + lm] = f2bf(acc[tz][kf][i][nb][r]);
                    }
        __syncthreads();
        #pragma unroll
        for (int tz=0;tz<2;tz++){
            unsigned short* dst = tz ? kcb : vcb;
            #pragma unroll
            for (int it=0; it<4; it++){
                int idx = tid + it*256;
                int row = idx>>3, seg = idx&7;
                sh8 v = *(const sh8*)(&lds[tz*9216 + row*72 + seg*8]);
                *(sh8*)(dst + ((hd*Ll + TT*128 + row)*KF + kf0+kf)*64 + seg*8) = v;
            }
        }
        // logits: P = kc @ M^T via LDS A-frags; wave owns rows wid*32..+31
        f32x4 accp[2][4];
        #pragma unroll
        for (int i2=0;i2<2;i2++)
            #pragma unroll
            for (int nb=0;nb<4;nb++) accp[i2][nb]=(f32x4){0.f,0.f,0.f,0.f};
        #pragma unroll
        for (int i2=0;i2<2;i2++)
            #pragma unroll
            for (int ks=0;ks<2;ks++){
                sh8 a2 = *(const sh8*)(&lds[9216 + (wid*32+i2*16+lm)*72 + ks*32 + quad*8]);
                #pragma unroll
                for (int nb=0;nb<4;nb++){
                    sh8 bm = *(const sh8*)(mbp + (nb*2+ks)*512 + lane*8);
                    accp[i2][nb] = __builtin_amdgcn_mfma_f32_16x16x32_bf16(a2, bm, accp[i2][nb], 0,0,0);
                }
            }
        #pragma unroll
        for (int i2=0;i2<2;i2++)
            #pragma unroll
            for (int r=0;r<4;r++){
                int row_l = wid*32 + i2*16 + quad*4 + r;
                float s = 0.f;
                #pragma unroll
                for (int nb=0;nb<4;nb++)
                    s += accp[i2][nb][r]*bf2f(lds[row_l*72 + nb*16 + lm]);
                logacc[i2][r] += s;
            }
    }
    #pragma unroll
    for (int i2=0;i2<2;i2++)
        #pragma unroll
        for (int r=0;r<4;r++){
            float s = logacc[i2][r];
            s += __shfl_xor(s, 1, 64);
            s += __shfl_xor(s, 2, 64);
            s += __shfl_xor(s, 4, 64);
            s += __shfl_xor(s, 8, 64);
            if (lm==0){
                int row_l = wid*32 + i2*16 + quad*4 + r;
                atomicAdd(&logits[hd*Ll + TT*128 + row_l], s);
            }
        }
}

// scan (fused gates): logits -> gates, factor
__global__ __launch_bounds__(256) void scan_kernel(
    const float* __restrict__ simg, const float* __restrict__ logits,
    const float* __restrict__ bg, float* __restrict__ gates, float* __restrict__ factor)
{
    int hd=blockIdx.x, tid=threadIdx.x;
    __shared__ float sm[256], ssc[256], sg[256];
    float bgv = bg[0];
    float simv[4], m_loc[4], s_loc[4], g_loc[4];
    float m = -__builtin_inff(), s = 0.f, g = 0.f;
    for(int e=0;e<4;e++){
        int ix = hd*Ll + tid*4 + e;
        simv[e] = simg[ix];
        float lg = logits[ix] + bgv;
        float r = fmaxf(lg, 0.f);
        float gv = r*r + EPSf;
        gates[ix] = gv;
        float mn = fmaxf(m, simv[e]);
        s = s*__expf(m-mn) + __expf(simv[e]-mn);
        m = mn; g += gv;
        m_loc[e]=m; s_loc[e]=s; g_loc[e]=g;
    }
    sm[tid]=m; ssc[tid]=s; sg[tid]=g;
    __syncthreads();
    for(int off=1; off<256; off<<=1){
        float pm=0, ps=0, pg=0; bool has = (tid>=off);
        if(has){ pm=sm[tid-off]; ps=ssc[tid-off]; pg=sg[tid-off]; }
        __syncthreads();
        if(has){
            float mn=fmaxf(pm, sm[tid]);
            float sn=ps*__expf(pm-mn) + ssc[tid]*__expf(sm[tid]-mn);
            sm[tid]=mn; ssc[tid]=sn; sg[tid]=pg+sg[tid];
        }
        __syncthreads();
    }
    float pm=-__builtin_inff(), ps=0.f, pg=0.f;
    if (tid>0){ pm=sm[tid-1]; ps=ssc[tid-1]; pg=sg[tid-1]; }
    for(int e=0;e<4;e++){
        float mn=fmaxf(pm, m_loc[e]);
        float sn=ps*__expf(pm-mn) + s_loc[e]*__expf(m_loc[e]-mn);
        float gn=pg + g_loc[e];
        float sw = __expf(simv[e]-mn)/(sn+EPSf);
        float silu = sw/(1.f+__expf(-sw));
        factor[hd*Ll + tid*4 + e] = (1.f+silu)/(gn+EPSf);
    }
}

// ---------- fused phase3 + chunkz (MFMA) ----------
#define VTS 68
#define ASS 72
__global__ __launch_bounds__(256) void p3cz_kernel(
    const unsigned short* __restrict__ Qpk,
    const unsigned short* __restrict__ vcb, const unsigned short* __restrict__ kcb,
    const float* __restrict__ gates, float* __restrict__ cpart, float* __restrict__ czp)
{
    __shared__ unsigned short VT[64*VTS];
    __shared__ unsigned short KT[64*VTS];
    __shared__ unsigned short As[4][16*ASS];
    __shared__ float gl[16];
    int tid=threadIdx.x, w=tid>>6, lane=tid&63;
    int quad=lane>>4, lm=lane&15;
    int c=blockIdx.x, qq=blockIdx.y, hd=blockIdx.z;
    int T0=c*64, tq0=T0+qq*16, RQ0=tq0*KF;
    if (tid<16) gl[tid]=gates[hd*Ll+tq0+tid];
    sh8 aq[2];
    {
        const unsigned short* qb = Qpk + ((hd*64 + (c*4+w))*2)*512;
        aq[0] = *(const sh8*)(qb + lane*8);
        aq[1] = *(const sh8*)(qb + 512 + lane*8);
    }
    f32x4 ctx[4], cz[4];
    #pragma unroll
    for (int nb=0;nb<4;nb++){ ctx[nb]=(f32x4){0,0,0,0}; cz[nb]=(f32x4){0,0,0,0}; }
    int t_g = T0 + w*16 + quad*4;
    int rp = tid>>3, e0 = (tid&7)*8, r0 = rp*2;

    for (int sub=0; sub<6; sub++){
        int RB = RQ0 + sub*64;
        const unsigned short* vrow = vcb + (hd*LK + RB)*64;
        const unsigned short* krow = kcb + (hd*LK + RB)*64;
        __syncthreads();
        {
            float g0 = gl[(RB + r0)/KF - tq0];
            float g1 = gl[(RB + r0 + 1)/KF - tq0];
            sh8 v0 = *(const sh8*)(vrow + r0*64 + e0);
            sh8 v1 = *(const sh8*)(vrow + (r0+1)*64 + e0);
            sh8 k0 = *(const sh8*)(krow + r0*64 + e0);
            sh8 k1 = *(const sh8*)(krow + (r0+1)*64 + e0);
            #pragma unroll
            for (int j=0;j<8;j++){
                unsigned int pv = (unsigned int)f2bf(bf2f((unsigned short)v0[j])*g0)
                                | ((unsigned int)f2bf(bf2f((unsigned short)v1[j])*g1)<<16);
                *(unsigned int*)(&VT[(e0+j)*VTS + r0]) = pv;
                unsigned int pk = (unsigned int)(unsigned short)k0[j]
                                | ((unsigned int)(unsigned short)k1[j]<<16);
                *(unsigned int*)(&KT[(e0+j)*VTS + r0]) = pk;
            }
        }
        f32x4 S[4];
        #pragma unroll
        for (int nb=0;nb<4;nb++) S[nb]=(f32x4){0,0,0,0};
        #pragma unroll
        for (int ks=0;ks<2;ks++){
            #pragma unroll
            for (int nb=0;nb<4;nb++){
                sh8 b = *(const sh8*)(vrow + (nb*16+lm)*64 + ks*32 + quad*8);
                S[nb] = __builtin_amdgcn_mfma_f32_16x16x32_bf16(aq[ks], b, S[nb], 0,0,0);
            }
        }
        #pragma unroll
        for (int nb=0;nb<4;nb++){
            int row_l = nb*16+lm;
            int tp = (RB + row_l)/KF;
            float g = gl[tp - tq0];
            #pragma unroll
            for (int r=0;r<4;r++){
                float v = (t_g + r >= tp) ? S[nb][r]*g : 0.f;
                As[w][(quad*4+r)*ASS + row_l] = f2bf(v);
            }
        }
        __syncthreads();
        #pragma unroll
        for (int ks=0;ks<2;ks++){
            sh8 a2 = *(const sh8*)(&As[w][lm*ASS + ks*32 + quad*8]);
            sh8 av = ld8_8B(&VT[(w*16+lm)*VTS + ks*32 + quad*8]);
            #pragma unroll
            for (int nb=0;nb<4;nb++){
                sh8 bk = ld8_8B(&KT[(nb*16+lm)*VTS + ks*32 + quad*8]);
                ctx[nb] = __builtin_amdgcn_mfma_f32_16x16x32_bf16(a2, bk, ctx[nb], 0,0,0);
                cz[nb]  = __builtin_amdgcn_mfma_f32_16x16x32_bf16(av, bk, cz[nb], 0,0,0);
            }
        }
    }
    #pragma unroll
    for (int nb=0;nb<4;nb++){
        #pragma unroll
        for (int r=0;r<4;r++){
            cpart[((qq*8+hd)*Ll + t_g + r)*64 + nb*16+lm] = ctx[nb][r];
        }
    }
    int ob = ((hd*16+c)*4+qq)*4096;
    #pragma unroll
    for (int nb=0;nb<4;nb++){
        #pragma unroll
        for (int r=0;r<4;r++){
            czp[ob + (w*16+quad*4+r)*64 + nb*16+lm] = cz[nb][r];
        }
    }
}

// exclusive chunk prefix -> bf16 B-frag layout
__global__ __launch_bounds__(256) void s0_kernel(
    const float* __restrict__ czp, unsigned short* __restrict__ S0b)
{
    int idx = blockIdx.x*256 + threadIdx.x;   // [d][e] position
    int hd = blockIdx.y;
    int d = idx>>6, e = idx&63;
    int frag = (d>>5)*2048 + (e>>4)*512 + ((((d>>3)&3)*16) + (e&15))*8 + (d&7);
    float a = 0.f;
    for (int c=0;c<16;c++){
        S0b[(hd*16+c)*4096 + frag] = f2bf(a);
        int b = ((hd*16+c)*4)*4096 + idx;
        a += czp[b] + czp[b+4096] + czp[b+2*4096] + czp[b+3*4096];
    }
}

// combine (MFMA): Cpk = factor * ( Qpk @ S0b + sum_q cpart )
__global__ __launch_bounds__(256) void combine_kernel(
    const unsigned short* __restrict__ Qpk, const unsigned short* __restrict__ S0b,
    const float* __restrict__ cpart, const float* __restrict__ factor,
    unsigned short* __restrict__ Cpk)
{
    int c=blockIdx.x, hd=blockIdx.y;
    int tid=threadIdx.x, wid=tid>>6, lane=tid&63, quad=lane>>4, lm=lane&15;
    int mb = c*4 + wid;
    sh8 aq0 = *(const sh8*)(Qpk + ((hd*64+mb)*2)*512 + lane*8);
    sh8 aq1 = *(const sh8*)(Qpk + ((hd*64+mb)*2+1)*512 + lane*8);
    const unsigned short* sb = S0b + (hd*16+c)*4096;
    f32x4 acc[4];
    #pragma unroll
    for (int nb=0;nb<4;nb++) acc[nb]=(f32x4){0.f,0.f,0.f,0.f};
    #pragma unroll
    for (int ks=0;ks<2;ks++){
        sh8 a = ks ? aq1 : aq0;
        #pragma unroll
        for (int nb=0;nb<4;nb++){
            sh8 b = *(const sh8*)(sb + ks*2048 + nb*512 + lane*8);
            acc[nb] = __builtin_amdgcn_mfma_f32_16x16x32_bf16(a, b, acc[nb], 0,0,0);
        }
    }
    float fv[4];
    #pragma unroll
    for (int r=0;r<4;r++) fv[r] = factor[hd*Ll + mb*16 + quad*4 + r];
    #pragma unroll
    for (int nb=0;nb<4;nb++){
        int e = nb*16 + lm;
        int dim = hd*64 + e;
        int ks2 = dim>>5, koff = dim&31, qd = koff>>3, jj = koff&7;
        #pragma unroll
        for (int r=0;r<4;r++){
            int t = mb*16 + quad*4 + r;
            float v = acc[nb][r];
            #pragma unroll
            for (int q=0;q<4;q++) v += cpart[((q*8+hd)*Ll + t)*64 + e];
            v *= fv[r];
            Cpk[((t>>4)*16 + ks2)*512 + qd*128 + (t&15)*8 + jj] = f2bf(v);
        }
    }
}

// out = Cpk @ Wopk + bo
__global__ __launch_bounds__(256) void outprojm_kernel(
    const unsigned short* __restrict__ Cpk, const unsigned short* __restrict__ Wopk,
    const float* __restrict__ bo, float* __restrict__ out)
{
    int mt=blockIdx.x, nt=blockIdx.y;
    int tid=threadIdx.x, wid=tid>>6, lane=tid&63;
    int mb=mt*4+wid;
    f32x4 acc[4];
    #pragma unroll
    for (int nb=0;nb<4;nb++) acc[nb]=(f32x4){0.f,0.f,0.f,0.f};
    for (int ks=0;ks<16;ks++){
        sh8 a = *(const sh8*)(Cpk + (mb*16+ks)*512 + lane*8);
        #pragma unroll
        for (int nb2=0;nb2<4;nb2++){
            sh8 b = *(const sh8*)(Wopk + ((nt*4+nb2)*16+ks)*512 + lane*8);
            acc[nb2] = __builtin_amdgcn_mfma_f32_16x16x32_bf16(a, b, acc[nb2], 0,0,0);
        }
    }
    int quad=lane>>4, col=lane&15;
    #pragma unroll
    for (int nb2=0;nb2<4;nb2++){
        int n = nt*64 + nb2*16 + col;
        float bval = bo[n];
        #pragma unroll
        for (int r=0;r<4;r++){
            out[(mb*16+quad*4+r)*Dm + n] = acc[nb2][r] + bval;
        }
    }
}

extern "C" void kernel_launch(void* const* d_in, const int* in_sizes, int n_in,
                              void* d_out, int out_size, void* d_ws, size_t ws_size,
                              hipStream_t stream)
{
    (void)in_sizes; (void)n_in; (void)out_size; (void)ws_size;
    const float* x   =(const float*)d_in[0];
    const float* Wq  =(const float*)d_in[1];
    const float* bq  =(const float*)d_in[2];
    const float* Wk  =(const float*)d_in[3];
    const float* bk  =(const float*)d_in[4];
    const float* Wv  =(const float*)d_in[5];
    const float* bv  =(const float*)d_in[6];
    const float* Wo  =(const float*)d_in[7];
    const float* bo  =(const float*)d_in[8];
    const float* Wg  =(const float*)d_in[9];
    const float* bg  =(const float*)d_in[10];
    const float* kvs =(const float*)d_in[11];
    const float* qks =(const float*)d_in[12];
    const float* filt=(const float*)d_in[13];
    float* ws = (float*)d_ws;
    float* qh    = ws+OFF_QH;
    float* kn    = ws+OFF_KN;
    float* vn    = ws+OFF_VN;
    float* simg  = ws+OFF_SIM;
    float* logits= ws+OFF_LOGITS;
    float* gates = ws+OFF_GATES;
    float* factor= ws+OFF_FACTOR;
    float* czp   = ws+OFF_CZP;
    float* cpart = ws+OFF_CPART;
    unsigned short* vcb  = (unsigned short*)(ws + OFF_VCB);
    unsigned short* kcb  = (unsigned short*)(ws + OFF_KCB);
    unsigned short* Qpk  = (unsigned short*)(ws + OFF_QPK);
    unsigned short* Mpk  = (unsigned short*)(ws + OFF_MPK);
    unsigned short* Wopk = (unsigned short*)(ws + OFF_WOPK);
    unsigned short* Cpk  = (unsigned short*)(ws + OFF_CPK);
    unsigned short* S0b  = (unsigned short*)(ws + OFF_S0);
    unsigned short* Fpk  = (unsigned short*)(ws + OFF_FPK_F);
    unsigned short* Upk  = (unsigned short*)(ws + OFF_UPK_F);
    unsigned short* Apk  = (unsigned short*)(ws + OFF_APK_F);
    unsigned short* Bpk  = (unsigned short*)(ws + OFF_BPK_F);
    float* out   = (float*)d_out;

    hipMemsetAsync(logits, 0, Hh*Ll*sizeof(float), stream);
    xpk_kernel    <<<dim3(64),      256,0,stream>>>(x,Apk);
    wpk_kernel    <<<dim3(96),      256,0,stream>>>(Wq,Wk,Wv,Bpk);
    qkvm_kernel   <<<dim3(16,24),   256,0,stream>>>(Apk,Bpk,bq,bk,bv,qh,kn,vn);
    nse_kernel    <<<dim3(2048),    256,0,stream>>>(qh,kn,vn,qks,simg,Upk,Qpk);
    fpk_kernel    <<<dim3(24,17),   256,0,stream>>>(filt,Fpk);
    mpk_kernel    <<<dim3(8),       256,0,stream>>>(kvs,Wg,Mpk);
    wopk_kernel   <<<dim3(32),      256,0,stream>>>(Wo,Wopk);
    convf_kernel  <<<dim3(8,12,8),  256,0,stream>>>(Fpk,Upk,Mpk,vcb,kcb,logits);
    scan_kernel   <<<dim3(8),       256,0,stream>>>(simg,logits,bg,gates,factor);
    p3cz_kernel   <<<dim3(16,4,8),  256,0,stream>>>(Qpk,vcb,kcb,gates,cpart,czp);
    s0_kernel     <<<dim3(16,8),    256,0,stream>>>(czp,S0b);
    combine_kernel<<<dim3(16,8),    256,0,stream>>>(Qpk,S0b,cpart,factor,Cpk);
    outprojm_kernel<<<dim3(16,8),   256,0,stream>>>(Cpk,Wopk,bo,out);
}

// Round 7
// 175.612 us; speedup vs baseline: 5.6203x; 1.1751x over previous
//
#include <hip/hip_runtime.h>
#include <math.h>

#define Hh 8
#define Ll 1024
#define KF 24
#define Dm 512
#define EPSf 1e-5f
#define LK (Ll*KF)   // 24576 rows (t,kf) per head

typedef __attribute__((ext_vector_type(8))) short sh8;
typedef __attribute__((ext_vector_type(4))) short sh4;
typedef __attribute__((ext_vector_type(4))) float f32x4;

// ---- workspace offsets (floats) ----
#define OFF_QH     0
#define OFF_KN     524288
#define OFF_VN     1048576
#define OFF_SIM    1572864
#define OFF_LOGITS 1581056
#define OFF_GATES  1589248
#define OFF_FACTOR 1597440
#define OFF_VCB    1605632     // bf16 vc
#define OFF_KCB    7897088     // bf16 kc
#define OFF_QPK    14188544    // bf16 Q A-frags
#define OFF_MPK    14450688    // bf16 M B-frags
#define OFF_WOPK   14467072    // bf16 Wo B-frags
#define OFF_CPK    14598144    // bf16 ctxt A-frags
#define OFF_CZP    26771456
#define OFF_S0     28868608    // bf16 S0 B-frags
#define OFF_CPART  29392896
// pack overlays inside CZP region (all consumed before p3cz writes czp):
#define OFF_FPK_F  26771456    // Fpk16: 24*64*1024 ush = 786,432 fl (fits 835,584)
#define OFF_UPK_F  27607040
#define OFF_APK_F  28131328
#define OFF_BPK_F  28393472

__device__ inline unsigned short f2bf(float x){
    unsigned int u = __float_as_uint(x);
    unsigned int r = (u + 0x7fffu + ((u>>16)&1u)) >> 16;
    return (unsigned short)r;
}
__device__ inline float bf2f(unsigned short u){ return __uint_as_float(((unsigned int)u)<<16); }
__device__ inline sh8 ld8_8B(const unsigned short* p){
    union { sh8 s; sh4 h[2]; } u;
    u.h[0] = *(const sh4*)(p);
    u.h[1] = *(const sh4*)(p+4);
    return u.s;
}

// ---------- fused packing kernel ----------
// blocks 0..63: x A-frags | 64..159: Wq/Wk/Wv B-frags | 160..191: Wo B-frags
// 192..199: M B-frags | 200..295: Fpk16 Toeplitz 16x64 A-tiles
__global__ __launch_bounds__(256) void pack_all_kernel(
    const float* __restrict__ x,
    const float* __restrict__ Wq, const float* __restrict__ Wk, const float* __restrict__ Wv,
    const float* __restrict__ Wo, const float* __restrict__ kvs, const float* __restrict__ Wg,
    const float* __restrict__ filt,
    unsigned short* __restrict__ Apk, unsigned short* __restrict__ Bpk,
    unsigned short* __restrict__ Wopk, unsigned short* __restrict__ Mpk,
    unsigned short* __restrict__ Fpk16)
{
    int bid = blockIdx.x, tid = threadIdx.x;
    if (bid < 64){
        int mb = bid;
        for (int ks=0; ks<16; ks++){
            #pragma unroll
            for (int p=0;p<2;p++){
                int e = tid + p*256;
                int lane = e>>3, j = e&7;
                int m = mb*16 + (lane&15);
                int k = ks*32 + ((lane>>4)&3)*8 + j;
                Apk[(mb*16+ks)*512 + e] = f2bf(x[m*Dm + k]);
            }
        }
    } else if (bid < 160){
        int nb = bid - 64;
        int n0 = nb*16;
        int mm = n0>>9;
        const float* W = (mm==0)?Wq:((mm==1)?Wk:Wv);
        int coff = n0 & 511;
        for (int ks=0; ks<16; ks++){
            #pragma unroll
            for (int p=0;p<2;p++){
                int e = tid + p*256;
                int lane = e>>3, j = e&7;
                int kk = ks*32 + ((lane>>4)&3)*8 + j;
                Bpk[(nb*16+ks)*512 + e] = f2bf(W[kk*Dm + coff + (lane&15)]);
            }
        }
    } else if (bid < 192){
        int nb = bid - 160;
        int n0 = nb*16;
        for (int ks=0; ks<16; ks++){
            #pragma unroll
            for (int p=0;p<2;p++){
                int e = tid + p*256;
                int lane = e>>3, j = e&7;
                int kk = ks*32 + ((lane>>4)&3)*8 + j;
                Wopk[(nb*16+ks)*512 + e] = f2bf(Wo[kk*Dm + n0 + (lane&15)]);
            }
        }
    } else if (bid < 200){
        int hd = bid - 192;
        for (int it=0; it<16; it++){
            int idx = tid + it*256;
            int f = idx & 511, ksnb = idx >> 9;
            int nb = ksnb>>1, ks = ksnb&1;
            int lane = f>>3, j = f&7;
            int e = nb*16 + (lane&15);
            int d = ks*32 + ((lane>>4)&3)*8 + j;
            Mpk[hd*4096 + idx] = f2bf(kvs[(hd*64+e)*64 + d]*Wg[e*64+d]);
        }
    } else {
        int b2 = bid - 200;          // 0..95, 16 tiles each
        for (int ti=0; ti<16; ti++){
            int tile = b2*16 + ti;   // = kf*64 + d16
            int kf = tile>>6, d16 = tile&63;
            unsigned short* dst = Fpk16 + tile*1024;
            #pragma unroll
            for (int p2=0;p2<4;p2++){
                int e = tid + p2*256;
                int ks = e>>9, f = e&511;
                int lane = f>>3, j = f&7;
                int m = lane&15;
                int k = ks*32 + ((lane>>4)&3)*8 + j;
                int fidx = 16*d16 + m - k;
                float v = (fidx>=0 && fidx<Ll) ? filt[fidx*KF+kf] : 0.0f;
                dst[e] = f2bf(v);
            }
        }
    }
}

// ---------- QKV MFMA GEMM ----------
__global__ __launch_bounds__(256) void qkvm_kernel(
    const unsigned short* __restrict__ Apk, const unsigned short* __restrict__ Bpk,
    const float* __restrict__ bq, const float* __restrict__ bk, const float* __restrict__ bv,
    float* __restrict__ qh, float* __restrict__ kn, float* __restrict__ vn)
{
    int mt = blockIdx.x, nt = blockIdx.y;
    int tid = threadIdx.x, wid = tid>>6, lane = tid&63;
    int mb = mt*4 + wid;
    f32x4 acc[4];
    #pragma unroll
    for (int nb=0;nb<4;nb++) acc[nb]=(f32x4){0.f,0.f,0.f,0.f};
    for (int ks=0; ks<16; ks++){
        sh8 a = *(const sh8*)(Apk + (mb*16+ks)*512 + lane*8);
        #pragma unroll
        for (int nb2=0;nb2<4;nb2++){
            sh8 b = *(const sh8*)(Bpk + ((nt*4+nb2)*16+ks)*512 + lane*8);
            acc[nb2] = __builtin_amdgcn_mfma_f32_16x16x32_bf16(a, b, acc[nb2], 0,0,0);
        }
    }
    int mm = nt>>3, hd = nt&7;
    const float* bias = (mm==0)?bq:((mm==1)?bk:bv);
    float* dst = (mm==0)?qh:((mm==1)?kn:vn);
    int quad = lane>>4, col = lane&15;
    #pragma unroll
    for (int nb2=0;nb2<4;nb2++){
        int d = nb2*16 + col;
        float bval = bias[hd*64+d];
        #pragma unroll
        for (int r=0;r<4;r++){
            int t = mb*16 + quad*4 + r;
            dst[(hd*Ll + t)*64 + d] = acc[nb2][r] + bval;
        }
    }
}

// nse: per-row sim; normalize k,v -> packed bf16 (Upk) + pack q (Qpk)
__global__ __launch_bounds__(256) void nse_kernel(
    const float* __restrict__ qh, const float* __restrict__ kn, const float* __restrict__ vn,
    const float* __restrict__ qks, float* __restrict__ simg,
    unsigned short* __restrict__ Upk, unsigned short* __restrict__ Qpk)
{
    int gw = blockIdx.x*4 + (threadIdx.x>>6);   // hd*1024 + t
    int lane = threadIdx.x & 63;                 // = d
    int hd = gw>>10, t = gw&1023;
    int base = gw*64 + lane;
    float q = qh[base], k = kn[base], v = vn[base];
    float sim = q*k, k2 = k*k, v2 = v*v;
    #pragma unroll
    for (int off=32; off; off>>=1){
        sim += __shfl_xor(sim, off, 64);
        k2  += __shfl_xor(k2,  off, 64);
        v2  += __shfl_xor(v2,  off, 64);
    }
    float kfv = k * (1.f/fmaxf(sqrtf(k2), 1e-12f));
    float vfv = v * (1.f/fmaxf(sqrtf(v2), 1e-12f));
    int d = lane;
    int ST = t>>6, ks = (t>>5)&1, j = t&7;
    int frag = ks*2048 + (d>>4)*512 + (((t>>3)&3)*16 + (d&15))*8 + j;
    Upk[((hd*16) + ST)*4096 + frag]        = f2bf(vfv);   // tensor 0 = v
    Upk[(((8+hd)*16) + ST)*4096 + frag]    = f2bf(kfv);   // tensor 1 = k
    int mb = t>>4, ks2 = d>>5, j2 = d&7;
    int fl2 = ((d>>3)&3)*16 + (t&15);
    Qpk[((hd*64+mb)*2+ks2)*512 + fl2*8 + j2] = f2bf(q);
    if (lane==0) simg[gw] = sim * qks[hd];
}

// ---------- conv phase: one 64-row t-tile T (steps 0..T), both tensors, 2 kf ----------
__device__ __forceinline__ void conv_phase(
    int T, int kf0, int hd,
    const unsigned short* __restrict__ Fpk16,
    const unsigned short* __restrict__ Uv, const unsigned short* __restrict__ Uk,
    const unsigned short* __restrict__ Mh,
    unsigned short* __restrict__ vcb, unsigned short* __restrict__ kcb,
    float* __restrict__ logits, unsigned short* lds,
    int tid, int w, int lane)
{
    int quad = lane>>4, lm = lane&15;
    f32x4 acc[2][2][4];   // [kf][tz][nb]
    #pragma unroll
    for (int kf=0;kf<2;kf++)
        #pragma unroll
        for (int tz=0;tz<2;tz++)
            #pragma unroll
            for (int nb=0;nb<4;nb++) acc[kf][tz][nb]=(f32x4){0.f,0.f,0.f,0.f};

    __syncthreads();   // protect LDS from previous phase's reads
    {
        sh8 v0=*(const sh8*)(Uv+tid*8), v1=*(const sh8*)(Uv+(tid+256)*8);
        sh8 k0=*(const sh8*)(Uk+tid*8), k1=*(const sh8*)(Uk+(tid+256)*8);
        *(sh8*)(&lds[tid*8])=v0; *(sh8*)(&lds[(tid+256)*8])=v1;
        *(sh8*)(&lds[4096+tid*8])=k0; *(sh8*)(&lds[4096+(tid+256)*8])=k1;
    }
    for (int ST=0; ST<=T; ST++){
        sh8 nv0,nv1,nk0,nk1;
        bool more = (ST < T);
        if (more){
            const unsigned short* Uvn = Uv + (ST+1)*4096;
            const unsigned short* Ukn = Uk + (ST+1)*4096;
            nv0=*(const sh8*)(Uvn+tid*8); nv1=*(const sh8*)(Uvn+(tid+256)*8);
            nk0=*(const sh8*)(Ukn+tid*8); nk1=*(const sh8*)(Ukn+(tid+256)*8);
        }
        int d16 = 4*(T-ST) + w;
        sh8 a[2][2];
        #pragma unroll
        for (int kf=0;kf<2;kf++)
            #pragma unroll
            for (int ks=0;ks<2;ks++)
                a[kf][ks] = *(const sh8*)(Fpk16 + ((kf0+kf)*64 + d16)*1024 + ks*512 + lane*8);
        __syncthreads();
        const unsigned short* Bb = &lds[(ST&1)*8192];
        #pragma unroll
        for (int ks=0;ks<2;ks++)
            #pragma unroll
            for (int nb=0;nb<4;nb++){
                sh8 bv = *(const sh8*)(Bb + ks*2048 + nb*512 + lane*8);
                sh8 bk = *(const sh8*)(Bb + 4096 + ks*2048 + nb*512 + lane*8);
                #pragma unroll
                for (int kf=0;kf<2;kf++){
                    acc[kf][0][nb] = __builtin_amdgcn_mfma_f32_16x16x32_bf16(
                        a[kf][ks], bv, acc[kf][0][nb], 0,0,0);
                    acc[kf][1][nb] = __builtin_amdgcn_mfma_f32_16x16x32_bf16(
                        a[kf][ks], bk, acc[kf][1][nb], 0,0,0);
                }
            }
        if (more){
            unsigned short* Bn = &lds[((ST+1)&1)*8192];
            *(sh8*)(Bn+tid*8)=nv0; *(sh8*)(Bn+(tid+256)*8)=nv1;
            *(sh8*)(Bn+4096+tid*8)=nk0; *(sh8*)(Bn+4096+(tid+256)*8)=nk1;
        }
    }
    // epilogue: per kf: stage bf16 (stride 72), global write, P=kc@M^T, dot vc
    float logacc[4] = {0.f,0.f,0.f,0.f};
    #pragma unroll
    for (int kf=0;kf<2;kf++){
        __syncthreads();
        #pragma unroll
        for (int tz=0;tz<2;tz++)
            #pragma unroll
            for (int nb=0;nb<4;nb++)
                #pragma unroll
                for (int r=0;r<4;r++){
                    int tl = w*16 + quad*4 + r;
                    lds[tz*4608 + tl*72 + nb*16 + lm] = f2bf(acc[kf][tz][nb][r]);
                }
        __syncthreads();
        #pragma unroll
        for (int tz=0;tz<2;tz++){
            unsigned short* dst = tz ? kcb : vcb;
            #pragma unroll
            for (int it=0; it<2; it++){
                int idx = tid + it*256;
                int row = idx>>3, seg = idx&7;
                sh8 vv = *(const sh8*)(&lds[tz*4608 + row*72 + seg*8]);
                *(sh8*)(dst + ((hd*Ll + T*64 + row)*KF + kf0+kf)*64 + seg*8) = vv;
            }
        }
        f32x4 accp[4];
        #pragma unroll
        for (int nb=0;nb<4;nb++) accp[nb]=(f32x4){0.f,0.f,0.f,0.f};
        #pragma unroll
        for (int ks=0;ks<2;ks++){
            sh8 a2 = *(const sh8*)(&lds[4608 + (w*16+lm)*72 + ks*32 + quad*8]);
            #pragma unroll
            for (int nb=0;nb<4;nb++){
                sh8 bm = *(const sh8*)(Mh + (nb*2+ks)*512 + lane*8);
                accp[nb] = __builtin_amdgcn_mfma_f32_16x16x32_bf16(a2, bm, accp[nb], 0,0,0);
            }
        }
        #pragma unroll
        for (int r=0;r<4;r++){
            int rloc = w*16 + quad*4 + r;
            float s = 0.f;
            #pragma unroll
            for (int nb=0;nb<4;nb++)
                s += accp[nb][r]*bf2f(lds[rloc*72 + nb*16 + lm]);
            logacc[r] += s;
        }
    }
    #pragma unroll
    for (int r=0;r<4;r++){
        float s = logacc[r];
        s += __shfl_xor(s, 1, 64);
        s += __shfl_xor(s, 2, 64);
        s += __shfl_xor(s, 4, 64);
        s += __shfl_xor(s, 8, 64);
        if (lm==0)
            atomicAdd(&logits[hd*Ll + T*64 + w*16 + quad*4 + r], s);
    }
}

// grid (8 pairs, 12 kf-pairs, 8 hd); every block = 17 K-steps (tiles 15-p and p)
__global__ __launch_bounds__(256,2) void convf_kernel(
    const unsigned short* __restrict__ Fpk16, const unsigned short* __restrict__ Upk,
    const unsigned short* __restrict__ Mpk,
    unsigned short* __restrict__ vcb, unsigned short* __restrict__ kcb,
    float* __restrict__ logits)
{
    __shared__ unsigned short lds[16384];   // 32 KB: B ping-pong ∪ epilogue staging
    int p = blockIdx.x, kf0 = blockIdx.y*2, hd = blockIdx.z;
    int tid=threadIdx.x, w=tid>>6, lane=tid&63;
    const unsigned short* Uv = Upk + (hd*16)*4096;
    const unsigned short* Uk = Upk + ((8+hd)*16)*4096;
    const unsigned short* Mh = Mpk + hd*4096;
    conv_phase(15-p, kf0, hd, Fpk16, Uv, Uk, Mh, vcb, kcb, logits, lds, tid, w, lane);
    conv_phase(p,    kf0, hd, Fpk16, Uv, Uk, Mh, vcb, kcb, logits, lds, tid, w, lane);
}

// scan (fused gates): logits -> gates, factor
__global__ __launch_bounds__(256) void scan_kernel(
    const float* __restrict__ simg, const float* __restrict__ logits,
    const float* __restrict__ bg, float* __restrict__ gates, float* __restrict__ factor)
{
    int hd=blockIdx.x, tid=threadIdx.x;
    __shared__ float sm[256], ssc[256], sg[256];
    float bgv = bg[0];
    float simv[4], m_loc[4], s_loc[4], g_loc[4];
    float m = -__builtin_inff(), s = 0.f, g = 0.f;
    for(int e=0;e<4;e++){
        int ix = hd*Ll + tid*4 + e;
        simv[e] = simg[ix];
        float lg = logits[ix] + bgv;
        float r = fmaxf(lg, 0.f);
        float gv = r*r + EPSf;
        gates[ix] = gv;
        float mn = fmaxf(m, simv[e]);
        s = s*__expf(m-mn) + __expf(simv[e]-mn);
        m = mn; g += gv;
        m_loc[e]=m; s_loc[e]=s; g_loc[e]=g;
    }
    sm[tid]=m; ssc[tid]=s; sg[tid]=g;
    __syncthreads();
    for(int off=1; off<256; off<<=1){
        float pm=0, ps=0, pg=0; bool has = (tid>=off);
        if(has){ pm=sm[tid-off]; ps=ssc[tid-off]; pg=sg[tid-off]; }
        __syncthreads();
        if(has){
            float mn=fmaxf(pm, sm[tid]);
            float sn=ps*__expf(pm-mn) + ssc[tid]*__expf(sm[tid]-mn);
            sm[tid]=mn; ssc[tid]=sn; sg[tid]=pg+sg[tid];
        }
        __syncthreads();
    }
    float pm=-__builtin_inff(), ps=0.f, pg=0.f;
    if (tid>0){ pm=sm[tid-1]; ps=ssc[tid-1]; pg=sg[tid-1]; }
    for(int e=0;e<4;e++){
        float mn=fmaxf(pm, m_loc[e]);
        float sn=ps*__expf(pm-mn) + s_loc[e]*__expf(m_loc[e]-mn);
        float gn=pg + g_loc[e];
        float sw = __expf(simv[e]-mn)/(sn+EPSf);
        float silu = sw/(1.f+__expf(-sw));
        factor[hd*Ll + tid*4 + e] = (1.f+silu)/(gn+EPSf);
    }
}

// ---------- fused phase3 + chunkz (MFMA); vc raw tile shared in LDS ----------
#define VTS 68
#define ASS 72
__global__ __launch_bounds__(256) void p3cz_kernel(
    const unsigned short* __restrict__ Qpk,
    const unsigned short* __restrict__ vcb, const unsigned short* __restrict__ kcb,
    const float* __restrict__ gates, float* __restrict__ cpart, float* __restrict__ czp)
{
    __shared__ unsigned short VT[64*VTS];
    __shared__ unsigned short KT[64*VTS];
    __shared__ unsigned short As[4][16*ASS];
    __shared__ unsigned short Vraw[64*72];
    __shared__ float gl[16];
    int tid=threadIdx.x, w=tid>>6, lane=tid&63;
    int quad=lane>>4, lm=lane&15;
    int c=blockIdx.x, qq=blockIdx.y, hd=blockIdx.z;
    int T0=c*64, tq0=T0+qq*16, RQ0=tq0*KF;
    if (tid<16) gl[tid]=gates[hd*Ll+tq0+tid];
    sh8 aq[2];
    {
        const unsigned short* qb = Qpk + ((hd*64 + (c*4+w))*2)*512;
        aq[0] = *(const sh8*)(qb + lane*8);
        aq[1] = *(const sh8*)(qb + 512 + lane*8);
    }
    f32x4 ctx[4], cz[4];
    #pragma unroll
    for (int nb=0;nb<4;nb++){ ctx[nb]=(f32x4){0,0,0,0}; cz[nb]=(f32x4){0,0,0,0}; }
    int t_g = T0 + w*16 + quad*4;
    int rp = tid>>3, e0 = (tid&7)*8, r0 = rp*2;

    for (int sub=0; sub<6; sub++){
        int RB = RQ0 + sub*64;
        const unsigned short* vrow = vcb + (hd*LK + RB)*64;
        const unsigned short* krow = kcb + (hd*LK + RB)*64;
        __syncthreads();                 // protect LDS from previous sub's reads
        {
            float g0 = gl[(RB + r0)/KF - tq0];
            float g1 = gl[(RB + r0 + 1)/KF - tq0];
            sh8 v0 = *(const sh8*)(vrow + r0*64 + e0);
            sh8 v1 = *(const sh8*)(vrow + (r0+1)*64 + e0);
            sh8 k0 = *(const sh8*)(krow + r0*64 + e0);
            sh8 k1 = *(const sh8*)(krow + (r0+1)*64 + e0);
            *(sh8*)(&Vraw[r0*72 + e0]) = v0;
            *(sh8*)(&Vraw[(r0+1)*72 + e0]) = v1;
            #pragma unroll
            for (int j=0;j<8;j++){
                unsigned int pv = (unsigned int)f2bf(bf2f((unsigned short)v0[j])*g0)
                                | ((unsigned int)f2bf(bf2f((unsigned short)v1[j])*g1)<<16);
                *(unsigned int*)(&VT[(e0+j)*VTS + r0]) = pv;
                unsigned int pk = (unsigned int)(unsigned short)k0[j]
                                | ((unsigned int)(unsigned short)k1[j]<<16);
                *(unsigned int*)(&KT[(e0+j)*VTS + r0]) = pk;
            }
        }
        __syncthreads();                 // staging visible
        f32x4 S[4];
        #pragma unroll
        for (int nb=0;nb<4;nb++) S[nb]=(f32x4){0,0,0,0};
        #pragma unroll
        for (int ks=0;ks<2;ks++){
            #pragma unroll
            for (int nb=0;nb<4;nb++){
                sh8 b = *(const sh8*)(&Vraw[(nb*16+lm)*72 + ks*32 + quad*8]);
                S[nb] = __builtin_amdgcn_mfma_f32_16x16x32_bf16(aq[ks], b, S[nb], 0,0,0);
            }
        }
        // mask + gate -> As (per-wave region, same-wave consumer: no barrier needed)
        #pragma unroll
        for (int nb=0;nb<4;nb++){
            int row_l = nb*16+lm;
            int tp = (RB + row_l)/KF;
            float g = gl[tp - tq0];
            #pragma unroll
            for (int r=0;r<4;r++){
                float v = (t_g + r >= tp) ? S[nb][r]*g : 0.f;
                As[w][(quad*4+r)*ASS + row_l] = f2bf(v);
            }
        }
        #pragma unroll
        for (int ks=0;ks<2;ks++){
            sh8 a2 = *(const sh8*)(&As[w][lm*ASS + ks*32 + quad*8]);
            sh8 av = ld8_8B(&VT[(w*16+lm)*VTS + ks*32 + quad*8]);
            #pragma unroll
            for (int nb=0;nb<4;nb++){
                sh8 bk = ld8_8B(&KT[(nb*16+lm)*VTS + ks*32 + quad*8]);
                ctx[nb] = __builtin_amdgcn_mfma_f32_16x16x32_bf16(a2, bk, ctx[nb], 0,0,0);
                cz[nb]  = __builtin_amdgcn_mfma_f32_16x16x32_bf16(av, bk, cz[nb], 0,0,0);
            }
        }
    }
    #pragma unroll
    for (int nb=0;nb<4;nb++){
        #pragma unroll
        for (int r=0;r<4;r++){
            cpart[((qq*8+hd)*Ll + t_g + r)*64 + nb*16+lm] = ctx[nb][r];
        }
    }
    int ob = ((hd*16+c)*4+qq)*4096;
    #pragma unroll
    for (int nb=0;nb<4;nb++){
        #pragma unroll
        for (int r=0;r<4;r++){
            czp[ob + (w*16+quad*4+r)*64 + nb*16+lm] = cz[nb][r];
        }
    }
}

// exclusive chunk prefix -> bf16 B-frag layout
__global__ __launch_bounds__(256) void s0_kernel(
    const float* __restrict__ czp, unsigned short* __restrict__ S0b)
{
    int idx = blockIdx.x*256 + threadIdx.x;   // [d][e] position
    int hd = blockIdx.y;
    int d = idx>>6, e = idx&63;
    int frag = (d>>5)*2048 + (e>>4)*512 + ((((d>>3)&3)*16) + (e&15))*8 + (d&7);
    float a = 0.f;
    for (int c=0;c<16;c++){
        S0b[(hd*16+c)*4096 + frag] = f2bf(a);
        int b = ((hd*16+c)*4)*4096 + idx;
        a += czp[b] + czp[b+4096] + czp[b+2*4096] + czp[b+3*4096];
    }
}

// combine (MFMA): Cpk = factor * ( Qpk @ S0b + sum_q cpart )
__global__ __launch_bounds__(256) void combine_kernel(
    const unsigned short* __restrict__ Qpk, const unsigned short* __restrict__ S0b,
    const float* __restrict__ cpart, const float* __restrict__ factor,
    unsigned short* __restrict__ Cpk)
{
    int c=blockIdx.x, hd=blockIdx.y;
    int tid=threadIdx.x, wid=tid>>6, lane=tid&63, quad=lane>>4, lm=lane&15;
    int mb = c*4 + wid;
    sh8 aq0 = *(const sh8*)(Qpk + ((hd*64+mb)*2)*512 + lane*8);
    sh8 aq1 = *(const sh8*)(Qpk + ((hd*64+mb)*2+1)*512 + lane*8);
    const unsigned short* sb = S0b + (hd*16+c)*4096;
    f32x4 acc[4];
    #pragma unroll
    for (int nb=0;nb<4;nb++) acc[nb]=(f32x4){0.f,0.f,0.f,0.f};
    #pragma unroll
    for (int ks=0;ks<2;ks++){
        sh8 a = ks ? aq1 : aq0;
        #pragma unroll
        for (int nb=0;nb<4;nb++){
            sh8 b = *(const sh8*)(sb + ks*2048 + nb*512 + lane*8);
            acc[nb] = __builtin_amdgcn_mfma_f32_16x16x32_bf16(a, b, acc[nb], 0,0,0);
        }
    }
    float fv[4];
    #pragma unroll
    for (int r=0;r<4;r++) fv[r] = factor[hd*Ll + mb*16 + quad*4 + r];
    #pragma unroll
    for (int nb=0;nb<4;nb++){
        int e = nb*16 + lm;
        int dim = hd*64 + e;
        int ks2 = dim>>5, koff = dim&31, qd = koff>>3, jj = koff&7;
        #pragma unroll
        for (int r=0;r<4;r++){
            int t = mb*16 + quad*4 + r;
            float v = acc[nb][r];
            #pragma unroll
            for (int q=0;q<4;q++) v += cpart[((q*8+hd)*Ll + t)*64 + e];
            v *= fv[r];
            Cpk[((t>>4)*16 + ks2)*512 + qd*128 + (t&15)*8 + jj] = f2bf(v);
        }
    }
}

// out = Cpk @ Wopk + bo
__global__ __launch_bounds__(256) void outprojm_kernel(
    const unsigned short* __restrict__ Cpk, const unsigned short* __restrict__ Wopk,
    const float* __restrict__ bo, float* __restrict__ out)
{
    int mt=blockIdx.x, nt=blockIdx.y;
    int tid=threadIdx.x, wid=tid>>6, lane=tid&63;
    int mb=mt*4+wid;
    f32x4 acc[4];
    #pragma unroll
    for (int nb=0;nb<4;nb++) acc[nb]=(f32x4){0.f,0.f,0.f,0.f};
    for (int ks=0;ks<16;ks++){
        sh8 a = *(const sh8*)(Cpk + (mb*16+ks)*512 + lane*8);
        #pragma unroll
        for (int nb2=0;nb2<4;nb2++){
            sh8 b = *(const sh8*)(Wopk + ((nt*4+nb2)*16+ks)*512 + lane*8);
            acc[nb2] = __builtin_amdgcn_mfma_f32_16x16x32_bf16(a, b, acc[nb2], 0,0,0);
        }
    }
    int quad=lane>>4, col=lane&15;
    #pragma unroll
    for (int nb2=0;nb2<4;nb2++){
        int n = nt*64 + nb2*16 + col;
        float bval = bo[n];
        #pragma unroll
        for (int r=0;r<4;r++){
            out[(mb*16+quad*4+r)*Dm + n] = acc[nb2][r] + bval;
        }
    }
}

extern "C" void kernel_launch(void* const* d_in, const int* in_sizes, int n_in,
                              void* d_out, int out_size, void* d_ws, size_t ws_size,
                              hipStream_t stream)
{
    (void)in_sizes; (void)n_in; (void)out_size; (void)ws_size;
    const float* x   =(const float*)d_in[0];
    const float* Wq  =(const float*)d_in[1];
    const float* bq  =(const float*)d_in[2];
    const float* Wk  =(const float*)d_in[3];
    const float* bk  =(const float*)d_in[4];
    const float* Wv  =(const float*)d_in[5];
    const float* bv  =(const float*)d_in[6];
    const float* Wo  =(const float*)d_in[7];
    const float* bo  =(const float*)d_in[8];
    const float* Wg  =(const float*)d_in[9];
    const float* bg  =(const float*)d_in[10];
    const float* kvs =(const float*)d_in[11];
    const float* qks =(const float*)d_in[12];
    const float* filt=(const float*)d_in[13];
    float* ws = (float*)d_ws;
    float* qh    = ws+OFF_QH;
    float* kn    = ws+OFF_KN;
    float* vn    = ws+OFF_VN;
    float* simg  = ws+OFF_SIM;
    float* logits= ws+OFF_LOGITS;
    float* gates = ws+OFF_GATES;
    float* factor= ws+OFF_FACTOR;
    float* czp   = ws+OFF_CZP;
    float* cpart = ws+OFF_CPART;
    unsigned short* vcb  = (unsigned short*)(ws + OFF_VCB);
    unsigned short* kcb  = (unsigned short*)(ws + OFF_KCB);
    unsigned short* Qpk  = (unsigned short*)(ws + OFF_QPK);
    unsigned short* Mpk  = (unsigned short*)(ws + OFF_MPK);
    unsigned short* Wopk = (unsigned short*)(ws + OFF_WOPK);
    unsigned short* Cpk  = (unsigned short*)(ws + OFF_CPK);
    unsigned short* S0b  = (unsigned short*)(ws + OFF_S0);
    unsigned short* Fpk16= (unsigned short*)(ws + OFF_FPK_F);
    unsigned short* Upk  = (unsigned short*)(ws + OFF_UPK_F);
    unsigned short* Apk  = (unsigned short*)(ws + OFF_APK_F);
    unsigned short* Bpk  = (unsigned short*)(ws + OFF_BPK_F);
    float* out   = (float*)d_out;

    hipMemsetAsync(logits, 0, Hh*Ll*sizeof(float), stream);
    pack_all_kernel<<<dim3(296),    256,0,stream>>>(x,Wq,Wk,Wv,Wo,kvs,Wg,filt,
                                                    Apk,Bpk,Wopk,Mpk,Fpk16);
    qkvm_kernel   <<<dim3(16,24),   256,0,stream>>>(Apk,Bpk,bq,bk,bv,qh,kn,vn);
    nse_kernel    <<<dim3(2048),    256,0,stream>>>(qh,kn,vn,qks,simg,Upk,Qpk);
    convf_kernel  <<<dim3(8,12,8),  256,0,stream>>>(Fpk16,Upk,Mpk,vcb,kcb,logits);
    scan_kernel   <<<dim3(8),       256,0,stream>>>(simg,logits,bg,gates,factor);
    p3cz_kernel   <<<dim3(16,4,8),  256,0,stream>>>(Qpk,vcb,kcb,gates,cpart,czp);
    s0_kernel     <<<dim3(16,8),    256,0,stream>>>(czp,S0b);
    combine_kernel<<<dim3(16,8),    256,0,stream>>>(Qpk,S0b,cpart,factor,Cpk);
    outprojm_kernel<<<dim3(16,8),   256,0,stream>>>(Cpk,Wopk,bo,out);
}